// Round 11
// baseline (769.728 us; speedup 1.0000x reference)
//
#include <hip/hip_runtime.h>
#include <hip/hip_bf16.h>

#define N_ 128
#define C_ 64
#define T_ 128
#define V_ 25
#define S_ 3
#define IG 16
#define IH 8
#define H_ 8
#define D_ 200   // IH*V
#define CV 1600  // C_*V_
#define TV 3200  // T_*V_
#define EPSB 1e-5f
#define NCHUNK 16
#define TPC 8    // t per chunk (k_gcn_att1)

typedef __attribute__((ext_vector_type(8))) short short8v;
typedef __attribute__((ext_vector_type(4))) float f32x4;
#define MFMA16 __builtin_amdgcn_mfma_f32_16x16x32_bf16

__device__ __forceinline__ float sigm(float x){ return 1.f/(1.f+expf(-x)); }
__device__ __forceinline__ float b2f(__hip_bfloat16 b){ return __bfloat162float(b); }
__device__ __forceinline__ __hip_bfloat16 f2b(float f){ return __float2bfloat16(f); }
__device__ __forceinline__ float ubl(unsigned int u){ return __uint_as_float(u<<16); }
__device__ __forceinline__ float ubh(unsigned int u){ return __uint_as_float(u & 0xffff0000u); }
__device__ __forceinline__ unsigned short f2bu(float f){
  unsigned int u = __float_as_uint(f);
  u += 0x7fff + ((u>>16)&1);
  return (unsigned short)(u>>16);
}
__device__ __forceinline__ unsigned long long pk4bf(f32x4 v){
  unsigned long long a = f2bu(v[0]);
  unsigned long long b = f2bu(v[1]);
  unsigned long long c = f2bu(v[2]);
  unsigned long long d = f2bu(v[3]);
  return a | (b<<16) | (c<<32) | (d<<48);
}

// ---------------- K1a: MFMA adaptive graph attention partials ----------------
__global__ __launch_bounds__(256) void k_gcn_att1(
    const float* __restrict__ x,
    const float* __restrict__ Wq, const float* __restrict__ bq,
    const float* __restrict__ Wk, const float* __restrict__ bk,
    float* __restrict__ attg)
{
  const int tc = blockIdx.x, ns = blockIdx.y, n = ns / S_, s = ns % S_;
  const int tid = threadIdx.x;
  const int wv = tid>>6, l = tid&63, lc = l&15, lk = l>>4;
  __shared__ __align__(16) short wql[16*72], wkl[16*72];
  __shared__ float bql[16], bkl[16];
  __shared__ __align__(16) short xtb[4*32*72];   // [tl][v(32)][c(72)], v>=25 zeroed
  __shared__ __align__(16) char QB[32*256];      // [v][K=128 bf16], byte^=(v&7)<<4
  __shared__ __align__(16) char KB[32*256];
  for (int i=tid;i<IG*C_;i+=256){
    int ii=i>>6, c=i&63;
    wql[ii*72+c] = (short)f2bu(Wq[s*IG*C_+i]);
    wkl[ii*72+c] = (short)f2bu(Wk[s*IG*C_+i]);
  }
  if (tid<16){ bql[tid]=bq[s*IG+tid]; bkl[tid]=bk[s*IG+tid]; }
  for (int i=tid;i<4*7*72;i+=256){
    int tl=i/(7*72), r=i%(7*72);
    xtb[(tl*32+25)*72 + r] = 0;
  }
  const float* xn = x + (size_t)n*C_*T_*V_;
  const int t0 = tc*TPC;
  #pragma unroll
  for (int tg=0; tg<2; ++tg){
    __syncthreads();
    for (int i=tid;i<4*1600;i+=256){
      int tl=i/1600, r=i%1600, c=r/25, v=r%25;
      xtb[(tl*32+v)*72 + c] = (short)f2bu(xn[(size_t)c*TV + (t0+tg*4+tl)*V_ + v]);
    }
    __syncthreads();
    const int tcol = (tg*4+wv)*32;
    f32x4 z={0.f,0.f,0.f,0.f};
    f32x4 aq0=z,aq1=z,ak0=z,ak1=z;
    #pragma unroll
    for (int ks=0;ks<2;++ks){
      short8v aq = *(const short8v*)(wql + lc*72 + ks*32 + lk*8);
      short8v ak = *(const short8v*)(wkl + lc*72 + ks*32 + lk*8);
      short8v b0 = *(const short8v*)(xtb + (wv*32+lc)*72 + ks*32 + lk*8);
      short8v b1 = *(const short8v*)(xtb + (wv*32+16+lc)*72 + ks*32 + lk*8);
      aq0 = MFMA16(aq,b0,aq0,0,0,0);
      aq1 = MFMA16(aq,b1,aq1,0,0,0);
      ak0 = MFMA16(ak,b0,ak0,0,0,0);
      ak1 = MFMA16(ak,b1,ak1,0,0,0);
    }
    f32x4 q0,q1,k0,k1;
    #pragma unroll
    for (int r=0;r<4;++r){
      float bqv = bql[lk*4+r], bkv = bkl[lk*4+r];
      q0[r]=aq0[r]+bqv; q1[r]=aq1[r]+bqv;
      k0[r]=ak0[r]+bkv; k1[r]=ak1[r]+bkv;
    }
    const int sw = (lc&7)<<4;
    *(unsigned long long*)(QB + ((lc*256      + tcol + lk*8) ^ sw)) = pk4bf(q0);
    *(unsigned long long*)(QB + (((16+lc)*256 + tcol + lk*8) ^ sw)) = pk4bf(q1);
    *(unsigned long long*)(KB + ((lc*256      + tcol + lk*8) ^ sw)) = pk4bf(k0);
    *(unsigned long long*)(KB + (((16+lc)*256 + tcol + lk*8) ^ sw)) = pk4bf(k1);
  }
  __syncthreads();
  const int mt = wv>>1, nt = wv&1;
  const int sw = (lc&7)<<4;
  f32x4 acc = {0.f,0.f,0.f,0.f};
  #pragma unroll
  for (int ks=0;ks<4;++ks){
    short8v a = *(const short8v*)(QB + (((mt*16+lc)*256 + ks*64 + lk*16) ^ sw));
    short8v b = *(const short8v*)(KB + (((nt*16+lc)*256 + ks*64 + lk*16) ^ sw));
    acc = MFMA16(a,b,acc,0,0,0);
  }
  float* Ao = attg + ((size_t)tc*(N_*S_) + ns)*(V_*V_);
  #pragma unroll
  for (int reg=0;reg<4;++reg){
    int v = mt*16 + lk*4 + reg, w = nt*16 + lc;
    if (v<V_ && w<V_) Ao[v*V_+w] = acc[reg];
  }
}

// ---------------- K1b: reduce chunks + softmax(dim=-2) + Aad ----------------
__global__ __launch_bounds__(256) void k_gcn_att2(
    const float* __restrict__ attg, const float* __restrict__ A,
    const float* __restrict__ alphap, float* __restrict__ Aad)
{
  const int ns = blockIdx.x, s = ns % S_, tid = threadIdx.x;
  __shared__ float att[V_*V_];
  for (int i=tid;i<V_*V_;i+=256){
    float acc=0.f;
    #pragma unroll
    for (int tcc=0;tcc<NCHUNK;++tcc) acc += attg[((size_t)tcc*(N_*S_) + ns)*(V_*V_) + i];
    att[i]=acc;
  }
  __syncthreads();
  if (tid<V_){
    const int w=tid; const float inv=1.f/(IG*T_);
    float mx=-1e30f;
    for (int v=0;v<V_;++v) mx=fmaxf(mx, att[v*V_+w]*inv);
    float sum=0.f;
    for (int v=0;v<V_;++v){ float e=expf(att[v*V_+w]*inv-mx); att[v*V_+w]=e; sum+=e; }
    float rs=1.f/sum;
    for (int v=0;v<V_;++v) att[v*V_+w]*=rs;
  }
  __syncthreads();
  const float alpha=alphap[0];
  float* Ao = Aad + (size_t)ns*V_*V_;
  for (int i=tid;i<V_*V_;i+=256) Ao[i]=A[s*V_*V_+i]+alpha*att[i];
}

// ---------------- K2: 4-t tile MFMA graph conv + Wf + bn + residual + relu ----------------
__global__ __launch_bounds__(256) void k_gcn_y(
    const float* __restrict__ x, const float* __restrict__ Aad,
    const float* __restrict__ Wf, const float* __restrict__ bfp,
    const float* __restrict__ g_gamma, const float* __restrict__ g_beta,
    __hip_bfloat16* __restrict__ y1)
{
  const int tc=blockIdx.x, n=blockIdx.y, tid=threadIdx.x;
  const int wv=tid>>6, l=tid&63, lc=l&15, lk=l>>4;
  __shared__ __align__(16) short xtb[64*136];   // [c][t*32+v], v-pad zeroed
  __shared__ __align__(16) short AsT[3*32*40];  // [s][w][v], v-pad zeroed
  __shared__ __align__(16) short aggT[112*200]; // [tv][sc], rows 100..111 zeroed
  const float* xn = x + (size_t)n*C_*TV;
  const int tv0 = tc*100;
  for (int i=tid;i<64*25;i+=256){
    int c=i/25, a=i%25, tv4=a*4;
    float4 xv4 = *(const float4*)(xn + (size_t)c*TV + tv0 + tv4);
    float xv[4] = {xv4.x, xv4.y, xv4.z, xv4.w};
    #pragma unroll
    for (int j=0;j<4;++j){
      int tv=tv4+j, t=tv/25, v=tv-t*25;
      xtb[c*136 + t*32 + v] = (short)f2bu(xv[j]);
    }
  }
  for (int i=tid;i<64*28;i+=256){ int c=i/28, r=i%28; xtb[c*136 + (r/7)*32 + 25 + (r%7)] = 0; }
  for (int i=tid;i<3*32*7;i+=256){ int sw_=i/7; AsT[sw_*40 + 25 + (i%7)] = 0; }
  const float* Adn = Aad + (size_t)n*S_*V_*V_;
  for (int i=tid;i<S_*V_*V_;i+=256){
    int s=i/625, r=i%625, v=r/25, w=r%25;
    AsT[(s*32+w)*40+v] = (short)f2bu(Adn[i]);
  }
  for (int i=tid;i<12*200;i+=256) aggT[100*200+i]=0;
  __syncthreads();
  {
    const int t = wv;
    for (int s=0;s<S_;++s){
      short8v b0 = *(const short8v*)(AsT + (s*32+lc)*40 + lk*8);
      short8v b1 = *(const short8v*)(AsT + (s*32+16+lc)*40 + lk*8);
      #pragma unroll
      for (int mt=0;mt<4;++mt){
        short8v a = *(const short8v*)(xtb + (mt*16+lc)*136 + t*32 + lk*8);
        f32x4 z={0.f,0.f,0.f,0.f};
        f32x4 acc0 = MFMA16(a,b0,z,0,0,0);
        f32x4 acc1 = MFMA16(a,b1,z,0,0,0);
        *(unsigned long long*)(aggT + (t*25+lc)*200 + s*64 + mt*16 + lk*4) = pk4bf(acc0);
        if (lc<9)
          *(unsigned long long*)(aggT + (t*25+16+lc)*200 + s*64 + mt*16 + lk*4) = pk4bf(acc1);
      }
    }
  }
  short8v af[6];
  #pragma unroll
  for (int ks=0;ks<6;++ks){
    const int s = ks>>1, c0 = (ks&1)*32 + lk*8;
    const float* wr = Wf + ((size_t)s*C_ + wv*16+lc)*C_ + c0;
    short8v t8;
    #pragma unroll
    for (int j=0;j<8;++j) t8[j] = (short)f2bu(wr[j]);
    af[ks]=t8;
  }
  __syncthreads();
  f32x4 acc[7];
  #pragma unroll
  for (int dt=0;dt<7;++dt) acc[dt]=(f32x4){0.f,0.f,0.f,0.f};
  #pragma unroll
  for (int dt=0;dt<7;++dt){
    #pragma unroll
    for (int ks=0;ks<6;++ks){
      short8v b = *(const short8v*)(aggT + (dt*16+lc)*200 + ks*32 + lk*8);
      acc[dt] = MFMA16(af[ks], b, acc[dt],0,0,0);
    }
  }
  const float invs = rsqrtf(1.f+EPSB);
  __hip_bfloat16* yo = y1 + (size_t)n*C_*TV;
  #pragma unroll
  for (int reg=0;reg<4;++reg){
    const int o = wv*16 + lk*4 + reg;
    const float bsum = bfp[o]+bfp[C_+o]+bfp[2*C_+o];
    const float gs = g_gamma[o]*invs, gb = g_beta[o];
    #pragma unroll
    for (int dt=0;dt<7;++dt){
      const int tv = dt*16 + lc;
      if (tv < 100){
        float val = (acc[dt][reg]+bsum)*gs + gb + xn[(size_t)o*TV + tv0 + tv];
        yo[(size_t)o*TV + tv0 + tv] = f2b(fmaxf(val,0.f));
      }
    }
  }
}

// ---------------- K3a: seT[n,c,v] = mean_t y1 ----------------
__global__ __launch_bounds__(256) void k_seT(const __hip_bfloat16* __restrict__ y1,
    float* __restrict__ seT)
{
  const int c=blockIdx.x, n=blockIdx.y, tid=threadIdx.x;
  const int v = tid&31, g = tid>>5;
  __shared__ float red[8][33];
  const __hip_bfloat16* yp = y1 + ((size_t)n*C_+c)*T_*V_;
  float s=0.f;
  if (v < V_){
    #pragma unroll 4
    for (int j=0;j<16;++j){
      int t = g + j*8;
      s += b2f(yp[t*V_+v]);
    }
  }
  red[g][v]=s;
  __syncthreads();
  if (tid < V_){
    float tot=0.f;
    #pragma unroll
    for (int g2=0;g2<8;++g2) tot += red[g2][tid];
    seT[((size_t)n*C_+c)*V_+tid]=tot*(1.f/T_);
  }
}

// ---------------- K3b: sa[n,v] spatial gate ----------------
__global__ __launch_bounds__(64) void k_sa(const float* __restrict__ seT,
    const float* __restrict__ W_sa, const float* __restrict__ b_sa,
    float* __restrict__ sa)
{
  const int n=blockIdx.x, tid=threadIdx.x;
  if (tid>=V_) return;
  const float* se = seT + (size_t)n*C_*V_;
  float acc=b_sa[0];
  for (int c=0;c<C_;++c){
    #pragma unroll
    for (int k=0;k<V_;++k){
      int vv=tid+k-12;  // pad = (V-1)/2 = 12
      if (vv>=0&&vv<V_) acc+=se[c*V_+vv]*W_sa[c*V_+k];
    }
  }
  sa[n*V_+tid]=sigm(acc);
}

// ---------------- K3c: seV[n,c,t] = mean_v y1*(1+sa) ----------------
__global__ __launch_bounds__(256) void k_seV(const __hip_bfloat16* __restrict__ y1,
    const float* __restrict__ sa, float* __restrict__ seV)
{
  const int c=blockIdx.x, n=blockIdx.y, tid=threadIdx.x;
  const int v = tid&31, g = tid>>5;
  __shared__ float sal[32];
  if (tid<32) sal[tid] = (tid<V_)? 1.f+sa[n*V_+tid] : 0.f;
  __syncthreads();
  const __hip_bfloat16* yp = y1 + ((size_t)n*C_+c)*T_*V_;
  float* svo = seV + ((size_t)n*C_+c)*T_;
  const float sv_ = sal[v];
  for (int j=0;j<16;++j){
    int t = g*16 + j;
    float val = (v<V_)? b2f(yp[t*V_+v])*sv_ : 0.f;
    #pragma unroll
    for (int off=16;off;off>>=1) val += __shfl_xor(val, off);
    if (v==0) svo[t]=val*(1.f/V_);
  }
}

// ---------------- K3d: ta[n,t] temporal gate + ca[n,c] channel gate ----------------
__global__ __launch_bounds__(128) void k_ta_ca(const float* __restrict__ seV,
    const float* __restrict__ W_ta, const float* __restrict__ b_ta,
    const float* __restrict__ W_fc1, const float* __restrict__ b_fc1,
    const float* __restrict__ W_fc2, const float* __restrict__ b_fc2,
    float* __restrict__ ta, float* __restrict__ ca)
{
  const int n=blockIdx.x, tid=threadIdx.x;
  __shared__ float tal[T_];
  __shared__ float scl[C_];
  __shared__ float h1[32];
  const float* sv = seV + (size_t)n*C_*T_;
  {
    float acc=b_ta[0];
    for (int c=0;c<C_;++c){
      #pragma unroll
      for (int k=0;k<9;++k){
        int tt=tid+k-4;
        if (tt>=0&&tt<T_) acc+=sv[c*T_+tt]*W_ta[c*9+k];
      }
    }
    float s=sigm(acc);
    tal[tid]=s; ta[n*T_+tid]=s;
  }
  __syncthreads();
  if (tid<C_){
    float acc=0.f;
    for (int t=0;t<T_;++t) acc += sv[tid*T_+t]*(1.f+tal[t]);
    scl[tid]=acc*(1.f/T_);
  }
  __syncthreads();
  if (tid<32){
    float acc=b_fc1[tid];
    for (int c=0;c<C_;++c) acc += scl[c]*W_fc1[tid*C_+c];
    h1[tid]=fmaxf(acc,0.f);
  }
  __syncthreads();
  if (tid<C_){
    float acc=b_fc2[tid];
    for (int j=0;j<32;++j) acc += h1[j]*W_fc2[tid*32+j];
    ca[n*C_+tid]=sigm(acc);
  }
}

// ---------------- K4: 4-t tile MFMA xa/gates + q/k/v projections ----------------
__global__ __launch_bounds__(256) void k_xa_qkv(
    const __hip_bfloat16* __restrict__ y1, const float* __restrict__ pos_emb,
    const float* __restrict__ sa, const float* __restrict__ ta, const float* __restrict__ ca,
    const float* __restrict__ Wq_h, const float* __restrict__ bq_h,
    const float* __restrict__ Wk_h, const float* __restrict__ bk_h,
    const float* __restrict__ Wv_h, const float* __restrict__ bv_h,
    __hip_bfloat16* __restrict__ xa, __hip_bfloat16* __restrict__ qb,
    __hip_bfloat16* __restrict__ kb, __hip_bfloat16* __restrict__ vb)
{
  const int tc=blockIdx.x, n=blockIdx.y, tid=threadIdx.x;
  const int wv=tid>>6, l=tid&63, lc=l&15, lk=l>>4;
  __shared__ __align__(16) short w3[192*72];      // [mu][c], mu = which*64+ho
  __shared__ __align__(16) short xalT[4][32*72];  // per t: [v][c], v>=25 zeroed
  __shared__ float bl[192];
  __shared__ float sal[32], cal[64], tgs[4];
  for (int i=tid;i<192*64;i+=256){
    int mu=i>>6, c=i&63, which=mu/C_, ho=mu%C_;
    const float* W = which==0?Wq_h:(which==1?Wk_h:Wv_h);
    w3[mu*72+c] = (short)f2bu(W[(size_t)ho*C_+c]);
  }
  if (tid<192){
    int which=tid/C_, ho=tid%C_;
    bl[tid] = (which==0?bq_h:(which==1?bk_h:bv_h))[ho];
  }
  if (tid<32) sal[tid] = (tid<V_)? 1.f+sa[n*V_+tid] : 0.f;
  if (tid>=32 && tid<96) cal[tid-32] = 1.f+ca[n*C_+tid-32];
  if (tid>=96 && tid<100) tgs[tid-96] = 1.f+ta[n*T_+tc*4+(tid-96)];
  for (int i=tid;i<4*7*72;i+=256){
    int tl=i/(7*72), r=i%(7*72);
    xalT[tl][25*72 + r] = 0;   // rows 25..31 contiguous
  }
  __syncthreads();
  const int tv0 = tc*100;
  const __hip_bfloat16* y1n = y1 + (size_t)n*C_*TV;
  __hip_bfloat16* xan = xa + (size_t)n*C_*TV;
  // vectorized: y1 uint2 read (4 bf16), xa packed 8B write
  for (int i=tid;i<64*25;i+=256){
    int c=i/25, a=i%25, tv4=a*4;
    const unsigned int* ys = (const unsigned int*)(y1n + (size_t)c*TV + tv0 + tv4);
    unsigned int u0=ys[0], u1=ys[1];
    float yv[4] = {ubl(u0),ubh(u0),ubl(u1),ubh(u1)};
    const float calc = cal[c];
    unsigned long long pack = 0ull;
    #pragma unroll
    for (int j=0;j<4;++j){
      int tv=tv4+j, tl=tv/25, v=tv-tl*25;
      float val = yv[j]*sal[v]*tgs[tl]*calc + pos_emb[(size_t)(tc*4+tl)*CV + c*V_ + v];
      unsigned short b = f2bu(val);
      pack |= (unsigned long long)b << (16*j);
      xalT[tl][v*72 + c] = (short)b;
    }
    *(unsigned long long*)(xan + (size_t)c*TV + tv0 + tv4) = pack;
  }
  __syncthreads();
  const int t = tc*4 + wv;    // wave wv owns this t
  short8v bf_[2][2];
  #pragma unroll
  for (int ks=0;ks<2;++ks){
    bf_[ks][0] = *(const short8v*)(&xalT[wv][lc*72      + ks*32 + lk*8]);
    bf_[ks][1] = *(const short8v*)(&xalT[wv][(16+lc)*72 + ks*32 + lk*8]);
  }
  #pragma unroll
  for (int mt=0;mt<12;++mt){
    f32x4 acc0 = {0.f,0.f,0.f,0.f}, acc1 = {0.f,0.f,0.f,0.f};
    #pragma unroll
    for (int ks=0;ks<2;++ks){
      short8v a = *(const short8v*)(w3 + (mt*16+lc)*72 + ks*32 + lk*8);
      acc0 = MFMA16(a, bf_[ks][0], acc0,0,0,0);
      acc1 = MFMA16(a, bf_[ks][1], acc1,0,0,0);
    }
    #pragma unroll
    for (int reg=0;reg<4;++reg){
      const int mu = mt*16 + lk*4 + reg;
      const int which = mt>>2;              // = mu/64, constant per unrolled mt
      const int ho = mu & 63, h = ho>>3, o = ho&7;
      __hip_bfloat16* dst = (which==0?qb:(which==1?kb:vb))
                            + (((size_t)n*H_+h)*T_+t)*D_ + o*V_;
      const float bb = bl[mu];
      dst[lc] = f2b(acc0[reg]+bb);
      if (lc < 9) dst[16+lc] = f2b(acc1[reg]+bb);
    }
  }
}

// ---------------- K5: MFMA flash causal MHA ----------------
// NOTE: oh is written in (n, c, t, v) layout (c = h*8 + d/25, v = d%25) so that
// k_out can read it with coalesced uint2 loads, same as xa.
__global__ __launch_bounds__(256) void k_attn(
    const __hip_bfloat16* __restrict__ qb, const __hip_bfloat16* __restrict__ kb,
    const __hip_bfloat16* __restrict__ vb, __hip_bfloat16* __restrict__ oh)
{
  const int bx = blockIdx.x;
  const int hh = blockIdx.y;
  const int n  = blockIdx.z;
  const int nh = n*H_ + hh;
  const int tid = threadIdx.x;
  const int wv = tid>>6, l = tid&63;
  const int lc = l&15, lg = l>>4;
  __shared__ __align__(16) char KlB[32*512];      // [key][d(256sh)] bf16, byte^=(key&7)<<4
  __shared__ __align__(16) short VT[208*40];      // [d][key] bf16
  __shared__ __align__(16) short Pl[64*40];       // [qloc][key] bf16 (per-wave slices)
  const __hip_bfloat16* qg_ = qb + (size_t)nh*T_*D_;
  const __hip_bfloat16* kg_ = kb + (size_t)nh*T_*D_;
  const __hip_bfloat16* vg_ = vb + (size_t)nh*T_*D_;
  __hip_bfloat16* ohn = oh + (size_t)n*C_*TV;     // (n,c,t,v) layout
  const float scale = 0.0707106781f;  // 1/sqrt(200)

  for (int i=tid;i<32*12;i+=256){
    int key=i/12, j=i%12;
    *(unsigned int*)(KlB + ((key*512 + 400 + j*4) ^ ((key&7)<<4))) = 0u;
  }
  for (int i=tid;i<8*40;i+=256) VT[200*40 + i] = 0;

  const int qrow = bx*64 + wv*16 + lc;
  short8v qf[7];
  {
    const short8v* qs8 = (const short8v*)(qg_ + (size_t)qrow*D_);
    #pragma unroll
    for (int ks=0;ks<7;++ks) qf[ks] = qs8[ks*4 + lg];
  }
  f32x4 oacc[13];
  #pragma unroll
  for (int i=0;i<13;++i) oacc[i] = (f32x4){0.f,0.f,0.f,0.f};
  float m[4], lsm[4];
  #pragma unroll
  for (int r=0;r<4;++r){ m[r]=-1e30f; lsm[r]=0.f; }

  const int ntiles = (bx==0)? 2 : 4;
  for (int kt=0; kt<ntiles; ++kt){
    const int j0 = kt*32;
    __syncthreads();
    {
      const short8v* ks8 = (const short8v*)(kg_ + (size_t)j0*D_);
      for (int i=tid;i<32*25;i+=256){
        int row=i/25, w=i%25;
        *(short8v*)(KlB + ((row*512 + w*16) ^ ((row&7)<<4))) = ks8[i];
      }
      const short8v* vs8 = (const short8v*)(vg_ + (size_t)j0*D_);
      for (int i=tid;i<32*25;i+=256){
        int row=i&31, w4=i>>5;
        short8v u = vs8[row*25 + w4];
        #pragma unroll
        for (int j=0;j<8;++j) VT[(w4*8+j)*40 + row] = u[j];
      }
    }
    __syncthreads();
    const bool active = (j0 <= bx*64 + wv*16 + 15);
    if (active){
      f32x4 s0 = {0.f,0.f,0.f,0.f}, s1 = {0.f,0.f,0.f,0.f};
      #pragma unroll
      for (int ks=0;ks<7;++ks){
        short8v b0 = *(const short8v*)(KlB + ((lc*512      + ks*64 + lg*16) ^ ((lc&7)<<4)));
        short8v b1 = *(const short8v*)(KlB + (((16+lc)*512 + ks*64 + lg*16) ^ ((lc&7)<<4)));
        s0 = MFMA16(qf[ks], b0, s0,0,0,0);
        s1 = MFMA16(qf[ks], b1, s1,0,0,0);
      }
      float fr[4];
      #pragma unroll
      for (int r=0;r<4;++r){
        const int qg = bx*64 + wv*16 + lg*4 + r;
        float v0 = (j0+lc    <= qg) ? s0[r]*scale : -1e30f;
        float v1 = (j0+16+lc <= qg) ? s1[r]*scale : -1e30f;
        float mx = fmaxf(v0,v1);
        #pragma unroll
        for (int off=1;off<16;off<<=1) mx = fmaxf(mx, __shfl_xor(mx, off));
        float mn = fmaxf(m[r], mx);
        fr[r] = __expf(m[r]-mn);
        float p0 = __expf(v0-mn), p1 = __expf(v1-mn);
        float ts = p0+p1;
        #pragma unroll
        for (int off=1;off<16;off<<=1) ts += __shfl_xor(ts, off);
        lsm[r] = lsm[r]*fr[r] + ts;
        m[r] = mn;
        Pl[(wv*16 + lg*4 + r)*40 + lc]      = (short)f2bu(p0);
        Pl[(wv*16 + lg*4 + r)*40 + 16 + lc] = (short)f2bu(p1);
      }
      #pragma unroll
      for (int dt=0;dt<13;++dt){
        #pragma unroll
        for (int r=0;r<4;++r) oacc[dt][r] *= fr[r];
      }
      short8v pa = *(const short8v*)(Pl + (wv*16+lc)*40 + lg*8);
      #pragma unroll
      for (int dt=0;dt<13;++dt){
        short8v b = *(const short8v*)(VT + (dt*16+lc)*40 + lg*8);
        oacc[dt] = MFMA16(pa, b, oacc[dt],0,0,0);
      }
    }
  }
  float rl[4];
  #pragma unroll
  for (int r=0;r<4;++r) rl[r] = 1.f/lsm[r];
  #pragma unroll
  for (int dt=0;dt<13;++dt){
    const int d = dt*16 + lc;
    if (d < D_){
      const int oi = d/25, v = d - oi*25;
      const int c = hh*IH + oi;
      #pragma unroll
      for (int r=0;r<4;++r){
        const int q = bx*64 + wv*16 + lg*4 + r;
        ohn[(size_t)c*TV + q*V_ + v] = f2b(oacc[dt][r]*rl[r]);
      }
    }
  }
}

// ---------------- K7: 8-t tile MFMA out kernel ----------------
// oh now in (n,c,t,v) layout -> staging is fully uint2-vectorized like xa.
__global__ __launch_bounds__(256) void k_out(
    const __hip_bfloat16* __restrict__ oh, const __hip_bfloat16* __restrict__ xa,
    const float* __restrict__ x, const float* __restrict__ W_ffn,
    const float* __restrict__ b_ffn, const float* __restrict__ m_gamma,
    const float* __restrict__ m_beta, float* __restrict__ out)
{
  const int tc = blockIdx.x, n = blockIdx.y, tid = threadIdx.x;
  const int wv = tid>>6, l = tid&63, lc = l&15, lg = l>>4;
  __shared__ __align__(16) short wfl[64*72];   // W_ffn bf16 [o][c]
  __shared__ __align__(16) short zT[208*72];   // z^T bf16 [tv][c], rows 200..207 zeroed
  __shared__ float bn_s[64], bn_b[64], bff[64];
  const float invs = rsqrtf(1.f+EPSB);
  for (int i=tid;i<64*64;i+=256){
    int o=i>>6, c=i&63;
    wfl[o*72+c] = (short)f2bu(W_ffn[i]);
  }
  if (tid<64){ bn_s[tid]=m_gamma[tid]*invs; bn_b[tid]=m_beta[tid]; bff[tid]=b_ffn[tid]; }
  for (int i=tid;i<8*72;i+=256) zT[200*72+i]=0;
  __syncthreads();
  const int tv0 = tc*200;
  const __hip_bfloat16* xan = xa + (size_t)n*C_*TV;
  const __hip_bfloat16* ohn = oh + (size_t)n*C_*TV;
  // ---- assemble z^T: both xa and oh vectorized uint2 (4 bf16 each) ----
  for (int i=tid;i<64*50;i+=256){
    int c=i/50, a=i%50, tv4=a*4;
    const unsigned int* xs = (const unsigned int*)(xan + (size_t)c*TV + tv0 + tv4);
    const unsigned int* os = (const unsigned int*)(ohn + (size_t)c*TV + tv0 + tv4);
    unsigned int xu0 = xs[0], xu1 = xs[1];
    unsigned int ou0 = os[0], ou1 = os[1];
    float xv[4] = {ubl(xu0),ubh(xu0),ubl(xu1),ubh(xu1)};
    float ov[4] = {ubl(ou0),ubh(ou0),ubl(ou1),ubh(ou1)};
    const float s_=bn_s[c], b_=bn_b[c];
    #pragma unroll
    for (int j=0;j<4;++j){
      zT[(tv4+j)*72 + c] = (short)f2bu(s_*ov[j] + b_ + xv[j]);
    }
  }
  __syncthreads();
  const int lk = lg;
  short8v af0 = *(const short8v*)(wfl + (wv*16+lc)*72 + lk*8);
  short8v af1 = *(const short8v*)(wfl + (wv*16+lc)*72 + 32 + lk*8);
  f32x4 acc[13];
  #pragma unroll
  for (int dt=0;dt<13;++dt) acc[dt] = (f32x4){0.f,0.f,0.f,0.f};
  #pragma unroll
  for (int dt=0;dt<13;++dt){
    short8v b0 = *(const short8v*)(zT + (dt*16+lc)*72 + lk*8);
    short8v b1 = *(const short8v*)(zT + (dt*16+lc)*72 + 32 + lk*8);
    acc[dt] = MFMA16(af0, b0, acc[dt],0,0,0);
    acc[dt] = MFMA16(af1, b1, acc[dt],0,0,0);
  }
  const float* xn = x + (size_t)n*C_*TV;
  float* outn = out + (size_t)n*C_*TV;
  #pragma unroll
  for (int dt=0;dt<13;++dt){
    const int tv = dt*16 + lc;
    if (tv < 200){
      #pragma unroll
      for (int reg=0;reg<4;++reg){
        const int o = wv*16 + lg*4 + reg;
        float z2 = fmaxf(acc[dt][reg] + bff[o], 0.f) + b2f(xan[(size_t)o*TV + tv0 + tv]);
        float z3 = bn_s[o]*z2 + bn_b[o];
        outn[(size_t)o*TV + tv0 + tv] = fmaxf(z3 + xn[(size_t)o*TV + tv0 + tv], 0.f);
      }
    }
  }
}

extern "C" void kernel_launch(void* const* d_in, const int* in_sizes, int n_in,
                              void* d_out, int out_size, void* d_ws, size_t ws_size,
                              hipStream_t stream) {
  const float* x      = (const float*)d_in[0];
  const float* A      = (const float*)d_in[1];
  const float* alphap = (const float*)d_in[2];
  const float* Wq     = (const float*)d_in[3];
  const float* bq     = (const float*)d_in[4];
  const float* Wk     = (const float*)d_in[5];
  const float* bk     = (const float*)d_in[6];
  const float* Wf     = (const float*)d_in[7];
  const float* bfp    = (const float*)d_in[8];
  const float* g_gamma= (const float*)d_in[9];
  const float* g_beta = (const float*)d_in[10];
  const float* W_sa   = (const float*)d_in[11];
  const float* b_sa   = (const float*)d_in[12];
  const float* W_ta   = (const float*)d_in[13];
  const float* b_ta   = (const float*)d_in[14];
  const float* W_fc1  = (const float*)d_in[15];
  const float* b_fc1  = (const float*)d_in[16];
  const float* W_fc2  = (const float*)d_in[17];
  const float* b_fc2  = (const float*)d_in[18];
  const float* pos_emb= (const float*)d_in[19];
  const float* Wq_h   = (const float*)d_in[20];
  const float* bq_h   = (const float*)d_in[21];
  const float* Wk_h   = (const float*)d_in[22];
  const float* bk_h   = (const float*)d_in[23];
  const float* Wv_h   = (const float*)d_in[24];
  const float* bv_h   = (const float*)d_in[25];
  const float* W_ffn  = (const float*)d_in[26];
  const float* b_ffn  = (const float*)d_in[27];
  const float* m_gamma= (const float*)d_in[28];
  const float* m_beta = (const float*)d_in[29];
  float* out = (float*)d_out;

  float* ws   = (float*)d_ws;
  float* Aad  = ws;                    // 128*3*625   = 240000
  float* seT  = Aad + 240000;          // 128*64*25   = 204800
  float* seV  = seT + 204800;          // 128*64*128  = 1048576
  float* sa   = seV + 1048576;         // 128*25      = 3200
  float* ta   = sa  + 3200;            // 128*128     = 16384
  float* ca   = ta  + 16384;           // 128*64      = 8192
  __hip_bfloat16* y1 = (__hip_bfloat16*)(ca + 8192);  // 26214400 elems (reused as oh)
  __hip_bfloat16* xa = y1 + (size_t)26214400;
  __hip_bfloat16* qb = xa + (size_t)26214400;
  __hip_bfloat16* kb = qb + (size_t)26214400;
  __hip_bfloat16* vb = kb + (size_t)26214400;
  __hip_bfloat16* oh = y1;  // reuse: y1 dead after k_xa_qkv
  float* attg = (float*)y1; // scratch before y1 is written (16*384*625*4 = 15.4MB)

  k_gcn_att1<<<dim3(NCHUNK, N_*S_), 256, 0, stream>>>(x, Wq, bq, Wk, bk, attg);
  k_gcn_att2<<<N_*S_, 256, 0, stream>>>(attg, A, alphap, Aad);
  k_gcn_y<<<dim3(T_/4, N_), 256, 0, stream>>>(x, Aad, Wf, bfp, g_gamma, g_beta, y1);
  k_seT<<<dim3(C_, N_), 256, 0, stream>>>(y1, seT);
  k_sa<<<N_, 64, 0, stream>>>(seT, W_sa, b_sa, sa);
  k_seV<<<dim3(C_, N_), 256, 0, stream>>>(y1, sa, seV);
  k_ta_ca<<<N_, 128, 0, stream>>>(seV, W_ta, b_ta, W_fc1, b_fc1, W_fc2, b_fc2, ta, ca);
  k_xa_qkv<<<dim3(T_/4, N_), 256, 0, stream>>>(y1, pos_emb, sa, ta, ca,
      Wq_h, bq_h, Wk_h, bk_h, Wv_h, bv_h, xa, qb, kb, vb);
  k_attn<<<dim3(2, H_, N_), 256, 0, stream>>>(qb, kb, vb, oh);
  k_out<<<dim3(T_/8, N_), 256, 0, stream>>>(oh, xa, x, W_ffn, b_ffn, m_gamma, m_beta, out);
}

// Round 12
// 728.876 us; speedup vs baseline: 1.0560x; 1.0560x over previous
//
#include <hip/hip_runtime.h>
#include <hip/hip_bf16.h>

#define N_ 128
#define C_ 64
#define T_ 128
#define V_ 25
#define S_ 3
#define IG 16
#define IH 8
#define H_ 8
#define D_ 200   // IH*V
#define CV 1600  // C_*V_
#define TV 3200  // T_*V_
#define EPSB 1e-5f
#define NCHUNK 16
#define TPC 8    // t per chunk (k_gcn_att1)

typedef __attribute__((ext_vector_type(8))) short short8v;
typedef __attribute__((ext_vector_type(4))) float f32x4;
#define MFMA16 __builtin_amdgcn_mfma_f32_16x16x32_bf16
// zT column swizzle keyed on row bits that vary across staging lanes
#define ZIDX(r,c) ((r)*72 + ((c) ^ ((((r)>>3)&7)<<3)))

__device__ __forceinline__ float sigm(float x){ return 1.f/(1.f+expf(-x)); }
__device__ __forceinline__ float b2f(__hip_bfloat16 b){ return __bfloat162float(b); }
__device__ __forceinline__ __hip_bfloat16 f2b(float f){ return __float2bfloat16(f); }
__device__ __forceinline__ float ubl(unsigned int u){ return __uint_as_float(u<<16); }
__device__ __forceinline__ float ubh(unsigned int u){ return __uint_as_float(u & 0xffff0000u); }
__device__ __forceinline__ unsigned short f2bu(float f){
  unsigned int u = __float_as_uint(f);
  u += 0x7fff + ((u>>16)&1);
  return (unsigned short)(u>>16);
}
__device__ __forceinline__ unsigned long long pk4bf(f32x4 v){
  unsigned long long a = f2bu(v[0]);
  unsigned long long b = f2bu(v[1]);
  unsigned long long c = f2bu(v[2]);
  unsigned long long d = f2bu(v[3]);
  return a | (b<<16) | (c<<32) | (d<<48);
}

// ---------------- K1a: MFMA adaptive graph attention partials ----------------
__global__ __launch_bounds__(256) void k_gcn_att1(
    const float* __restrict__ x,
    const float* __restrict__ Wq, const float* __restrict__ bq,
    const float* __restrict__ Wk, const float* __restrict__ bk,
    float* __restrict__ attg)
{
  const int tc = blockIdx.x, ns = blockIdx.y, n = ns / S_, s = ns % S_;
  const int tid = threadIdx.x;
  const int wv = tid>>6, l = tid&63, lc = l&15, lk = l>>4;
  __shared__ __align__(16) short wql[16*72], wkl[16*72];
  __shared__ float bql[16], bkl[16];
  __shared__ __align__(16) short xtb[4*32*72];   // [tl][v(32)][c(72)], v>=25 zeroed
  __shared__ __align__(16) char QB[32*256];      // [v][K=128 bf16], byte^=(v&7)<<4
  __shared__ __align__(16) char KB[32*256];
  for (int i=tid;i<IG*C_;i+=256){
    int ii=i>>6, c=i&63;
    wql[ii*72+c] = (short)f2bu(Wq[s*IG*C_+i]);
    wkl[ii*72+c] = (short)f2bu(Wk[s*IG*C_+i]);
  }
  if (tid<16){ bql[tid]=bq[s*IG+tid]; bkl[tid]=bk[s*IG+tid]; }
  for (int i=tid;i<4*7*72;i+=256){
    int tl=i/(7*72), r=i%(7*72);
    xtb[(tl*32+25)*72 + r] = 0;
  }
  const float* xn = x + (size_t)n*C_*T_*V_;
  const int t0 = tc*TPC;
  #pragma unroll
  for (int tg=0; tg<2; ++tg){
    __syncthreads();
    for (int i=tid;i<4*1600;i+=256){
      int tl=i/1600, r=i%1600, c=r/25, v=r%25;
      xtb[(tl*32+v)*72 + c] = (short)f2bu(xn[(size_t)c*TV + (t0+tg*4+tl)*V_ + v]);
    }
    __syncthreads();
    const int tcol = (tg*4+wv)*32;
    f32x4 z={0.f,0.f,0.f,0.f};
    f32x4 aq0=z,aq1=z,ak0=z,ak1=z;
    #pragma unroll
    for (int ks=0;ks<2;++ks){
      short8v aq = *(const short8v*)(wql + lc*72 + ks*32 + lk*8);
      short8v ak = *(const short8v*)(wkl + lc*72 + ks*32 + lk*8);
      short8v b0 = *(const short8v*)(xtb + (wv*32+lc)*72 + ks*32 + lk*8);
      short8v b1 = *(const short8v*)(xtb + (wv*32+16+lc)*72 + ks*32 + lk*8);
      aq0 = MFMA16(aq,b0,aq0,0,0,0);
      aq1 = MFMA16(aq,b1,aq1,0,0,0);
      ak0 = MFMA16(ak,b0,ak0,0,0,0);
      ak1 = MFMA16(ak,b1,ak1,0,0,0);
    }
    f32x4 q0,q1,k0,k1;
    #pragma unroll
    for (int r=0;r<4;++r){
      float bqv = bql[lk*4+r], bkv = bkl[lk*4+r];
      q0[r]=aq0[r]+bqv; q1[r]=aq1[r]+bqv;
      k0[r]=ak0[r]+bkv; k1[r]=ak1[r]+bkv;
    }
    const int sw = (lc&7)<<4;
    *(unsigned long long*)(QB + ((lc*256      + tcol + lk*8) ^ sw)) = pk4bf(q0);
    *(unsigned long long*)(QB + (((16+lc)*256 + tcol + lk*8) ^ sw)) = pk4bf(q1);
    *(unsigned long long*)(KB + ((lc*256      + tcol + lk*8) ^ sw)) = pk4bf(k0);
    *(unsigned long long*)(KB + (((16+lc)*256 + tcol + lk*8) ^ sw)) = pk4bf(k1);
  }
  __syncthreads();
  const int mt = wv>>1, nt = wv&1;
  const int sw = (lc&7)<<4;
  f32x4 acc = {0.f,0.f,0.f,0.f};
  #pragma unroll
  for (int ks=0;ks<4;++ks){
    short8v a = *(const short8v*)(QB + (((mt*16+lc)*256 + ks*64 + lk*16) ^ sw));
    short8v b = *(const short8v*)(KB + (((nt*16+lc)*256 + ks*64 + lk*16) ^ sw));
    acc = MFMA16(a,b,acc,0,0,0);
  }
  float* Ao = attg + ((size_t)tc*(N_*S_) + ns)*(V_*V_);
  #pragma unroll
  for (int reg=0;reg<4;++reg){
    int v = mt*16 + lk*4 + reg, w = nt*16 + lc;
    if (v<V_ && w<V_) Ao[v*V_+w] = acc[reg];
  }
}

// ---------------- K1b: reduce chunks + softmax(dim=-2) + Aad ----------------
__global__ __launch_bounds__(256) void k_gcn_att2(
    const float* __restrict__ attg, const float* __restrict__ A,
    const float* __restrict__ alphap, float* __restrict__ Aad)
{
  const int ns = blockIdx.x, s = ns % S_, tid = threadIdx.x;
  __shared__ float att[V_*V_];
  for (int i=tid;i<V_*V_;i+=256){
    float acc=0.f;
    #pragma unroll
    for (int tcc=0;tcc<NCHUNK;++tcc) acc += attg[((size_t)tcc*(N_*S_) + ns)*(V_*V_) + i];
    att[i]=acc;
  }
  __syncthreads();
  if (tid<V_){
    const int w=tid; const float inv=1.f/(IG*T_);
    float mx=-1e30f;
    for (int v=0;v<V_;++v) mx=fmaxf(mx, att[v*V_+w]*inv);
    float sum=0.f;
    for (int v=0;v<V_;++v){ float e=expf(att[v*V_+w]*inv-mx); att[v*V_+w]=e; sum+=e; }
    float rs=1.f/sum;
    for (int v=0;v<V_;++v) att[v*V_+w]*=rs;
  }
  __syncthreads();
  const float alpha=alphap[0];
  float* Ao = Aad + (size_t)ns*V_*V_;
  for (int i=tid;i<V_*V_;i+=256) Ao[i]=A[s*V_*V_+i]+alpha*att[i];
}

// ---------------- K2: 4-t tile MFMA graph conv + Wf + bn + residual + relu ----------------
__global__ __launch_bounds__(256) void k_gcn_y(
    const float* __restrict__ x, const float* __restrict__ Aad,
    const float* __restrict__ Wf, const float* __restrict__ bfp,
    const float* __restrict__ g_gamma, const float* __restrict__ g_beta,
    __hip_bfloat16* __restrict__ y1)
{
  const int tc=blockIdx.x, n=blockIdx.y, tid=threadIdx.x;
  const int wv=tid>>6, l=tid&63, lc=l&15, lk=l>>4;
  __shared__ __align__(16) short xtb[64*136];   // [c][t*32+v], v-pad zeroed
  __shared__ __align__(16) short AsT[3*32*40];  // [s][w][v], v-pad zeroed
  __shared__ __align__(16) short aggT[112*200]; // [tv][sc], rows 100..111 zeroed
  const float* xn = x + (size_t)n*C_*TV;
  const int tv0 = tc*100;
  // batched x loads (MLP)
  float4 xbuf[7];
  #pragma unroll
  for (int k=0;k<7;++k){
    int i = tid + k*256;
    if (i < 1600){
      int c=i/25, a=i%25;
      xbuf[k] = *(const float4*)(xn + (size_t)c*TV + tv0 + a*4);
    }
  }
  #pragma unroll
  for (int k=0;k<7;++k){
    int i = tid + k*256;
    if (i < 1600){
      int c=i/25, a=i%25, tv4=a*4;
      float xv[4] = {xbuf[k].x, xbuf[k].y, xbuf[k].z, xbuf[k].w};
      #pragma unroll
      for (int j=0;j<4;++j){
        int tv=tv4+j, t=tv/25, v=tv-t*25;
        xtb[c*136 + t*32 + v] = (short)f2bu(xv[j]);
      }
    }
  }
  for (int i=tid;i<64*28;i+=256){ int c=i/28, r=i%28; xtb[c*136 + (r/7)*32 + 25 + (r%7)] = 0; }
  for (int i=tid;i<3*32*7;i+=256){ int sw_=i/7; AsT[sw_*40 + 25 + (i%7)] = 0; }
  const float* Adn = Aad + (size_t)n*S_*V_*V_;
  for (int i=tid;i<S_*V_*V_;i+=256){
    int s=i/625, r=i%625, v=r/25, w=r%25;
    AsT[(s*32+w)*40+v] = (short)f2bu(Adn[i]);
  }
  for (int i=tid;i<12*200;i+=256) aggT[100*200+i]=0;
  __syncthreads();
  {
    const int t = wv;
    for (int s=0;s<S_;++s){
      short8v b0 = *(const short8v*)(AsT + (s*32+lc)*40 + lk*8);
      short8v b1 = *(const short8v*)(AsT + (s*32+16+lc)*40 + lk*8);
      #pragma unroll
      for (int mt=0;mt<4;++mt){
        short8v a = *(const short8v*)(xtb + (mt*16+lc)*136 + t*32 + lk*8);
        f32x4 z={0.f,0.f,0.f,0.f};
        f32x4 acc0 = MFMA16(a,b0,z,0,0,0);
        f32x4 acc1 = MFMA16(a,b1,z,0,0,0);
        *(unsigned long long*)(aggT + (t*25+lc)*200 + s*64 + mt*16 + lk*4) = pk4bf(acc0);
        if (lc<9)
          *(unsigned long long*)(aggT + (t*25+16+lc)*200 + s*64 + mt*16 + lk*4) = pk4bf(acc1);
      }
    }
  }
  short8v af[6];
  #pragma unroll
  for (int ks=0;ks<6;++ks){
    const int s = ks>>1, c0 = (ks&1)*32 + lk*8;
    const float* wr = Wf + ((size_t)s*C_ + wv*16+lc)*C_ + c0;
    short8v t8;
    #pragma unroll
    for (int j=0;j<8;++j) t8[j] = (short)f2bu(wr[j]);
    af[ks]=t8;
  }
  __syncthreads();
  f32x4 acc[7];
  #pragma unroll
  for (int dt=0;dt<7;++dt) acc[dt]=(f32x4){0.f,0.f,0.f,0.f};
  #pragma unroll
  for (int dt=0;dt<7;++dt){
    #pragma unroll
    for (int ks=0;ks<6;++ks){
      short8v b = *(const short8v*)(aggT + (dt*16+lc)*200 + ks*32 + lk*8);
      acc[dt] = MFMA16(af[ks], b, acc[dt],0,0,0);
    }
  }
  const float invs = rsqrtf(1.f+EPSB);
  __hip_bfloat16* yo = y1 + (size_t)n*C_*TV;
  #pragma unroll
  for (int reg=0;reg<4;++reg){
    const int o = wv*16 + lk*4 + reg;
    const float bsum = bfp[o]+bfp[C_+o]+bfp[2*C_+o];
    const float gs = g_gamma[o]*invs, gb = g_beta[o];
    #pragma unroll
    for (int dt=0;dt<7;++dt){
      const int tv = dt*16 + lc;
      if (tv < 100){
        float val = (acc[dt][reg]+bsum)*gs + gb + xn[(size_t)o*TV + tv0 + tv];
        yo[(size_t)o*TV + tv0 + tv] = f2b(fmaxf(val,0.f));
      }
    }
  }
}

// ---------------- K3a: seT[n,c,v] = mean_t y1 ----------------
__global__ __launch_bounds__(256) void k_seT(const __hip_bfloat16* __restrict__ y1,
    float* __restrict__ seT)
{
  const int c=blockIdx.x, n=blockIdx.y, tid=threadIdx.x;
  const int v = tid&31, g = tid>>5;
  __shared__ float red[8][33];
  const __hip_bfloat16* yp = y1 + ((size_t)n*C_+c)*T_*V_;
  float s=0.f;
  if (v < V_){
    #pragma unroll 4
    for (int j=0;j<16;++j){
      int t = g + j*8;
      s += b2f(yp[t*V_+v]);
    }
  }
  red[g][v]=s;
  __syncthreads();
  if (tid < V_){
    float tot=0.f;
    #pragma unroll
    for (int g2=0;g2<8;++g2) tot += red[g2][tid];
    seT[((size_t)n*C_+c)*V_+tid]=tot*(1.f/T_);
  }
}

// ---------------- K3b: sa[n,v] spatial gate ----------------
__global__ __launch_bounds__(64) void k_sa(const float* __restrict__ seT,
    const float* __restrict__ W_sa, const float* __restrict__ b_sa,
    float* __restrict__ sa)
{
  const int n=blockIdx.x, tid=threadIdx.x;
  if (tid>=V_) return;
  const float* se = seT + (size_t)n*C_*V_;
  float acc=b_sa[0];
  for (int c=0;c<C_;++c){
    #pragma unroll
    for (int k=0;k<V_;++k){
      int vv=tid+k-12;  // pad = (V-1)/2 = 12
      if (vv>=0&&vv<V_) acc+=se[c*V_+vv]*W_sa[c*V_+k];
    }
  }
  sa[n*V_+tid]=sigm(acc);
}

// ---------------- K3c: seV[n,c,t] = mean_v y1*(1+sa) ----------------
__global__ __launch_bounds__(256) void k_seV(const __hip_bfloat16* __restrict__ y1,
    const float* __restrict__ sa, float* __restrict__ seV)
{
  const int c=blockIdx.x, n=blockIdx.y, tid=threadIdx.x;
  const int v = tid&31, g = tid>>5;
  __shared__ float sal[32];
  if (tid<32) sal[tid] = (tid<V_)? 1.f+sa[n*V_+tid] : 0.f;
  __syncthreads();
  const __hip_bfloat16* yp = y1 + ((size_t)n*C_+c)*T_*V_;
  float* svo = seV + ((size_t)n*C_+c)*T_;
  const float sv_ = sal[v];
  for (int j=0;j<16;++j){
    int t = g*16 + j;
    float val = (v<V_)? b2f(yp[t*V_+v])*sv_ : 0.f;
    #pragma unroll
    for (int off=16;off;off>>=1) val += __shfl_xor(val, off);
    if (v==0) svo[t]=val*(1.f/V_);
  }
}

// ---------------- K3d: ta[n,t] temporal gate + ca[n,c] channel gate ----------------
__global__ __launch_bounds__(128) void k_ta_ca(const float* __restrict__ seV,
    const float* __restrict__ W_ta, const float* __restrict__ b_ta,
    const float* __restrict__ W_fc1, const float* __restrict__ b_fc1,
    const float* __restrict__ W_fc2, const float* __restrict__ b_fc2,
    float* __restrict__ ta, float* __restrict__ ca)
{
  const int n=blockIdx.x, tid=threadIdx.x;
  __shared__ float tal[T_];
  __shared__ float scl[C_];
  __shared__ float h1[32];
  const float* sv = seV + (size_t)n*C_*T_;
  {
    float acc=b_ta[0];
    for (int c=0;c<C_;++c){
      #pragma unroll
      for (int k=0;k<9;++k){
        int tt=tid+k-4;
        if (tt>=0&&tt<T_) acc+=sv[c*T_+tt]*W_ta[c*9+k];
      }
    }
    float s=sigm(acc);
    tal[tid]=s; ta[n*T_+tid]=s;
  }
  __syncthreads();
  if (tid<C_){
    float acc=0.f;
    for (int t=0;t<T_;++t) acc += sv[tid*T_+t]*(1.f+tal[t]);
    scl[tid]=acc*(1.f/T_);
  }
  __syncthreads();
  if (tid<32){
    float acc=b_fc1[tid];
    for (int c=0;c<C_;++c) acc += scl[c]*W_fc1[tid*C_+c];
    h1[tid]=fmaxf(acc,0.f);
  }
  __syncthreads();
  if (tid<C_){
    float acc=b_fc2[tid];
    for (int j=0;j<32;++j) acc += h1[j]*W_fc2[tid*32+j];
    ca[n*C_+tid]=sigm(acc);
  }
}

// ---------------- K4: 4-t tile MFMA xa/gates + q/k/v projections ----------------
__global__ __launch_bounds__(256) void k_xa_qkv(
    const __hip_bfloat16* __restrict__ y1, const float* __restrict__ pos_emb,
    const float* __restrict__ sa, const float* __restrict__ ta, const float* __restrict__ ca,
    const float* __restrict__ Wq_h, const float* __restrict__ bq_h,
    const float* __restrict__ Wk_h, const float* __restrict__ bk_h,
    const float* __restrict__ Wv_h, const float* __restrict__ bv_h,
    __hip_bfloat16* __restrict__ xa, __hip_bfloat16* __restrict__ qb,
    __hip_bfloat16* __restrict__ kb, __hip_bfloat16* __restrict__ vb)
{
  const int tc=blockIdx.x, n=blockIdx.y, tid=threadIdx.x;
  const int wv=tid>>6, l=tid&63, lc=l&15, lk=l>>4;
  __shared__ __align__(16) short w3[192*72];      // [mu][c], mu = which*64+ho
  __shared__ __align__(16) short xalT[4][32*72];  // per t: [v][c], v>=25 zeroed
  __shared__ float bl[192];
  __shared__ float sal[32], cal[64], tgs[4];
  const int tv0 = tc*100;
  const __hip_bfloat16* y1n = y1 + (size_t)n*C_*TV;
  __hip_bfloat16* xan = xa + (size_t)n*C_*TV;
  // batched y1 loads (MLP) — issued before any LDS dependency
  uint2 ybuf[7];
  #pragma unroll
  for (int k=0;k<7;++k){
    int i = tid + k*256;
    if (i < 1600){
      int c=i/25, a=i%25;
      ybuf[k] = *(const uint2*)(y1n + (size_t)c*TV + tv0 + a*4);
    }
  }
  for (int i=tid;i<192*64;i+=256){
    int mu=i>>6, c=i&63, which=mu/C_, ho=mu%C_;
    const float* W = which==0?Wq_h:(which==1?Wk_h:Wv_h);
    w3[mu*72+c] = (short)f2bu(W[(size_t)ho*C_+c]);
  }
  if (tid<192){
    int which=tid/C_, ho=tid%C_;
    bl[tid] = (which==0?bq_h:(which==1?bk_h:bv_h))[ho];
  }
  if (tid<32) sal[tid] = (tid<V_)? 1.f+sa[n*V_+tid] : 0.f;
  if (tid>=32 && tid<96) cal[tid-32] = 1.f+ca[n*C_+tid-32];
  if (tid>=96 && tid<100) tgs[tid-96] = 1.f+ta[n*T_+tc*4+(tid-96)];
  for (int i=tid;i<4*7*72;i+=256){
    int tl=i/(7*72), r=i%(7*72);
    xalT[tl][25*72 + r] = 0;   // rows 25..31 contiguous
  }
  __syncthreads();
  #pragma unroll
  for (int k=0;k<7;++k){
    int i = tid + k*256;
    if (i < 1600){
      int c=i/25, a=i%25, tv4=a*4;
      unsigned int u0=ybuf[k].x, u1=ybuf[k].y;
      float yv[4] = {ubl(u0),ubh(u0),ubl(u1),ubh(u1)};
      const float calc = cal[c];
      unsigned long long pack = 0ull;
      #pragma unroll
      for (int j=0;j<4;++j){
        int tv=tv4+j, tl=tv/25, v=tv-tl*25;
        float val = yv[j]*sal[v]*tgs[tl]*calc + pos_emb[(size_t)(tc*4+tl)*CV + c*V_ + v];
        unsigned short b = f2bu(val);
        pack |= (unsigned long long)b << (16*j);
        xalT[tl][v*72 + c] = (short)b;
      }
      *(unsigned long long*)(xan + (size_t)c*TV + tv0 + tv4) = pack;
    }
  }
  __syncthreads();
  const int t = tc*4 + wv;    // wave wv owns this t
  short8v bf_[2][2];
  #pragma unroll
  for (int ks=0;ks<2;++ks){
    bf_[ks][0] = *(const short8v*)(&xalT[wv][lc*72      + ks*32 + lk*8]);
    bf_[ks][1] = *(const short8v*)(&xalT[wv][(16+lc)*72 + ks*32 + lk*8]);
  }
  #pragma unroll
  for (int mt=0;mt<12;++mt){
    f32x4 acc0 = {0.f,0.f,0.f,0.f}, acc1 = {0.f,0.f,0.f,0.f};
    #pragma unroll
    for (int ks=0;ks<2;++ks){
      short8v a = *(const short8v*)(w3 + (mt*16+lc)*72 + ks*32 + lk*8);
      acc0 = MFMA16(a, bf_[ks][0], acc0,0,0,0);
      acc1 = MFMA16(a, bf_[ks][1], acc1,0,0,0);
    }
    #pragma unroll
    for (int reg=0;reg<4;++reg){
      const int mu = mt*16 + lk*4 + reg;
      const int which = mt>>2;              // = mu/64, constant per unrolled mt
      const int ho = mu & 63, h = ho>>3, o = ho&7;
      __hip_bfloat16* dst = (which==0?qb:(which==1?kb:vb))
                            + (((size_t)n*H_+h)*T_+t)*D_ + o*V_;
      const float bb = bl[mu];
      dst[lc] = f2b(acc0[reg]+bb);
      if (lc < 9) dst[16+lc] = f2b(acc1[reg]+bb);
    }
  }
}

// ---------------- K5: MFMA flash causal MHA ----------------
// oh written in (n, c, t, v) layout (c = h*8 + d/25, v = d%25).
__global__ __launch_bounds__(256) void k_attn(
    const __hip_bfloat16* __restrict__ qb, const __hip_bfloat16* __restrict__ kb,
    const __hip_bfloat16* __restrict__ vb, __hip_bfloat16* __restrict__ oh)
{
  const int bx = blockIdx.x;
  const int hh = blockIdx.y;
  const int n  = blockIdx.z;
  const int nh = n*H_ + hh;
  const int tid = threadIdx.x;
  const int wv = tid>>6, l = tid&63;
  const int lc = l&15, lg = l>>4;
  __shared__ __align__(16) char KlB[32*512];      // [key][d(256sh)] bf16, byte^=(key&7)<<4
  __shared__ __align__(16) short VT[208*40];      // [d][key] bf16
  __shared__ __align__(16) short Pl[64*40];       // [qloc][key] bf16 (per-wave slices)
  const __hip_bfloat16* qg_ = qb + (size_t)nh*T_*D_;
  const __hip_bfloat16* kg_ = kb + (size_t)nh*T_*D_;
  const __hip_bfloat16* vg_ = vb + (size_t)nh*T_*D_;
  __hip_bfloat16* ohn = oh + (size_t)n*C_*TV;     // (n,c,t,v) layout
  const float scale = 0.0707106781f;  // 1/sqrt(200)

  for (int i=tid;i<32*12;i+=256){
    int key=i/12, j=i%12;
    *(unsigned int*)(KlB + ((key*512 + 400 + j*4) ^ ((key&7)<<4))) = 0u;
  }
  for (int i=tid;i<8*40;i+=256) VT[200*40 + i] = 0;

  const int qrow = bx*64 + wv*16 + lc;
  short8v qf[7];
  {
    const short8v* qs8 = (const short8v*)(qg_ + (size_t)qrow*D_);
    #pragma unroll
    for (int ks=0;ks<7;++ks) qf[ks] = qs8[ks*4 + lg];
  }
  f32x4 oacc[13];
  #pragma unroll
  for (int i=0;i<13;++i) oacc[i] = (f32x4){0.f,0.f,0.f,0.f};
  float m[4], lsm[4];
  #pragma unroll
  for (int r=0;r<4;++r){ m[r]=-1e30f; lsm[r]=0.f; }

  const int ntiles = (bx==0)? 2 : 4;
  for (int kt=0; kt<ntiles; ++kt){
    const int j0 = kt*32;
    __syncthreads();
    {
      const short8v* ks8 = (const short8v*)(kg_ + (size_t)j0*D_);
      for (int i=tid;i<32*25;i+=256){
        int row=i/25, w=i%25;
        *(short8v*)(KlB + ((row*512 + w*16) ^ ((row&7)<<4))) = ks8[i];
      }
      const short8v* vs8 = (const short8v*)(vg_ + (size_t)j0*D_);
      for (int i=tid;i<32*25;i+=256){
        int row=i&31, w4=i>>5;
        short8v u = vs8[row*25 + w4];
        #pragma unroll
        for (int j=0;j<8;++j) VT[(w4*8+j)*40 + row] = u[j];
      }
    }
    __syncthreads();
    const bool active = (j0 <= bx*64 + wv*16 + 15);
    if (active){
      f32x4 s0 = {0.f,0.f,0.f,0.f}, s1 = {0.f,0.f,0.f,0.f};
      #pragma unroll
      for (int ks=0;ks<7;++ks){
        short8v b0 = *(const short8v*)(KlB + ((lc*512      + ks*64 + lg*16) ^ ((lc&7)<<4)));
        short8v b1 = *(const short8v*)(KlB + (((16+lc)*512 + ks*64 + lg*16) ^ ((lc&7)<<4)));
        s0 = MFMA16(qf[ks], b0, s0,0,0,0);
        s1 = MFMA16(qf[ks], b1, s1,0,0,0);
      }
      float fr[4];
      #pragma unroll
      for (int r=0;r<4;++r){
        const int qg = bx*64 + wv*16 + lg*4 + r;
        float v0 = (j0+lc    <= qg) ? s0[r]*scale : -1e30f;
        float v1 = (j0+16+lc <= qg) ? s1[r]*scale : -1e30f;
        float mx = fmaxf(v0,v1);
        #pragma unroll
        for (int off=1;off<16;off<<=1) mx = fmaxf(mx, __shfl_xor(mx, off));
        float mn = fmaxf(m[r], mx);
        fr[r] = __expf(m[r]-mn);
        float p0 = __expf(v0-mn), p1 = __expf(v1-mn);
        float ts = p0+p1;
        #pragma unroll
        for (int off=1;off<16;off<<=1) ts += __shfl_xor(ts, off);
        lsm[r] = lsm[r]*fr[r] + ts;
        m[r] = mn;
        Pl[(wv*16 + lg*4 + r)*40 + lc]      = (short)f2bu(p0);
        Pl[(wv*16 + lg*4 + r)*40 + 16 + lc] = (short)f2bu(p1);
      }
      #pragma unroll
      for (int dt=0;dt<13;++dt){
        #pragma unroll
        for (int r=0;r<4;++r) oacc[dt][r] *= fr[r];
      }
      short8v pa = *(const short8v*)(Pl + (wv*16+lc)*40 + lg*8);
      #pragma unroll
      for (int dt=0;dt<13;++dt){
        short8v b = *(const short8v*)(VT + (dt*16+lc)*40 + lg*8);
        oacc[dt] = MFMA16(pa, b, oacc[dt],0,0,0);
      }
    }
  }
  float rl[4];
  #pragma unroll
  for (int r=0;r<4;++r) rl[r] = 1.f/lsm[r];
  #pragma unroll
  for (int dt=0;dt<13;++dt){
    const int d = dt*16 + lc;
    if (d < D_){
      const int oi = d/25, v = d - oi*25;
      const int c = hh*IH + oi;
      #pragma unroll
      for (int r=0;r<4;++r){
        const int q = bx*64 + wv*16 + lg*4 + r;
        ohn[(size_t)c*TV + q*V_ + v] = f2b(oacc[dt][r]*rl[r]);
      }
    }
  }
}

// ---------------- K7: 8-t tile MFMA out kernel (MLP-batched staging + swizzled zT) ----------------
__global__ __launch_bounds__(256) void k_out(
    const __hip_bfloat16* __restrict__ oh, const __hip_bfloat16* __restrict__ xa,
    const float* __restrict__ x, const float* __restrict__ W_ffn,
    const float* __restrict__ b_ffn, const float* __restrict__ m_gamma,
    const float* __restrict__ m_beta, float* __restrict__ out)
{
  const int tc = blockIdx.x, n = blockIdx.y, tid = threadIdx.x;
  const int wv = tid>>6, l = tid&63, lc = l&15, lg = l>>4;
  __shared__ __align__(16) short zT[208*72];   // z^T bf16, swizzled cols, rows 200..207 zeroed
  __shared__ float bn_s[64], bn_b[64], bff[64];
  const float invs = rsqrtf(1.f+EPSB);
  if (tid<64){ bn_s[tid]=m_gamma[tid]*invs; bn_b[tid]=m_beta[tid]; bff[tid]=b_ffn[tid]; }
  for (int i=tid;i<8*72;i+=256) zT[200*72+i]=0;
  const int tv0 = tc*200;
  const __hip_bfloat16* xan = xa + (size_t)n*C_*TV;
  const __hip_bfloat16* ohn = oh + (size_t)n*C_*TV;
  // ---- batched loads (MLP): 7 x (uint4 xa + uint4 oh) = 8 bf16 each ----
  uint4 xbuf[7], obuf[7];
  #pragma unroll
  for (int k=0;k<7;++k){
    int i = tid + k*256;
    if (i < 1600){
      int c=i/25, a=i%25;
      xbuf[k] = *(const uint4*)(xan + (size_t)c*TV + tv0 + a*8);
      obuf[k] = *(const uint4*)(ohn + (size_t)c*TV + tv0 + a*8);
    }
  }
  __syncthreads();   // bn_s ready
  #pragma unroll
  for (int k=0;k<7;++k){
    int i = tid + k*256;
    if (i < 1600){
      int c=i/25, a=i%25, tv8=a*8;
      const float s_=bn_s[c], b_=bn_b[c];
      const unsigned int* xu = (const unsigned int*)&xbuf[k];
      const unsigned int* ou = (const unsigned int*)&obuf[k];
      #pragma unroll
      for (int j=0;j<4;++j){
        zT[ZIDX(tv8+2*j,   c)] = (short)f2bu(s_*ubl(ou[j]) + b_ + ubl(xu[j]));
        zT[ZIDX(tv8+2*j+1, c)] = (short)f2bu(s_*ubh(ou[j]) + b_ + ubh(xu[j]));
      }
    }
  }
  __syncthreads();
  // ---- A-frags from global W_ffn (f32 -> bf16, L2-hot) ----
  short8v af0, af1;
  {
    const float* wr = W_ffn + (size_t)(wv*16+lc)*C_ + lg*8;
    #pragma unroll
    for (int j=0;j<8;++j){ af0[j]=(short)f2bu(wr[j]); af1[j]=(short)f2bu(wr[32+j]); }
  }
  f32x4 acc[13];
  #pragma unroll
  for (int dt=0;dt<13;++dt) acc[dt] = (f32x4){0.f,0.f,0.f,0.f};
  #pragma unroll
  for (int dt=0;dt<13;++dt){
    short8v b0 = *(const short8v*)(zT + ZIDX(dt*16+lc, lg*8));
    short8v b1 = *(const short8v*)(zT + ZIDX(dt*16+lc, 32+lg*8));
    acc[dt] = MFMA16(af0, b0, acc[dt],0,0,0);
    acc[dt] = MFMA16(af1, b1, acc[dt],0,0,0);
  }
  const float* xn = x + (size_t)n*C_*TV;
  float* outn = out + (size_t)n*C_*TV;
  #pragma unroll
  for (int dt=0;dt<13;++dt){
    const int tv = dt*16 + lc;
    if (tv < 200){
      #pragma unroll
      for (int reg=0;reg<4;++reg){
        const int o = wv*16 + lg*4 + reg;
        float z2 = fmaxf(acc[dt][reg] + bff[o], 0.f) + b2f(xan[(size_t)o*TV + tv0 + tv]);
        float z3 = bn_s[o]*z2 + bn_b[o];
        outn[(size_t)o*TV + tv0 + tv] = fmaxf(z3 + xn[(size_t)o*TV + tv0 + tv], 0.f);
      }
    }
  }
}

extern "C" void kernel_launch(void* const* d_in, const int* in_sizes, int n_in,
                              void* d_out, int out_size, void* d_ws, size_t ws_size,
                              hipStream_t stream) {
  const float* x      = (const float*)d_in[0];
  const float* A      = (const float*)d_in[1];
  const float* alphap = (const float*)d_in[2];
  const float* Wq     = (const float*)d_in[3];
  const float* bq     = (const float*)d_in[4];
  const float* Wk     = (const float*)d_in[5];
  const float* bk     = (const float*)d_in[6];
  const float* Wf     = (const float*)d_in[7];
  const float* bfp    = (const float*)d_in[8];
  const float* g_gamma= (const float*)d_in[9];
  const float* g_beta = (const float*)d_in[10];
  const float* W_sa   = (const float*)d_in[11];
  const float* b_sa   = (const float*)d_in[12];
  const float* W_ta   = (const float*)d_in[13];
  const float* b_ta   = (const float*)d_in[14];
  const float* W_fc1  = (const float*)d_in[15];
  const float* b_fc1  = (const float*)d_in[16];
  const float* W_fc2  = (const float*)d_in[17];
  const float* b_fc2  = (const float*)d_in[18];
  const float* pos_emb= (const float*)d_in[19];
  const float* Wq_h   = (const float*)d_in[20];
  const float* bq_h   = (const float*)d_in[21];
  const float* Wk_h   = (const float*)d_in[22];
  const float* bk_h   = (const float*)d_in[23];
  const float* Wv_h   = (const float*)d_in[24];
  const float* bv_h   = (const float*)d_in[25];
  const float* W_ffn  = (const float*)d_in[26];
  const float* b_ffn  = (const float*)d_in[27];
  const float* m_gamma= (const float*)d_in[28];
  const float* m_beta = (const float*)d_in[29];
  float* out = (float*)d_out;

  float* ws   = (float*)d_ws;
  float* Aad  = ws;                    // 128*3*625   = 240000
  float* seT  = Aad + 240000;          // 128*64*25   = 204800
  float* seV  = seT + 204800;          // 128*64*128  = 1048576
  float* sa   = seV + 1048576;         // 128*25      = 3200
  float* ta   = sa  + 3200;            // 128*128     = 16384
  float* ca   = ta  + 16384;           // 128*64      = 8192
  __hip_bfloat16* y1 = (__hip_bfloat16*)(ca + 8192);  // 26214400 elems (reused as oh)
  __hip_bfloat16* xa = y1 + (size_t)26214400;
  __hip_bfloat16* qb = xa + (size_t)26214400;
  __hip_bfloat16* kb = qb + (size_t)26214400;
  __hip_bfloat16* vb = kb + (size_t)26214400;
  __hip_bfloat16* oh = y1;  // reuse: y1 dead after k_xa_qkv
  float* attg = (float*)y1; // scratch before y1 is written (16*384*625*4 = 15.4MB)

  k_gcn_att1<<<dim3(NCHUNK, N_*S_), 256, 0, stream>>>(x, Wq, bq, Wk, bk, attg);
  k_gcn_att2<<<N_*S_, 256, 0, stream>>>(attg, A, alphap, Aad);
  k_gcn_y<<<dim3(T_/4, N_), 256, 0, stream>>>(x, Aad, Wf, bfp, g_gamma, g_beta, y1);
  k_seT<<<dim3(C_, N_), 256, 0, stream>>>(y1, seT);
  k_sa<<<N_, 64, 0, stream>>>(seT, W_sa, b_sa, sa);
  k_seV<<<dim3(C_, N_), 256, 0, stream>>>(y1, sa, seV);
  k_ta_ca<<<N_, 128, 0, stream>>>(seV, W_ta, b_ta, W_fc1, b_fc1, W_fc2, b_fc2, ta, ca);
  k_xa_qkv<<<dim3(T_/4, N_), 256, 0, stream>>>(y1, pos_emb, sa, ta, ca,
      Wq_h, bq_h, Wk_h, bk_h, Wv_h, bv_h, xa, qb, kb, vb);
  k_attn<<<dim3(2, H_, N_), 256, 0, stream>>>(qb, kb, vb, oh);
  k_out<<<dim3(T_/8, N_), 256, 0, stream>>>(oh, xa, x, W_ffn, b_ffn, m_gamma, m_beta, out);
}

// Round 13
// 577.740 us; speedup vs baseline: 1.3323x; 1.2616x over previous
//
#include <hip/hip_runtime.h>
#include <hip/hip_bf16.h>

#define N_ 128
#define C_ 64
#define T_ 128
#define V_ 25
#define S_ 3
#define IG 16
#define IH 8
#define H_ 8
#define D_ 200   // IH*V
#define CV 1600  // C_*V_
#define TV 3200  // T_*V_
#define EPSB 1e-5f
#define NCHUNK 16
#define TPC 8    // t per chunk (k_gcn_att1)

typedef __attribute__((ext_vector_type(8))) short short8v;
typedef __attribute__((ext_vector_type(4))) float f32x4;
#define MFMA16 __builtin_amdgcn_mfma_f32_16x16x32_bf16
// zT column swizzle keyed on row bits that vary across staging lanes
#define ZIDX(r,c) ((r)*72 + ((c) ^ ((((r)>>3)&7)<<3)))

__device__ __forceinline__ float sigm(float x){ return 1.f/(1.f+expf(-x)); }
__device__ __forceinline__ float b2f(__hip_bfloat16 b){ return __bfloat162float(b); }
__device__ __forceinline__ __hip_bfloat16 f2b(float f){ return __float2bfloat16(f); }
__device__ __forceinline__ float ubl(unsigned int u){ return __uint_as_float(u<<16); }
__device__ __forceinline__ float ubh(unsigned int u){ return __uint_as_float(u & 0xffff0000u); }
__device__ __forceinline__ unsigned short f2bu(float f){
  unsigned int u = __float_as_uint(f);
  u += 0x7fff + ((u>>16)&1);
  return (unsigned short)(u>>16);
}
__device__ __forceinline__ unsigned long long pk4bf(f32x4 v){
  unsigned long long a = f2bu(v[0]);
  unsigned long long b = f2bu(v[1]);
  unsigned long long c = f2bu(v[2]);
  unsigned long long d = f2bu(v[3]);
  return a | (b<<16) | (c<<32) | (d<<48);
}

// ---------------- K1a: MFMA adaptive graph attention partials ----------------
__global__ __launch_bounds__(256) void k_gcn_att1(
    const float* __restrict__ x,
    const float* __restrict__ Wq, const float* __restrict__ bq,
    const float* __restrict__ Wk, const float* __restrict__ bk,
    float* __restrict__ attg)
{
  const int tc = blockIdx.x, ns = blockIdx.y, n = ns / S_, s = ns % S_;
  const int tid = threadIdx.x;
  const int wv = tid>>6, l = tid&63, lc = l&15, lk = l>>4;
  __shared__ __align__(16) short wql[16*72], wkl[16*72];
  __shared__ float bql[16], bkl[16];
  __shared__ __align__(16) short xtb[4*32*72];   // [tl][v(32)][c(72)], v>=25 zeroed
  __shared__ __align__(16) char QB[32*256];      // [v][K=128 bf16], byte^=(v&7)<<4
  __shared__ __align__(16) char KB[32*256];
  for (int i=tid;i<IG*C_;i+=256){
    int ii=i>>6, c=i&63;
    wql[ii*72+c] = (short)f2bu(Wq[s*IG*C_+i]);
    wkl[ii*72+c] = (short)f2bu(Wk[s*IG*C_+i]);
  }
  if (tid<16){ bql[tid]=bq[s*IG+tid]; bkl[tid]=bk[s*IG+tid]; }
  for (int i=tid;i<4*7*72;i+=256){
    int tl=i/(7*72), r=i%(7*72);
    xtb[(tl*32+25)*72 + r] = 0;
  }
  const float* xn = x + (size_t)n*C_*T_*V_;
  const int t0 = tc*TPC;
  #pragma unroll
  for (int tg=0; tg<2; ++tg){
    __syncthreads();
    for (int i=tid;i<4*1600;i+=256){
      int tl=i/1600, r=i%1600, c=r/25, v=r%25;
      xtb[(tl*32+v)*72 + c] = (short)f2bu(xn[(size_t)c*TV + (t0+tg*4+tl)*V_ + v]);
    }
    __syncthreads();
    const int tcol = (tg*4+wv)*32;
    f32x4 z={0.f,0.f,0.f,0.f};
    f32x4 aq0=z,aq1=z,ak0=z,ak1=z;
    #pragma unroll
    for (int ks=0;ks<2;++ks){
      short8v aq = *(const short8v*)(wql + lc*72 + ks*32 + lk*8);
      short8v ak = *(const short8v*)(wkl + lc*72 + ks*32 + lk*8);
      short8v b0 = *(const short8v*)(xtb + (wv*32+lc)*72 + ks*32 + lk*8);
      short8v b1 = *(const short8v*)(xtb + (wv*32+16+lc)*72 + ks*32 + lk*8);
      aq0 = MFMA16(aq,b0,aq0,0,0,0);
      aq1 = MFMA16(aq,b1,aq1,0,0,0);
      ak0 = MFMA16(ak,b0,ak0,0,0,0);
      ak1 = MFMA16(ak,b1,ak1,0,0,0);
    }
    f32x4 q0,q1,k0,k1;
    #pragma unroll
    for (int r=0;r<4;++r){
      float bqv = bql[lk*4+r], bkv = bkl[lk*4+r];
      q0[r]=aq0[r]+bqv; q1[r]=aq1[r]+bqv;
      k0[r]=ak0[r]+bkv; k1[r]=ak1[r]+bkv;
    }
    const int sw = (lc&7)<<4;
    *(unsigned long long*)(QB + ((lc*256      + tcol + lk*8) ^ sw)) = pk4bf(q0);
    *(unsigned long long*)(QB + (((16+lc)*256 + tcol + lk*8) ^ sw)) = pk4bf(q1);
    *(unsigned long long*)(KB + ((lc*256      + tcol + lk*8) ^ sw)) = pk4bf(k0);
    *(unsigned long long*)(KB + (((16+lc)*256 + tcol + lk*8) ^ sw)) = pk4bf(k1);
  }
  __syncthreads();
  const int mt = wv>>1, nt = wv&1;
  const int sw = (lc&7)<<4;
  f32x4 acc = {0.f,0.f,0.f,0.f};
  #pragma unroll
  for (int ks=0;ks<4;++ks){
    short8v a = *(const short8v*)(QB + (((mt*16+lc)*256 + ks*64 + lk*16) ^ sw));
    short8v b = *(const short8v*)(KB + (((nt*16+lc)*256 + ks*64 + lk*16) ^ sw));
    acc = MFMA16(a,b,acc,0,0,0);
  }
  float* Ao = attg + ((size_t)tc*(N_*S_) + ns)*(V_*V_);
  #pragma unroll
  for (int reg=0;reg<4;++reg){
    int v = mt*16 + lk*4 + reg, w = nt*16 + lc;
    if (v<V_ && w<V_) Ao[v*V_+w] = acc[reg];
  }
}

// ---------------- K1b: reduce chunks + softmax(dim=-2) + Aad ----------------
__global__ __launch_bounds__(256) void k_gcn_att2(
    const float* __restrict__ attg, const float* __restrict__ A,
    const float* __restrict__ alphap, float* __restrict__ Aad)
{
  const int ns = blockIdx.x, s = ns % S_, tid = threadIdx.x;
  __shared__ float att[V_*V_];
  for (int i=tid;i<V_*V_;i+=256){
    float acc=0.f;
    #pragma unroll
    for (int tcc=0;tcc<NCHUNK;++tcc) acc += attg[((size_t)tcc*(N_*S_) + ns)*(V_*V_) + i];
    att[i]=acc;
  }
  __syncthreads();
  if (tid<V_){
    const int w=tid; const float inv=1.f/(IG*T_);
    float mx=-1e30f;
    for (int v=0;v<V_;++v) mx=fmaxf(mx, att[v*V_+w]*inv);
    float sum=0.f;
    for (int v=0;v<V_;++v){ float e=expf(att[v*V_+w]*inv-mx); att[v*V_+w]=e; sum+=e; }
    float rs=1.f/sum;
    for (int v=0;v<V_;++v) att[v*V_+w]*=rs;
  }
  __syncthreads();
  const float alpha=alphap[0];
  float* Ao = Aad + (size_t)ns*V_*V_;
  for (int i=tid;i<V_*V_;i+=256) Ao[i]=A[s*V_*V_+i]+alpha*att[i];
}

// ---------------- K2: 4-t tile MFMA graph conv + Wf + bn + residual + relu ----------------
__global__ __launch_bounds__(256) void k_gcn_y(
    const float* __restrict__ x, const float* __restrict__ Aad,
    const float* __restrict__ Wf, const float* __restrict__ bfp,
    const float* __restrict__ g_gamma, const float* __restrict__ g_beta,
    __hip_bfloat16* __restrict__ y1)
{
  const int tc=blockIdx.x, n=blockIdx.y, tid=threadIdx.x;
  const int wv=tid>>6, l=tid&63, lc=l&15, lk=l>>4;
  __shared__ __align__(16) short xtb[64*136];   // [c][t*32+v], v-pad zeroed
  __shared__ __align__(16) short AsT[3*32*40];  // [s][w][v], v-pad zeroed
  __shared__ __align__(16) short aggT[112*200]; // [tv][sc], rows 100..111 zeroed
  const float* xn = x + (size_t)n*C_*TV;
  const int tv0 = tc*100;
  float4 xbuf[7];
  #pragma unroll
  for (int k=0;k<7;++k){
    int i = tid + k*256;
    if (i < 1600){
      int c=i/25, a=i%25;
      xbuf[k] = *(const float4*)(xn + (size_t)c*TV + tv0 + a*4);
    }
  }
  #pragma unroll
  for (int k=0;k<7;++k){
    int i = tid + k*256;
    if (i < 1600){
      int c=i/25, a=i%25, tv4=a*4;
      float xv[4] = {xbuf[k].x, xbuf[k].y, xbuf[k].z, xbuf[k].w};
      #pragma unroll
      for (int j=0;j<4;++j){
        int tv=tv4+j, t=tv/25, v=tv-t*25;
        xtb[c*136 + t*32 + v] = (short)f2bu(xv[j]);
      }
    }
  }
  for (int i=tid;i<64*28;i+=256){ int c=i/28, r=i%28; xtb[c*136 + (r/7)*32 + 25 + (r%7)] = 0; }
  for (int i=tid;i<3*32*7;i+=256){ int sw_=i/7; AsT[sw_*40 + 25 + (i%7)] = 0; }
  const float* Adn = Aad + (size_t)n*S_*V_*V_;
  for (int i=tid;i<S_*V_*V_;i+=256){
    int s=i/625, r=i%625, v=r/25, w=r%25;
    AsT[(s*32+w)*40+v] = (short)f2bu(Adn[i]);
  }
  for (int i=tid;i<12*200;i+=256) aggT[100*200+i]=0;
  __syncthreads();
  {
    const int t = wv;
    for (int s=0;s<S_;++s){
      short8v b0 = *(const short8v*)(AsT + (s*32+lc)*40 + lk*8);
      short8v b1 = *(const short8v*)(AsT + (s*32+16+lc)*40 + lk*8);
      #pragma unroll
      for (int mt=0;mt<4;++mt){
        short8v a = *(const short8v*)(xtb + (mt*16+lc)*136 + t*32 + lk*8);
        f32x4 z={0.f,0.f,0.f,0.f};
        f32x4 acc0 = MFMA16(a,b0,z,0,0,0);
        f32x4 acc1 = MFMA16(a,b1,z,0,0,0);
        *(unsigned long long*)(aggT + (t*25+lc)*200 + s*64 + mt*16 + lk*4) = pk4bf(acc0);
        if (lc<9)
          *(unsigned long long*)(aggT + (t*25+16+lc)*200 + s*64 + mt*16 + lk*4) = pk4bf(acc1);
      }
    }
  }
  short8v af[6];
  #pragma unroll
  for (int ks=0;ks<6;++ks){
    const int s = ks>>1, c0 = (ks&1)*32 + lk*8;
    const float* wr = Wf + ((size_t)s*C_ + wv*16+lc)*C_ + c0;
    short8v t8;
    #pragma unroll
    for (int j=0;j<8;++j) t8[j] = (short)f2bu(wr[j]);
    af[ks]=t8;
  }
  __syncthreads();
  f32x4 acc[7];
  #pragma unroll
  for (int dt=0;dt<7;++dt) acc[dt]=(f32x4){0.f,0.f,0.f,0.f};
  #pragma unroll
  for (int dt=0;dt<7;++dt){
    #pragma unroll
    for (int ks=0;ks<6;++ks){
      short8v b = *(const short8v*)(aggT + (dt*16+lc)*200 + ks*32 + lk*8);
      acc[dt] = MFMA16(af[ks], b, acc[dt],0,0,0);
    }
  }
  const float invs = rsqrtf(1.f+EPSB);
  __hip_bfloat16* yo = y1 + (size_t)n*C_*TV;
  #pragma unroll
  for (int reg=0;reg<4;++reg){
    const int o = wv*16 + lk*4 + reg;
    const float bsum = bfp[o]+bfp[C_+o]+bfp[2*C_+o];
    const float gs = g_gamma[o]*invs, gb = g_beta[o];
    #pragma unroll
    for (int dt=0;dt<7;++dt){
      const int tv = dt*16 + lc;
      if (tv < 100){
        float val = (acc[dt][reg]+bsum)*gs + gb + xn[(size_t)o*TV + tv0 + tv];
        yo[(size_t)o*TV + tv0 + tv] = f2b(fmaxf(val,0.f));
      }
    }
  }
}

// ---------------- K3a: seT[n,c,v] = mean_t y1 ----------------
__global__ __launch_bounds__(256) void k_seT(const __hip_bfloat16* __restrict__ y1,
    float* __restrict__ seT)
{
  const int c=blockIdx.x, n=blockIdx.y, tid=threadIdx.x;
  const int v = tid&31, g = tid>>5;
  __shared__ float red[8][33];
  const __hip_bfloat16* yp = y1 + ((size_t)n*C_+c)*T_*V_;
  float s=0.f;
  if (v < V_){
    #pragma unroll 4
    for (int j=0;j<16;++j){
      int t = g + j*8;
      s += b2f(yp[t*V_+v]);
    }
  }
  red[g][v]=s;
  __syncthreads();
  if (tid < V_){
    float tot=0.f;
    #pragma unroll
    for (int g2=0;g2<8;++g2) tot += red[g2][tid];
    seT[((size_t)n*C_+c)*V_+tid]=tot*(1.f/T_);
  }
}

// ---------------- K3b: sa[n,v] spatial gate (LDS-staged, c-split) ----------------
__global__ __launch_bounds__(256) void k_sa(const float* __restrict__ seT,
    const float* __restrict__ W_sa, const float* __restrict__ b_sa,
    float* __restrict__ sa)
{
  const int n=blockIdx.x, tid=threadIdx.x;
  __shared__ float sel[CV];
  __shared__ float wsl[CV];
  __shared__ float part[8][32];
  const float* se = seT + (size_t)n*C_*V_;
  for (int i=tid;i<CV;i+=256){ sel[i]=se[i]; wsl[i]=W_sa[i]; }
  __syncthreads();
  if (tid < 200){
    const int v = tid%25, cg = tid/25;
    float acc=0.f;
    for (int c=cg*8;c<cg*8+8;++c){
      #pragma unroll
      for (int k=0;k<V_;++k){
        int vv=v+k-12;  // pad = 12
        if (vv>=0&&vv<V_) acc += sel[c*V_+vv]*wsl[c*V_+k];
      }
    }
    part[cg][v]=acc;
  }
  __syncthreads();
  if (tid<V_){
    float acc=b_sa[0];
    #pragma unroll
    for (int g=0;g<8;++g) acc+=part[g][tid];
    sa[n*V_+tid]=sigm(acc);
  }
}

// ---------------- K3c: seV[n,c,t] = mean_v y1*(1+sa) ----------------
__global__ __launch_bounds__(256) void k_seV(const __hip_bfloat16* __restrict__ y1,
    const float* __restrict__ sa, float* __restrict__ seV)
{
  const int c=blockIdx.x, n=blockIdx.y, tid=threadIdx.x;
  const int v = tid&31, g = tid>>5;
  __shared__ float sal[32];
  if (tid<32) sal[tid] = (tid<V_)? 1.f+sa[n*V_+tid] : 0.f;
  __syncthreads();
  const __hip_bfloat16* yp = y1 + ((size_t)n*C_+c)*T_*V_;
  float* svo = seV + ((size_t)n*C_+c)*T_;
  const float sv_ = sal[v];
  for (int j=0;j<16;++j){
    int t = g*16 + j;
    float val = (v<V_)? b2f(yp[t*V_+v])*sv_ : 0.f;
    #pragma unroll
    for (int off=16;off;off>>=1) val += __shfl_xor(val, off);
    if (v==0) svo[t]=val*(1.f/V_);
  }
}

// ---------------- K3d: ta + ca gates (LDS-staged, split reductions) ----------------
__global__ __launch_bounds__(256) void k_ta_ca(const float* __restrict__ seV,
    const float* __restrict__ W_ta, const float* __restrict__ b_ta,
    const float* __restrict__ W_fc1, const float* __restrict__ b_fc1,
    const float* __restrict__ W_fc2, const float* __restrict__ b_fc2,
    float* __restrict__ ta, float* __restrict__ ca)
{
  const int n=blockIdx.x, tid=threadIdx.x;
  __shared__ float svl[C_*T_];       // 32 KB
  __shared__ float wtl[C_*9];
  __shared__ float w1l[32*C_];       // 8 KB
  __shared__ float w2l[C_*32];       // 8 KB
  __shared__ float tal[T_];
  __shared__ float part2[2][T_];
  __shared__ float part4[C_][4];
  __shared__ float scls[C_];
  __shared__ float h1[32];
  const float* sv = seV + (size_t)n*C_*T_;
  for (int i=tid;i<C_*T_;i+=256) svl[i]=sv[i];
  for (int i=tid;i<C_*9;i+=256) wtl[i]=W_ta[i];
  for (int i=tid;i<32*C_;i+=256){ w1l[i]=W_fc1[i]; w2l[i]=W_fc2[i]; }
  __syncthreads();
  // ---- ta: thread = half*128 + t, each sums 32 c's ----
  {
    const int t = tid & 127, half = tid >> 7;
    float acc = 0.f;
    for (int c=half*32; c<half*32+32; ++c){
      #pragma unroll
      for (int k=0;k<9;++k){
        int tt=t+k-4;
        if (tt>=0&&tt<T_) acc += svl[c*T_+tt]*wtl[c*9+k];
      }
    }
    part2[half][t]=acc;
  }
  __syncthreads();
  if (tid<T_){
    float s_=sigm(part2[0][tid]+part2[1][tid]+b_ta[0]);
    tal[tid]=s_; ta[n*T_+tid]=s_;
  }
  __syncthreads();
  // ---- scl: thread = c*4+q, each sums 32 t's ----
  {
    const int c = tid>>2, q = tid&3;
    float acc=0.f;
    for (int t=q*32;t<q*32+32;++t) acc += svl[c*T_+t]*(1.f+tal[t]);
    part4[c][q]=acc;
  }
  __syncthreads();
  if (tid<C_) scls[tid]=(part4[tid][0]+part4[tid][1]+part4[tid][2]+part4[tid][3])*(1.f/T_);
  __syncthreads();
  if (tid<32){
    float acc=b_fc1[tid];
    for (int c=0;c<C_;++c) acc += scls[c]*w1l[tid*C_+c];
    h1[tid]=fmaxf(acc,0.f);
  }
  __syncthreads();
  if (tid<C_){
    float acc=b_fc2[tid];
    for (int j=0;j<32;++j) acc += h1[j]*w2l[tid*32+j];
    ca[n*C_+tid]=sigm(acc);
  }
}

// ---------------- K4: 4-t tile MFMA xa/gates + q/k/v projections ----------------
__global__ __launch_bounds__(256) void k_xa_qkv(
    const __hip_bfloat16* __restrict__ y1, const float* __restrict__ pos_emb,
    const float* __restrict__ sa, const float* __restrict__ ta, const float* __restrict__ ca,
    const float* __restrict__ Wq_h, const float* __restrict__ bq_h,
    const float* __restrict__ Wk_h, const float* __restrict__ bk_h,
    const float* __restrict__ Wv_h, const float* __restrict__ bv_h,
    __hip_bfloat16* __restrict__ xa, __hip_bfloat16* __restrict__ qb,
    __hip_bfloat16* __restrict__ kb, __hip_bfloat16* __restrict__ vb)
{
  const int tc=blockIdx.x, n=blockIdx.y, tid=threadIdx.x;
  const int wv=tid>>6, l=tid&63, lc=l&15, lk=l>>4;
  __shared__ __align__(16) short w3[192*72];      // [mu][c], mu = which*64+ho
  __shared__ __align__(16) short xalT[4][32*72];  // per t: [v][c], v>=25 zeroed
  __shared__ float bl[192];
  __shared__ float sal[32], cal[64], tgs[4];
  const int tv0 = tc*100;
  const __hip_bfloat16* y1n = y1 + (size_t)n*C_*TV;
  __hip_bfloat16* xan = xa + (size_t)n*C_*TV;
  uint2 ybuf[7];
  #pragma unroll
  for (int k=0;k<7;++k){
    int i = tid + k*256;
    if (i < 1600){
      int c=i/25, a=i%25;
      ybuf[k] = *(const uint2*)(y1n + (size_t)c*TV + tv0 + a*4);
    }
  }
  for (int i=tid;i<192*64;i+=256){
    int mu=i>>6, c=i&63, which=mu/C_, ho=mu%C_;
    const float* W = which==0?Wq_h:(which==1?Wk_h:Wv_h);
    w3[mu*72+c] = (short)f2bu(W[(size_t)ho*C_+c]);
  }
  if (tid<192){
    int which=tid/C_, ho=tid%C_;
    bl[tid] = (which==0?bq_h:(which==1?bk_h:bv_h))[ho];
  }
  if (tid<32) sal[tid] = (tid<V_)? 1.f+sa[n*V_+tid] : 0.f;
  if (tid>=32 && tid<96) cal[tid-32] = 1.f+ca[n*C_+tid-32];
  if (tid>=96 && tid<100) tgs[tid-96] = 1.f+ta[n*T_+tc*4+(tid-96)];
  for (int i=tid;i<4*7*72;i+=256){
    int tl=i/(7*72), r=i%(7*72);
    xalT[tl][25*72 + r] = 0;
  }
  __syncthreads();
  #pragma unroll
  for (int k=0;k<7;++k){
    int i = tid + k*256;
    if (i < 1600){
      int c=i/25, a=i%25, tv4=a*4;
      unsigned int u0=ybuf[k].x, u1=ybuf[k].y;
      float yv[4] = {ubl(u0),ubh(u0),ubl(u1),ubh(u1)};
      const float calc = cal[c];
      unsigned long long pack = 0ull;
      #pragma unroll
      for (int j=0;j<4;++j){
        int tv=tv4+j, tl=tv/25, v=tv-tl*25;
        float val = yv[j]*sal[v]*tgs[tl]*calc + pos_emb[(size_t)(tc*4+tl)*CV + c*V_ + v];
        unsigned short b = f2bu(val);
        pack |= (unsigned long long)b << (16*j);
        xalT[tl][v*72 + c] = (short)b;
      }
      *(unsigned long long*)(xan + (size_t)c*TV + tv0 + tv4) = pack;
    }
  }
  __syncthreads();
  const int t = tc*4 + wv;
  short8v bf_[2][2];
  #pragma unroll
  for (int ks=0;ks<2;++ks){
    bf_[ks][0] = *(const short8v*)(&xalT[wv][lc*72      + ks*32 + lk*8]);
    bf_[ks][1] = *(const short8v*)(&xalT[wv][(16+lc)*72 + ks*32 + lk*8]);
  }
  #pragma unroll
  for (int mt=0;mt<12;++mt){
    f32x4 acc0 = {0.f,0.f,0.f,0.f}, acc1 = {0.f,0.f,0.f,0.f};
    #pragma unroll
    for (int ks=0;ks<2;++ks){
      short8v a = *(const short8v*)(w3 + (mt*16+lc)*72 + ks*32 + lk*8);
      acc0 = MFMA16(a, bf_[ks][0], acc0,0,0,0);
      acc1 = MFMA16(a, bf_[ks][1], acc1,0,0,0);
    }
    #pragma unroll
    for (int reg=0;reg<4;++reg){
      const int mu = mt*16 + lk*4 + reg;
      const int which = mt>>2;
      const int ho = mu & 63, h = ho>>3, o = ho&7;
      __hip_bfloat16* dst = (which==0?qb:(which==1?kb:vb))
                            + (((size_t)n*H_+h)*T_+t)*D_ + o*V_;
      const float bb = bl[mu];
      dst[lc] = f2b(acc0[reg]+bb);
      if (lc < 9) dst[16+lc] = f2b(acc1[reg]+bb);
    }
  }
}

// ---------------- K5: MFMA flash causal MHA ----------------
// oh written in (n, c, t, v) layout (c = h*8 + d/25, v = d%25).
__global__ __launch_bounds__(256) void k_attn(
    const __hip_bfloat16* __restrict__ qb, const __hip_bfloat16* __restrict__ kb,
    const __hip_bfloat16* __restrict__ vb, __hip_bfloat16* __restrict__ oh)
{
  const int bx = blockIdx.x;
  const int hh = blockIdx.y;
  const int n  = blockIdx.z;
  const int nh = n*H_ + hh;
  const int tid = threadIdx.x;
  const int wv = tid>>6, l = tid&63;
  const int lc = l&15, lg = l>>4;
  __shared__ __align__(16) char KlB[32*512];      // [key][d(256sh)] bf16, byte^=(key&7)<<4
  __shared__ __align__(16) short VT[208*40];      // [d][key] bf16
  __shared__ __align__(16) short Pl[64*40];       // [qloc][key] bf16 (per-wave slices)
  const __hip_bfloat16* qg_ = qb + (size_t)nh*T_*D_;
  const __hip_bfloat16* kg_ = kb + (size_t)nh*T_*D_;
  const __hip_bfloat16* vg_ = vb + (size_t)nh*T_*D_;
  __hip_bfloat16* ohn = oh + (size_t)n*C_*TV;     // (n,c,t,v) layout
  const float scale = 0.0707106781f;  // 1/sqrt(200)

  for (int i=tid;i<32*12;i+=256){
    int key=i/12, j=i%12;
    *(unsigned int*)(KlB + ((key*512 + 400 + j*4) ^ ((key&7)<<4))) = 0u;
  }
  for (int i=tid;i<8*40;i+=256) VT[200*40 + i] = 0;

  const int qrow = bx*64 + wv*16 + lc;
  short8v qf[7];
  {
    const short8v* qs8 = (const short8v*)(qg_ + (size_t)qrow*D_);
    #pragma unroll
    for (int ks=0;ks<7;++ks) qf[ks] = qs8[ks*4 + lg];
  }
  f32x4 oacc[13];
  #pragma unroll
  for (int i=0;i<13;++i) oacc[i] = (f32x4){0.f,0.f,0.f,0.f};
  float m[4], lsm[4];
  #pragma unroll
  for (int r=0;r<4;++r){ m[r]=-1e30f; lsm[r]=0.f; }

  const int ntiles = (bx==0)? 2 : 4;
  for (int kt=0; kt<ntiles; ++kt){
    const int j0 = kt*32;
    __syncthreads();
    {
      const short8v* ks8 = (const short8v*)(kg_ + (size_t)j0*D_);
      for (int i=tid;i<32*25;i+=256){
        int row=i/25, w=i%25;
        *(short8v*)(KlB + ((row*512 + w*16) ^ ((row&7)<<4))) = ks8[i];
      }
      const short8v* vs8 = (const short8v*)(vg_ + (size_t)j0*D_);
      for (int i=tid;i<32*25;i+=256){
        int row=i&31, w4=i>>5;
        short8v u = vs8[row*25 + w4];
        #pragma unroll
        for (int j=0;j<8;++j) VT[(w4*8+j)*40 + row] = u[j];
      }
    }
    __syncthreads();
    const bool active = (j0 <= bx*64 + wv*16 + 15);
    if (active){
      f32x4 s0 = {0.f,0.f,0.f,0.f}, s1 = {0.f,0.f,0.f,0.f};
      #pragma unroll
      for (int ks=0;ks<7;++ks){
        short8v b0 = *(const short8v*)(KlB + ((lc*512      + ks*64 + lg*16) ^ ((lc&7)<<4)));
        short8v b1 = *(const short8v*)(KlB + (((16+lc)*512 + ks*64 + lg*16) ^ ((lc&7)<<4)));
        s0 = MFMA16(qf[ks], b0, s0,0,0,0);
        s1 = MFMA16(qf[ks], b1, s1,0,0,0);
      }
      float fr[4];
      #pragma unroll
      for (int r=0;r<4;++r){
        const int qg = bx*64 + wv*16 + lg*4 + r;
        float v0 = (j0+lc    <= qg) ? s0[r]*scale : -1e30f;
        float v1 = (j0+16+lc <= qg) ? s1[r]*scale : -1e30f;
        float mx = fmaxf(v0,v1);
        #pragma unroll
        for (int off=1;off<16;off<<=1) mx = fmaxf(mx, __shfl_xor(mx, off));
        float mn = fmaxf(m[r], mx);
        fr[r] = __expf(m[r]-mn);
        float p0 = __expf(v0-mn), p1 = __expf(v1-mn);
        float ts = p0+p1;
        #pragma unroll
        for (int off=1;off<16;off<<=1) ts += __shfl_xor(ts, off);
        lsm[r] = lsm[r]*fr[r] + ts;
        m[r] = mn;
        Pl[(wv*16 + lg*4 + r)*40 + lc]      = (short)f2bu(p0);
        Pl[(wv*16 + lg*4 + r)*40 + 16 + lc] = (short)f2bu(p1);
      }
      #pragma unroll
      for (int dt=0;dt<13;++dt){
        #pragma unroll
        for (int r=0;r<4;++r) oacc[dt][r] *= fr[r];
      }
      short8v pa = *(const short8v*)(Pl + (wv*16+lc)*40 + lg*8);
      #pragma unroll
      for (int dt=0;dt<13;++dt){
        short8v b = *(const short8v*)(VT + (dt*16+lc)*40 + lg*8);
        oacc[dt] = MFMA16(pa, b, oacc[dt],0,0,0);
      }
    }
  }
  float rl[4];
  #pragma unroll
  for (int r=0;r<4;++r) rl[r] = 1.f/lsm[r];
  #pragma unroll
  for (int dt=0;dt<13;++dt){
    const int d = dt*16 + lc;
    if (d < D_){
      const int oi = d/25, v = d - oi*25;
      const int c = hh*IH + oi;
      #pragma unroll
      for (int r=0;r<4;++r){
        const int q = bx*64 + wv*16 + lg*4 + r;
        ohn[(size_t)c*TV + q*V_ + v] = f2b(oacc[dt][r]*rl[r]);
      }
    }
  }
}

// ---------------- K7: 8-t tile MFMA out kernel (MLP-batched staging + swizzled zT) ----------------
__global__ __launch_bounds__(256) void k_out(
    const __hip_bfloat16* __restrict__ oh, const __hip_bfloat16* __restrict__ xa,
    const float* __restrict__ x, const float* __restrict__ W_ffn,
    const float* __restrict__ b_ffn, const float* __restrict__ m_gamma,
    const float* __restrict__ m_beta, float* __restrict__ out)
{
  const int tc = blockIdx.x, n = blockIdx.y, tid = threadIdx.x;
  const int wv = tid>>6, l = tid&63, lc = l&15, lg = l>>4;
  __shared__ __align__(16) short zT[208*72];   // z^T bf16, swizzled cols, rows 200..207 zeroed
  __shared__ float bn_s[64], bn_b[64], bff[64];
  const float invs = rsqrtf(1.f+EPSB);
  if (tid<64){ bn_s[tid]=m_gamma[tid]*invs; bn_b[tid]=m_beta[tid]; bff[tid]=b_ffn[tid]; }
  for (int i=tid;i<8*72;i+=256) zT[200*72+i]=0;
  const int tv0 = tc*200;
  const __hip_bfloat16* xan = xa + (size_t)n*C_*TV;
  const __hip_bfloat16* ohn = oh + (size_t)n*C_*TV;
  uint4 xbuf[7], obuf[7];
  #pragma unroll
  for (int k=0;k<7;++k){
    int i = tid + k*256;
    if (i < 1600){
      int c=i/25, a=i%25;
      xbuf[k] = *(const uint4*)(xan + (size_t)c*TV + tv0 + a*8);
      obuf[k] = *(const uint4*)(ohn + (size_t)c*TV + tv0 + a*8);
    }
  }
  __syncthreads();   // bn_s ready
  #pragma unroll
  for (int k=0;k<7;++k){
    int i = tid + k*256;
    if (i < 1600){
      int c=i/25, a=i%25, tv8=a*8;
      const float s_=bn_s[c], b_=bn_b[c];
      const unsigned int* xu = (const unsigned int*)&xbuf[k];
      const unsigned int* ou = (const unsigned int*)&obuf[k];
      #pragma unroll
      for (int j=0;j<4;++j){
        zT[ZIDX(tv8+2*j,   c)] = (short)f2bu(s_*ubl(ou[j]) + b_ + ubl(xu[j]));
        zT[ZIDX(tv8+2*j+1, c)] = (short)f2bu(s_*ubh(ou[j]) + b_ + ubh(xu[j]));
      }
    }
  }
  __syncthreads();
  short8v af0, af1;
  {
    const float* wr = W_ffn + (size_t)(wv*16+lc)*C_ + lg*8;
    #pragma unroll
    for (int j=0;j<8;++j){ af0[j]=(short)f2bu(wr[j]); af1[j]=(short)f2bu(wr[32+j]); }
  }
  f32x4 acc[13];
  #pragma unroll
  for (int dt=0;dt<13;++dt) acc[dt] = (f32x4){0.f,0.f,0.f,0.f};
  #pragma unroll
  for (int dt=0;dt<13;++dt){
    short8v b0 = *(const short8v*)(zT + ZIDX(dt*16+lc, lg*8));
    short8v b1 = *(const short8v*)(zT + ZIDX(dt*16+lc, 32+lg*8));
    acc[dt] = MFMA16(af0, b0, acc[dt],0,0,0);
    acc[dt] = MFMA16(af1, b1, acc[dt],0,0,0);
  }
  const float* xn = x + (size_t)n*C_*TV;
  float* outn = out + (size_t)n*C_*TV;
  #pragma unroll
  for (int dt=0;dt<13;++dt){
    const int tv = dt*16 + lc;
    if (tv < 200){
      #pragma unroll
      for (int reg=0;reg<4;++reg){
        const int o = wv*16 + lg*4 + reg;
        float z2 = fmaxf(acc[dt][reg] + bff[o], 0.f) + b2f(xan[(size_t)o*TV + tv0 + tv]);
        float z3 = bn_s[o]*z2 + bn_b[o];
        outn[(size_t)o*TV + tv0 + tv] = fmaxf(z3 + xn[(size_t)o*TV + tv0 + tv], 0.f);
      }
    }
  }
}

extern "C" void kernel_launch(void* const* d_in, const int* in_sizes, int n_in,
                              void* d_out, int out_size, void* d_ws, size_t ws_size,
                              hipStream_t stream) {
  const float* x      = (const float*)d_in[0];
  const float* A      = (const float*)d_in[1];
  const float* alphap = (const float*)d_in[2];
  const float* Wq     = (const float*)d_in[3];
  const float* bq     = (const float*)d_in[4];
  const float* Wk     = (const float*)d_in[5];
  const float* bk     = (const float*)d_in[6];
  const float* Wf     = (const float*)d_in[7];
  const float* bfp    = (const float*)d_in[8];
  const float* g_gamma= (const float*)d_in[9];
  const float* g_beta = (const float*)d_in[10];
  const float* W_sa   = (const float*)d_in[11];
  const float* b_sa   = (const float*)d_in[12];
  const float* W_ta   = (const float*)d_in[13];
  const float* b_ta   = (const float*)d_in[14];
  const float* W_fc1  = (const float*)d_in[15];
  const float* b_fc1  = (const float*)d_in[16];
  const float* W_fc2  = (const float*)d_in[17];
  const float* b_fc2  = (const float*)d_in[18];
  const float* pos_emb= (const float*)d_in[19];
  const float* Wq_h   = (const float*)d_in[20];
  const float* bq_h   = (const float*)d_in[21];
  const float* Wk_h   = (const float*)d_in[22];
  const float* bk_h   = (const float*)d_in[23];
  const float* Wv_h   = (const float*)d_in[24];
  const float* bv_h   = (const float*)d_in[25];
  const float* W_ffn  = (const float*)d_in[26];
  const float* b_ffn  = (const float*)d_in[27];
  const float* m_gamma= (const float*)d_in[28];
  const float* m_beta = (const float*)d_in[29];
  float* out = (float*)d_out;

  float* ws   = (float*)d_ws;
  float* Aad  = ws;                    // 128*3*625   = 240000
  float* seT  = Aad + 240000;          // 128*64*25   = 204800
  float* seV  = seT + 204800;          // 128*64*128  = 1048576
  float* sa   = seV + 1048576;         // 128*25      = 3200
  float* ta   = sa  + 3200;            // 128*128     = 16384
  float* ca   = ta  + 16384;           // 128*64      = 8192
  __hip_bfloat16* y1 = (__hip_bfloat16*)(ca + 8192);  // 26214400 elems (reused as oh)
  __hip_bfloat16* xa = y1 + (size_t)26214400;
  __hip_bfloat16* qb = xa + (size_t)26214400;
  __hip_bfloat16* kb = qb + (size_t)26214400;
  __hip_bfloat16* vb = kb + (size_t)26214400;
  __hip_bfloat16* oh = y1;  // reuse: y1 dead after k_xa_qkv
  float* attg = (float*)y1; // scratch before y1 is written (16*384*625*4 = 15.4MB)

  k_gcn_att1<<<dim3(NCHUNK, N_*S_), 256, 0, stream>>>(x, Wq, bq, Wk, bk, attg);
  k_gcn_att2<<<N_*S_, 256, 0, stream>>>(attg, A, alphap, Aad);
  k_gcn_y<<<dim3(T_/4, N_), 256, 0, stream>>>(x, Aad, Wf, bfp, g_gamma, g_beta, y1);
  k_seT<<<dim3(C_, N_), 256, 0, stream>>>(y1, seT);
  k_sa<<<N_, 256, 0, stream>>>(seT, W_sa, b_sa, sa);
  k_seV<<<dim3(C_, N_), 256, 0, stream>>>(y1, sa, seV);
  k_ta_ca<<<N_, 256, 0, stream>>>(seV, W_ta, b_ta, W_fc1, b_fc1, W_fc2, b_fc2, ta, ca);
  k_xa_qkv<<<dim3(T_/4, N_), 256, 0, stream>>>(y1, pos_emb, sa, ta, ca,
      Wq_h, bq_h, Wk_h, bk_h, Wv_h, bv_h, xa, qb, kb, vb);
  k_attn<<<dim3(2, H_, N_), 256, 0, stream>>>(qb, kb, vb, oh);
  k_out<<<dim3(T_/8, N_), 256, 0, stream>>>(oh, xa, x, W_ffn, b_ffn, m_gamma, m_beta, out);
}

// Round 14
// 494.603 us; speedup vs baseline: 1.5563x; 1.1681x over previous
//
#include <hip/hip_runtime.h>
#include <hip/hip_bf16.h>

#define N_ 128
#define C_ 64
#define T_ 128
#define V_ 25
#define S_ 3
#define IG 16
#define IH 8
#define H_ 8
#define D_ 200   // IH*V
#define CV 1600  // C_*V_
#define TV 3200  // T_*V_
#define EPSB 1e-5f
#define NCHUNK 16

typedef __attribute__((ext_vector_type(8))) short short8v;
typedef __attribute__((ext_vector_type(4))) float f32x4;
#define MFMA16 __builtin_amdgcn_mfma_f32_16x16x32_bf16
#define ZIDX(r,c) ((r)*72 + ((c) ^ ((((r)>>3)&7)<<3)))

__device__ __forceinline__ float sigm(float x){ return 1.f/(1.f+expf(-x)); }
__device__ __forceinline__ float b2f(__hip_bfloat16 b){ return __bfloat162float(b); }
__device__ __forceinline__ __hip_bfloat16 f2b(float f){ return __float2bfloat16(f); }
__device__ __forceinline__ float ubl(unsigned int u){ return __uint_as_float(u<<16); }
__device__ __forceinline__ float ubh(unsigned int u){ return __uint_as_float(u & 0xffff0000u); }
__device__ __forceinline__ unsigned short f2bu(float f){
  unsigned int u = __float_as_uint(f);
  u += 0x7fff + ((u>>16)&1);
  return (unsigned short)(u>>16);
}
__device__ __forceinline__ unsigned long long pk4bf(f32x4 v){
  unsigned long long a = f2bu(v[0]);
  unsigned long long b = f2bu(v[1]);
  unsigned long long c = f2bu(v[2]);
  unsigned long long d = f2bu(v[3]);
  return a | (b<<16) | (c<<32) | (d<<48);
}

// ---------------- K0: one-shot weight f32->bf16 conversion ----------------
__global__ __launch_bounds__(256) void k_prep(
    const float* __restrict__ Wq, const float* __restrict__ Wk,
    const float* __restrict__ Wf,
    const float* __restrict__ Wq_h, const float* __restrict__ Wk_h,
    const float* __restrict__ Wv_h, const float* __restrict__ W_ffn,
    short* __restrict__ wqb, short* __restrict__ wkb, short* __restrict__ Wfb,
    short* __restrict__ w3b, short* __restrict__ Wffnb)
{
  const int i = blockIdx.x*256 + threadIdx.x;
  if (i < 3072){ wqb[i]=(short)f2bu(Wq[i]); wkb[i]=(short)f2bu(Wk[i]); }
  if (i < 12288) Wfb[i]=(short)f2bu(Wf[i]);
  if (i < 4096){
    w3b[i]      =(short)f2bu(Wq_h[i]);
    w3b[4096+i] =(short)f2bu(Wk_h[i]);
    w3b[8192+i] =(short)f2bu(Wv_h[i]);
    Wffnb[i]    =(short)f2bu(W_ffn[i]);
  }
}

// ---------------- K1a: MFMA graph attention partials, merged over s ----------------
// grid (16, N_): block = 8 t's of one n. Weights from prepped bf16 (registers).
__global__ __launch_bounds__(256) void k_gcn_att1(
    const float* __restrict__ x,
    const short* __restrict__ wqb, const float* __restrict__ bq,
    const short* __restrict__ wkb, const float* __restrict__ bk,
    float* __restrict__ attg)
{
  const int tc = blockIdx.x, n = blockIdx.y;
  const int tid = threadIdx.x;
  const int wv = tid>>6, l = tid&63, lc = l&15, lk = l>>4;
  __shared__ __align__(16) short xtb[4*32*72];   // [tl][v(32)][c(72)], v>=25 zeroed
  __shared__ __align__(16) char QB[3*32*256];    // per s: [v][K=128 bf16], byte^=(v&7)<<4
  __shared__ __align__(16) char KB[3*32*256];
  __shared__ float bql[48], bkl[48];
  // weight A-frags in registers (L2-hot bf16)
  short8v aqf[3][2], akf[3][2];
  #pragma unroll
  for (int s=0;s<3;++s){
    #pragma unroll
    for (int ks=0;ks<2;++ks){
      aqf[s][ks] = *(const short8v*)(wqb + (s*16+lc)*64 + ks*32 + lk*8);
      akf[s][ks] = *(const short8v*)(wkb + (s*16+lc)*64 + ks*32 + lk*8);
    }
  }
  if (tid<48){ bql[tid]=bq[tid]; bkl[tid]=bk[tid]; }
  for (int i=tid;i<4*7*72;i+=256){
    int tl=i/(7*72), r=i%(7*72);
    xtb[(tl*32+25)*72 + r] = 0;
  }
  const float* xn = x + (size_t)n*C_*TV;
  #pragma unroll
  for (int tg=0; tg<2; ++tg){
    if (tg) __syncthreads();   // previous tg's xtb fully consumed
    {
      const int base = tc*200 + tg*100;
      float4 xb[7];
      #pragma unroll
      for (int k=0;k<7;++k){
        int i = tid + k*256;
        if (i<1600){ int c=i/25,a=i%25; xb[k] = *(const float4*)(xn + (size_t)c*TV + base + a*4); }
      }
      #pragma unroll
      for (int k=0;k<7;++k){
        int i = tid + k*256;
        if (i<1600){
          int c=i/25,a=i%25;
          float xv[4]={xb[k].x,xb[k].y,xb[k].z,xb[k].w};
          #pragma unroll
          for (int j=0;j<4;++j){
            int tv=a*4+j, tl=tv/25, v=tv-tl*25;
            xtb[(tl*32+v)*72 + c] = (short)f2bu(xv[j]);
          }
        }
      }
    }
    __syncthreads();
    const int tcol = (tg*4+wv)*32;   // byte base of this t's 16 K-cols
    const int sw = (lc&7)<<4;
    #pragma unroll
    for (int s=0;s<3;++s){
      f32x4 z={0.f,0.f,0.f,0.f};
      f32x4 aq0=z,aq1=z,ak0=z,ak1=z;
      #pragma unroll
      for (int ks=0;ks<2;++ks){
        short8v b0 = *(const short8v*)(xtb + (wv*32+lc)*72 + ks*32 + lk*8);
        short8v b1 = *(const short8v*)(xtb + (wv*32+16+lc)*72 + ks*32 + lk*8);
        aq0 = MFMA16(aqf[s][ks], b0, aq0,0,0,0);
        aq1 = MFMA16(aqf[s][ks], b1, aq1,0,0,0);
        ak0 = MFMA16(akf[s][ks], b0, ak0,0,0,0);
        ak1 = MFMA16(akf[s][ks], b1, ak1,0,0,0);
      }
      f32x4 q0,q1,k0,k1;
      #pragma unroll
      for (int r=0;r<4;++r){
        float bqv=bql[s*16+lk*4+r], bkv=bkl[s*16+lk*4+r];
        q0[r]=aq0[r]+bqv; q1[r]=aq1[r]+bqv;
        k0[r]=ak0[r]+bkv; k1[r]=ak1[r]+bkv;
      }
      char* QBs = QB + s*8192;
      char* KBs = KB + s*8192;
      *(unsigned long long*)(QBs + ((lc*256      + tcol + lk*8) ^ sw)) = pk4bf(q0);
      *(unsigned long long*)(QBs + (((16+lc)*256 + tcol + lk*8) ^ sw)) = pk4bf(q1);
      *(unsigned long long*)(KBs + ((lc*256      + tcol + lk*8) ^ sw)) = pk4bf(k0);
      *(unsigned long long*)(KBs + (((16+lc)*256 + tcol + lk*8) ^ sw)) = pk4bf(k1);
    }
  }
  __syncthreads();
  const int mt = wv>>1, nt = wv&1;
  const int sw = (lc&7)<<4;
  #pragma unroll
  for (int s=0;s<3;++s){
    const char* QBs = QB + s*8192;
    const char* KBs = KB + s*8192;
    f32x4 acc = {0.f,0.f,0.f,0.f};
    #pragma unroll
    for (int ks=0;ks<4;++ks){
      short8v a = *(const short8v*)(QBs + (((mt*16+lc)*256 + ks*64 + lk*16) ^ sw));
      short8v b = *(const short8v*)(KBs + (((nt*16+lc)*256 + ks*64 + lk*16) ^ sw));
      acc = MFMA16(a,b,acc,0,0,0);
    }
    float* Ao = attg + ((size_t)tc*(N_*S_) + n*S_ + s)*(V_*V_);
    #pragma unroll
    for (int reg=0;reg<4;++reg){
      int v = mt*16 + lk*4 + reg, w = nt*16 + lc;
      if (v<V_ && w<V_) Ao[v*V_+w] = acc[reg];
    }
  }
}

// ---------------- K1b: reduce chunks + softmax + write AsTg (bf16, padded, transposed) ----------------
__global__ __launch_bounds__(256) void k_gcn_att2(
    const float* __restrict__ attg, const float* __restrict__ A,
    const float* __restrict__ alphap, short* __restrict__ AsTg)
{
  const int ns = blockIdx.x, s = ns % S_, tid = threadIdx.x;
  __shared__ float att[V_*V_];
  short* dst = AsTg + (size_t)ns*1280;   // [w(32)][v(40)]
  for (int i=tid;i<1280;i+=256) dst[i]=0;
  for (int i=tid;i<V_*V_;i+=256){
    float acc=0.f;
    #pragma unroll
    for (int tcc=0;tcc<NCHUNK;++tcc) acc += attg[((size_t)tcc*(N_*S_) + ns)*(V_*V_) + i];
    att[i]=acc;
  }
  __syncthreads();
  if (tid<V_){
    const int w=tid; const float inv=1.f/(IG*T_);
    float mx=-1e30f;
    for (int v=0;v<V_;++v) mx=fmaxf(mx, att[v*V_+w]*inv);
    float sum=0.f;
    for (int v=0;v<V_;++v){ float e=expf(att[v*V_+w]*inv-mx); att[v*V_+w]=e; sum+=e; }
    float rs=1.f/sum;
    for (int v=0;v<V_;++v) att[v*V_+w]*=rs;
  }
  __syncthreads();
  const float alpha=alphap[0];
  for (int i=tid;i<V_*V_;i+=256){
    int v=i/25, w=i%25;
    dst[w*40+v] = (short)f2bu(A[s*625+i] + alpha*att[i]);
  }
}

// ---------------- K2: 4-t tile MFMA graph conv + Wf + bn + residual + relu ----------------
__global__ __launch_bounds__(256) void k_gcn_y(
    const float* __restrict__ x, const short* __restrict__ AsTg,
    const short* __restrict__ Wfb, const float* __restrict__ bfp,
    const float* __restrict__ g_gamma, const float* __restrict__ g_beta,
    __hip_bfloat16* __restrict__ y1)
{
  const int tc=blockIdx.x, n=blockIdx.y, tid=threadIdx.x;
  const int wv=tid>>6, l=tid&63, lc=l&15, lk=l>>4;
  __shared__ __align__(16) short xtb[64*136];   // [c][t*32+v], v-pad zeroed
  __shared__ __align__(16) short AsT[3*32*40];  // copied from AsTg (pads included)
  __shared__ __align__(16) short aggT[112*200]; // [tv][sc], rows 100..111 zeroed
  const float* xn = x + (size_t)n*C_*TV;
  const int tv0 = tc*100;
  float4 xbuf[7];
  #pragma unroll
  for (int k=0;k<7;++k){
    int i = tid + k*256;
    if (i < 1600){
      int c=i/25, a=i%25;
      xbuf[k] = *(const float4*)(xn + (size_t)c*TV + tv0 + a*4);
    }
  }
  #pragma unroll
  for (int k=0;k<7;++k){
    int i = tid + k*256;
    if (i < 1600){
      int c=i/25, a=i%25, tv4=a*4;
      float xv[4] = {xbuf[k].x, xbuf[k].y, xbuf[k].z, xbuf[k].w};
      #pragma unroll
      for (int j=0;j<4;++j){
        int tv=tv4+j, t=tv/25, v=tv-t*25;
        xtb[c*136 + t*32 + v] = (short)f2bu(xv[j]);
      }
    }
  }
  for (int i=tid;i<64*28;i+=256){ int c=i/28, r=i%28; xtb[c*136 + (r/7)*32 + 25 + (r%7)] = 0; }
  {
    const short* As_g = AsTg + (size_t)n*3840;
    for (int i=tid;i<480;i+=256)
      *(short8v*)(AsT + i*8) = *(const short8v*)(As_g + i*8);
  }
  for (int i=tid;i<12*200;i+=256) aggT[100*200+i]=0;
  __syncthreads();
  {
    const int t = wv;
    for (int s=0;s<S_;++s){
      short8v b0 = *(const short8v*)(AsT + (s*32+lc)*40 + lk*8);
      short8v b1 = *(const short8v*)(AsT + (s*32+16+lc)*40 + lk*8);
      #pragma unroll
      for (int mt=0;mt<4;++mt){
        short8v a = *(const short8v*)(xtb + (mt*16+lc)*136 + t*32 + lk*8);
        f32x4 z={0.f,0.f,0.f,0.f};
        f32x4 acc0 = MFMA16(a,b0,z,0,0,0);
        f32x4 acc1 = MFMA16(a,b1,z,0,0,0);
        *(unsigned long long*)(aggT + (t*25+lc)*200 + s*64 + mt*16 + lk*4) = pk4bf(acc0);
        if (lc<9)
          *(unsigned long long*)(aggT + (t*25+16+lc)*200 + s*64 + mt*16 + lk*4) = pk4bf(acc1);
      }
    }
  }
  short8v af[6];
  #pragma unroll
  for (int ks=0;ks<6;++ks){
    const int s = ks>>1, c0 = (ks&1)*32 + lk*8;
    af[ks] = *(const short8v*)(Wfb + (size_t)(s*C_ + wv*16+lc)*C_ + c0);
  }
  __syncthreads();
  f32x4 acc[7];
  #pragma unroll
  for (int dt=0;dt<7;++dt) acc[dt]=(f32x4){0.f,0.f,0.f,0.f};
  #pragma unroll
  for (int dt=0;dt<7;++dt){
    #pragma unroll
    for (int ks=0;ks<6;++ks){
      short8v b = *(const short8v*)(aggT + (dt*16+lc)*200 + ks*32 + lk*8);
      acc[dt] = MFMA16(af[ks], b, acc[dt],0,0,0);
    }
  }
  const float invs = rsqrtf(1.f+EPSB);
  __hip_bfloat16* yo = y1 + (size_t)n*C_*TV;
  #pragma unroll
  for (int reg=0;reg<4;++reg){
    const int o = wv*16 + lk*4 + reg;
    const float bsum = bfp[o]+bfp[C_+o]+bfp[2*C_+o];
    const float gs = g_gamma[o]*invs, gb = g_beta[o];
    #pragma unroll
    for (int dt=0;dt<7;++dt){
      const int tv = dt*16 + lc;
      if (tv < 100){
        float val = (acc[dt][reg]+bsum)*gs + gb + xn[(size_t)o*TV + tv0 + tv];
        yo[(size_t)o*TV + tv0 + tv] = f2b(fmaxf(val,0.f));
      }
    }
  }
}

// ---------------- K3a: seT[n,c,v] = mean_t y1 ----------------
__global__ __launch_bounds__(256) void k_seT(const __hip_bfloat16* __restrict__ y1,
    float* __restrict__ seT)
{
  const int c=blockIdx.x, n=blockIdx.y, tid=threadIdx.x;
  const int v = tid&31, g = tid>>5;
  __shared__ float red[8][33];
  const __hip_bfloat16* yp = y1 + ((size_t)n*C_+c)*T_*V_;
  float s=0.f;
  if (v < V_){
    #pragma unroll 4
    for (int j=0;j<16;++j){
      int t = g + j*8;
      s += b2f(yp[t*V_+v]);
    }
  }
  red[g][v]=s;
  __syncthreads();
  if (tid < V_){
    float tot=0.f;
    #pragma unroll
    for (int g2=0;g2<8;++g2) tot += red[g2][tid];
    seT[((size_t)n*C_+c)*V_+tid]=tot*(1.f/T_);
  }
}

// ---------------- K3b: sa[n,v] spatial gate (LDS-staged, c-split) ----------------
__global__ __launch_bounds__(256) void k_sa(const float* __restrict__ seT,
    const float* __restrict__ W_sa, const float* __restrict__ b_sa,
    float* __restrict__ sa)
{
  const int n=blockIdx.x, tid=threadIdx.x;
  __shared__ float sel[CV];
  __shared__ float wsl[CV];
  __shared__ float part[8][32];
  const float* se = seT + (size_t)n*C_*V_;
  for (int i=tid;i<CV;i+=256){ sel[i]=se[i]; wsl[i]=W_sa[i]; }
  __syncthreads();
  if (tid < 200){
    const int v = tid%25, cg = tid/25;
    float acc=0.f;
    for (int c=cg*8;c<cg*8+8;++c){
      #pragma unroll
      for (int k=0;k<V_;++k){
        int vv=v+k-12;
        if (vv>=0&&vv<V_) acc += sel[c*V_+vv]*wsl[c*V_+k];
      }
    }
    part[cg][v]=acc;
  }
  __syncthreads();
  if (tid<V_){
    float acc=b_sa[0];
    #pragma unroll
    for (int g=0;g<8;++g) acc+=part[g][tid];
    sa[n*V_+tid]=sigm(acc);
  }
}

// ---------------- K3c: seV[n,c,t] = mean_v y1*(1+sa) ----------------
__global__ __launch_bounds__(256) void k_seV(const __hip_bfloat16* __restrict__ y1,
    const float* __restrict__ sa, float* __restrict__ seV)
{
  const int c=blockIdx.x, n=blockIdx.y, tid=threadIdx.x;
  const int v = tid&31, g = tid>>5;
  __shared__ float sal[32];
  if (tid<32) sal[tid] = (tid<V_)? 1.f+sa[n*V_+tid] : 0.f;
  __syncthreads();
  const __hip_bfloat16* yp = y1 + ((size_t)n*C_+c)*T_*V_;
  float* svo = seV + ((size_t)n*C_+c)*T_;
  const float sv_ = sal[v];
  for (int j=0;j<16;++j){
    int t = g*16 + j;
    float val = (v<V_)? b2f(yp[t*V_+v])*sv_ : 0.f;
    #pragma unroll
    for (int off=16;off;off>>=1) val += __shfl_xor(val, off);
    if (v==0) svo[t]=val*(1.f/V_);
  }
}

// ---------------- K3d: ta + ca gates (LDS-staged, split reductions) ----------------
__global__ __launch_bounds__(256) void k_ta_ca(const float* __restrict__ seV,
    const float* __restrict__ W_ta, const float* __restrict__ b_ta,
    const float* __restrict__ W_fc1, const float* __restrict__ b_fc1,
    const float* __restrict__ W_fc2, const float* __restrict__ b_fc2,
    float* __restrict__ ta, float* __restrict__ ca)
{
  const int n=blockIdx.x, tid=threadIdx.x;
  __shared__ float svl[C_*T_];
  __shared__ float wtl[C_*9];
  __shared__ float w1l[32*C_];
  __shared__ float w2l[C_*32];
  __shared__ float tal[T_];
  __shared__ float part2[2][T_];
  __shared__ float part4[C_][4];
  __shared__ float scls[C_];
  __shared__ float h1[32];
  const float* sv = seV + (size_t)n*C_*T_;
  for (int i=tid;i<C_*T_;i+=256) svl[i]=sv[i];
  for (int i=tid;i<C_*9;i+=256) wtl[i]=W_ta[i];
  for (int i=tid;i<32*C_;i+=256){ w1l[i]=W_fc1[i]; w2l[i]=W_fc2[i]; }
  __syncthreads();
  {
    const int t = tid & 127, half = tid >> 7;
    float acc = 0.f;
    for (int c=half*32; c<half*32+32; ++c){
      #pragma unroll
      for (int k=0;k<9;++k){
        int tt=t+k-4;
        if (tt>=0&&tt<T_) acc += svl[c*T_+tt]*wtl[c*9+k];
      }
    }
    part2[half][t]=acc;
  }
  __syncthreads();
  if (tid<T_){
    float s_=sigm(part2[0][tid]+part2[1][tid]+b_ta[0]);
    tal[tid]=s_; ta[n*T_+tid]=s_;
  }
  __syncthreads();
  {
    const int c = tid>>2, q = tid&3;
    float acc=0.f;
    for (int t=q*32;t<q*32+32;++t) acc += svl[c*T_+t]*(1.f+tal[t]);
    part4[c][q]=acc;
  }
  __syncthreads();
  if (tid<C_) scls[tid]=(part4[tid][0]+part4[tid][1]+part4[tid][2]+part4[tid][3])*(1.f/T_);
  __syncthreads();
  if (tid<32){
    float acc=b_fc1[tid];
    for (int c=0;c<C_;++c) acc += scls[c]*w1l[tid*C_+c];
    h1[tid]=fmaxf(acc,0.f);
  }
  __syncthreads();
  if (tid<C_){
    float acc=b_fc2[tid];
    for (int j=0;j<32;++j) acc += h1[j]*w2l[tid*32+j];
    ca[n*C_+tid]=sigm(acc);
  }
}

// ---------------- K4: 4-t tile MFMA xa/gates + q/k/v projections ----------------
__global__ __launch_bounds__(256) void k_xa_qkv(
    const __hip_bfloat16* __restrict__ y1, const float* __restrict__ pos_emb,
    const float* __restrict__ sa, const float* __restrict__ ta, const float* __restrict__ ca,
    const short* __restrict__ w3b, const float* __restrict__ bq_h,
    const float* __restrict__ bk_h, const float* __restrict__ bv_h,
    __hip_bfloat16* __restrict__ xa, __hip_bfloat16* __restrict__ qb,
    __hip_bfloat16* __restrict__ kb, __hip_bfloat16* __restrict__ vb)
{
  const int tc=blockIdx.x, n=blockIdx.y, tid=threadIdx.x;
  const int wv=tid>>6, l=tid&63, lc=l&15, lk=l>>4;
  __shared__ __align__(16) short w3[192*72];
  __shared__ __align__(16) short xalT[4][32*72];
  __shared__ float bl[192];
  __shared__ float sal[32], cal[64], tgs[4];
  const int tv0 = tc*100;
  const __hip_bfloat16* y1n = y1 + (size_t)n*C_*TV;
  __hip_bfloat16* xan = xa + (size_t)n*C_*TV;
  uint2 ybuf[7];
  #pragma unroll
  for (int k=0;k<7;++k){
    int i = tid + k*256;
    if (i < 1600){
      int c=i/25, a=i%25;
      ybuf[k] = *(const uint2*)(y1n + (size_t)c*TV + tv0 + a*4);
    }
  }
  for (int i=tid;i<1536;i+=256){
    int mu=i>>3, j=i&7;
    *(short8v*)(w3 + mu*72 + j*8) = *(const short8v*)(w3b + mu*64 + j*8);
  }
  if (tid<192){
    int which=tid/C_, ho=tid%C_;
    bl[tid] = (which==0?bq_h:(which==1?bk_h:bv_h))[ho];
  }
  if (tid<32) sal[tid] = (tid<V_)? 1.f+sa[n*V_+tid] : 0.f;
  if (tid>=32 && tid<96) cal[tid-32] = 1.f+ca[n*C_+tid-32];
  if (tid>=96 && tid<100) tgs[tid-96] = 1.f+ta[n*T_+tc*4+(tid-96)];
  for (int i=tid;i<4*7*72;i+=256){
    int tl=i/(7*72), r=i%(7*72);
    xalT[tl][25*72 + r] = 0;
  }
  __syncthreads();
  #pragma unroll
  for (int k=0;k<7;++k){
    int i = tid + k*256;
    if (i < 1600){
      int c=i/25, a=i%25, tv4=a*4;
      unsigned int u0=ybuf[k].x, u1=ybuf[k].y;
      float yv[4] = {ubl(u0),ubh(u0),ubl(u1),ubh(u1)};
      const float calc = cal[c];
      unsigned long long pack = 0ull;
      #pragma unroll
      for (int j=0;j<4;++j){
        int tv=tv4+j, tl=tv/25, v=tv-tl*25;
        float val = yv[j]*sal[v]*tgs[tl]*calc + pos_emb[(size_t)(tc*4+tl)*CV + c*V_ + v];
        unsigned short b = f2bu(val);
        pack |= (unsigned long long)b << (16*j);
        xalT[tl][v*72 + c] = (short)b;
      }
      *(unsigned long long*)(xan + (size_t)c*TV + tv0 + tv4) = pack;
    }
  }
  __syncthreads();
  const int t = tc*4 + wv;
  short8v bf_[2][2];
  #pragma unroll
  for (int ks=0;ks<2;++ks){
    bf_[ks][0] = *(const short8v*)(&xalT[wv][lc*72      + ks*32 + lk*8]);
    bf_[ks][1] = *(const short8v*)(&xalT[wv][(16+lc)*72 + ks*32 + lk*8]);
  }
  #pragma unroll
  for (int mt=0;mt<12;++mt){
    f32x4 acc0 = {0.f,0.f,0.f,0.f}, acc1 = {0.f,0.f,0.f,0.f};
    #pragma unroll
    for (int ks=0;ks<2;++ks){
      short8v a = *(const short8v*)(w3 + (mt*16+lc)*72 + ks*32 + lk*8);
      acc0 = MFMA16(a, bf_[ks][0], acc0,0,0,0);
      acc1 = MFMA16(a, bf_[ks][1], acc1,0,0,0);
    }
    #pragma unroll
    for (int reg=0;reg<4;++reg){
      const int mu = mt*16 + lk*4 + reg;
      const int which = mt>>2;
      const int ho = mu & 63, h = ho>>3, o = ho&7;
      __hip_bfloat16* dst = (which==0?qb:(which==1?kb:vb))
                            + (((size_t)n*H_+h)*T_+t)*D_ + o*V_;
      const float bb = bl[mu];
      dst[lc] = f2b(acc0[reg]+bb);
      if (lc < 9) dst[16+lc] = f2b(acc1[reg]+bb);
    }
  }
}

// ---------------- K5: MFMA flash causal MHA ----------------
__global__ __launch_bounds__(256) void k_attn(
    const __hip_bfloat16* __restrict__ qb, const __hip_bfloat16* __restrict__ kb,
    const __hip_bfloat16* __restrict__ vb, __hip_bfloat16* __restrict__ oh)
{
  const int bx = blockIdx.x;
  const int hh = blockIdx.y;
  const int n  = blockIdx.z;
  const int nh = n*H_ + hh;
  const int tid = threadIdx.x;
  const int wv = tid>>6, l = tid&63;
  const int lc = l&15, lg = l>>4;
  __shared__ __align__(16) char KlB[32*512];
  __shared__ __align__(16) short VT[208*40];
  __shared__ __align__(16) short Pl[64*40];
  const __hip_bfloat16* qg_ = qb + (size_t)nh*T_*D_;
  const __hip_bfloat16* kg_ = kb + (size_t)nh*T_*D_;
  const __hip_bfloat16* vg_ = vb + (size_t)nh*T_*D_;
  __hip_bfloat16* ohn = oh + (size_t)n*C_*TV;
  const float scale = 0.0707106781f;

  for (int i=tid;i<32*12;i+=256){
    int key=i/12, j=i%12;
    *(unsigned int*)(KlB + ((key*512 + 400 + j*4) ^ ((key&7)<<4))) = 0u;
  }
  for (int i=tid;i<8*40;i+=256) VT[200*40 + i] = 0;

  const int qrow = bx*64 + wv*16 + lc;
  short8v qf[7];
  {
    const short8v* qs8 = (const short8v*)(qg_ + (size_t)qrow*D_);
    #pragma unroll
    for (int ks=0;ks<7;++ks) qf[ks] = qs8[ks*4 + lg];
  }
  f32x4 oacc[13];
  #pragma unroll
  for (int i=0;i<13;++i) oacc[i] = (f32x4){0.f,0.f,0.f,0.f};
  float m[4], lsm[4];
  #pragma unroll
  for (int r=0;r<4;++r){ m[r]=-1e30f; lsm[r]=0.f; }

  const int ntiles = (bx==0)? 2 : 4;
  for (int kt=0; kt<ntiles; ++kt){
    const int j0 = kt*32;
    __syncthreads();
    {
      const short8v* ks8 = (const short8v*)(kg_ + (size_t)j0*D_);
      for (int i=tid;i<32*25;i+=256){
        int row=i/25, w=i%25;
        *(short8v*)(KlB + ((row*512 + w*16) ^ ((row&7)<<4))) = ks8[i];
      }
      const short8v* vs8 = (const short8v*)(vg_ + (size_t)j0*D_);
      for (int i=tid;i<32*25;i+=256){
        int row=i&31, w4=i>>5;
        short8v u = vs8[row*25 + w4];
        #pragma unroll
        for (int j=0;j<8;++j) VT[(w4*8+j)*40 + row] = u[j];
      }
    }
    __syncthreads();
    const bool active = (j0 <= bx*64 + wv*16 + 15);
    if (active){
      f32x4 s0 = {0.f,0.f,0.f,0.f}, s1 = {0.f,0.f,0.f,0.f};
      #pragma unroll
      for (int ks=0;ks<7;++ks){
        short8v b0 = *(const short8v*)(KlB + ((lc*512      + ks*64 + lg*16) ^ ((lc&7)<<4)));
        short8v b1 = *(const short8v*)(KlB + (((16+lc)*512 + ks*64 + lg*16) ^ ((lc&7)<<4)));
        s0 = MFMA16(qf[ks], b0, s0,0,0,0);
        s1 = MFMA16(qf[ks], b1, s1,0,0,0);
      }
      float fr[4];
      #pragma unroll
      for (int r=0;r<4;++r){
        const int qg = bx*64 + wv*16 + lg*4 + r;
        float v0 = (j0+lc    <= qg) ? s0[r]*scale : -1e30f;
        float v1 = (j0+16+lc <= qg) ? s1[r]*scale : -1e30f;
        float mx = fmaxf(v0,v1);
        #pragma unroll
        for (int off=1;off<16;off<<=1) mx = fmaxf(mx, __shfl_xor(mx, off));
        float mn = fmaxf(m[r], mx);
        fr[r] = __expf(m[r]-mn);
        float p0 = __expf(v0-mn), p1 = __expf(v1-mn);
        float ts = p0+p1;
        #pragma unroll
        for (int off=1;off<16;off<<=1) ts += __shfl_xor(ts, off);
        lsm[r] = lsm[r]*fr[r] + ts;
        m[r] = mn;
        Pl[(wv*16 + lg*4 + r)*40 + lc]      = (short)f2bu(p0);
        Pl[(wv*16 + lg*4 + r)*40 + 16 + lc] = (short)f2bu(p1);
      }
      #pragma unroll
      for (int dt=0;dt<13;++dt){
        #pragma unroll
        for (int r=0;r<4;++r) oacc[dt][r] *= fr[r];
      }
      short8v pa = *(const short8v*)(Pl + (wv*16+lc)*40 + lg*8);
      #pragma unroll
      for (int dt=0;dt<13;++dt){
        short8v b = *(const short8v*)(VT + (dt*16+lc)*40 + lg*8);
        oacc[dt] = MFMA16(pa, b, oacc[dt],0,0,0);
      }
    }
  }
  float rl[4];
  #pragma unroll
  for (int r=0;r<4;++r) rl[r] = 1.f/lsm[r];
  #pragma unroll
  for (int dt=0;dt<13;++dt){
    const int d = dt*16 + lc;
    if (d < D_){
      const int oi = d/25, v = d - oi*25;
      const int c = hh*IH + oi;
      #pragma unroll
      for (int r=0;r<4;++r){
        const int q = bx*64 + wv*16 + lg*4 + r;
        ohn[(size_t)c*TV + q*V_ + v] = f2b(oacc[dt][r]*rl[r]);
      }
    }
  }
}

// ---------------- K7: 8-t tile MFMA out kernel ----------------
__global__ __launch_bounds__(256) void k_out(
    const __hip_bfloat16* __restrict__ oh, const __hip_bfloat16* __restrict__ xa,
    const float* __restrict__ x, const short* __restrict__ Wffnb,
    const float* __restrict__ b_ffn, const float* __restrict__ m_gamma,
    const float* __restrict__ m_beta, float* __restrict__ out)
{
  const int tc = blockIdx.x, n = blockIdx.y, tid = threadIdx.x;
  const int wv = tid>>6, l = tid&63, lc = l&15, lg = l>>4;
  __shared__ __align__(16) short zT[208*72];
  __shared__ float bn_s[64], bn_b[64], bff[64];
  const float invs = rsqrtf(1.f+EPSB);
  if (tid<64){ bn_s[tid]=m_gamma[tid]*invs; bn_b[tid]=m_beta[tid]; bff[tid]=b_ffn[tid]; }
  for (int i=tid;i<8*72;i+=256) zT[200*72+i]=0;
  const int tv0 = tc*200;
  const __hip_bfloat16* xan = xa + (size_t)n*C_*TV;
  const __hip_bfloat16* ohn = oh + (size_t)n*C_*TV;
  uint4 xbuf[7], obuf[7];
  #pragma unroll
  for (int k=0;k<7;++k){
    int i = tid + k*256;
    if (i < 1600){
      int c=i/25, a=i%25;
      xbuf[k] = *(const uint4*)(xan + (size_t)c*TV + tv0 + a*8);
      obuf[k] = *(const uint4*)(ohn + (size_t)c*TV + tv0 + a*8);
    }
  }
  __syncthreads();
  #pragma unroll
  for (int k=0;k<7;++k){
    int i = tid + k*256;
    if (i < 1600){
      int c=i/25, a=i%25, tv8=a*8;
      const float s_=bn_s[c], b_=bn_b[c];
      const unsigned int* xu = (const unsigned int*)&xbuf[k];
      const unsigned int* ou = (const unsigned int*)&obuf[k];
      #pragma unroll
      for (int j=0;j<4;++j){
        zT[ZIDX(tv8+2*j,   c)] = (short)f2bu(s_*ubl(ou[j]) + b_ + ubl(xu[j]));
        zT[ZIDX(tv8+2*j+1, c)] = (short)f2bu(s_*ubh(ou[j]) + b_ + ubh(xu[j]));
      }
    }
  }
  __syncthreads();
  short8v af0 = *(const short8v*)(Wffnb + (wv*16+lc)*64 + lg*8);
  short8v af1 = *(const short8v*)(Wffnb + (wv*16+lc)*64 + 32 + lg*8);
  f32x4 acc[13];
  #pragma unroll
  for (int dt=0;dt<13;++dt) acc[dt] = (f32x4){0.f,0.f,0.f,0.f};
  #pragma unroll
  for (int dt=0;dt<13;++dt){
    short8v b0 = *(const short8v*)(zT + ZIDX(dt*16+lc, lg*8));
    short8v b1 = *(const short8v*)(zT + ZIDX(dt*16+lc, 32+lg*8));
    acc[dt] = MFMA16(af0, b0, acc[dt],0,0,0);
    acc[dt] = MFMA16(af1, b1, acc[dt],0,0,0);
  }
  const float* xn = x + (size_t)n*C_*TV;
  float* outn = out + (size_t)n*C_*TV;
  #pragma unroll
  for (int dt=0;dt<13;++dt){
    const int tv = dt*16 + lc;
    if (tv < 200){
      #pragma unroll
      for (int reg=0;reg<4;++reg){
        const int o = wv*16 + lg*4 + reg;
        float z2 = fmaxf(acc[dt][reg] + bff[o], 0.f) + b2f(xan[(size_t)o*TV + tv0 + tv]);
        float z3 = bn_s[o]*z2 + bn_b[o];
        outn[(size_t)o*TV + tv0 + tv] = fmaxf(z3 + xn[(size_t)o*TV + tv0 + tv], 0.f);
      }
    }
  }
}

extern "C" void kernel_launch(void* const* d_in, const int* in_sizes, int n_in,
                              void* d_out, int out_size, void* d_ws, size_t ws_size,
                              hipStream_t stream) {
  const float* x      = (const float*)d_in[0];
  const float* A      = (const float*)d_in[1];
  const float* alphap = (const float*)d_in[2];
  const float* Wq     = (const float*)d_in[3];
  const float* bq     = (const float*)d_in[4];
  const float* Wk     = (const float*)d_in[5];
  const float* bk     = (const float*)d_in[6];
  const float* Wf     = (const float*)d_in[7];
  const float* bfp    = (const float*)d_in[8];
  const float* g_gamma= (const float*)d_in[9];
  const float* g_beta = (const float*)d_in[10];
  const float* W_sa   = (const float*)d_in[11];
  const float* b_sa   = (const float*)d_in[12];
  const float* W_ta   = (const float*)d_in[13];
  const float* b_ta   = (const float*)d_in[14];
  const float* W_fc1  = (const float*)d_in[15];
  const float* b_fc1  = (const float*)d_in[16];
  const float* W_fc2  = (const float*)d_in[17];
  const float* b_fc2  = (const float*)d_in[18];
  const float* pos_emb= (const float*)d_in[19];
  const float* Wq_h   = (const float*)d_in[20];
  const float* bq_h   = (const float*)d_in[21];
  const float* Wk_h   = (const float*)d_in[22];
  const float* bk_h   = (const float*)d_in[23];
  const float* Wv_h   = (const float*)d_in[24];
  const float* bv_h   = (const float*)d_in[25];
  const float* W_ffn  = (const float*)d_in[26];
  const float* b_ffn  = (const float*)d_in[27];
  const float* m_gamma= (const float*)d_in[28];
  const float* m_beta = (const float*)d_in[29];
  float* out = (float*)d_out;

  float* ws   = (float*)d_ws;
  float* seT  = ws;                    // 204800
  float* seV  = seT + 204800;          // 1048576
  float* sa   = seV + 1048576;         // 3200
  float* ta   = sa  + 3200;            // 16384
  float* ca   = ta  + 16384;           // 8192
  short* wsh  = (short*)(ca + 8192);
  short* AsTg = wsh;                   // 128*3*32*40 = 491520
  short* wqb  = AsTg + 491520;         // 3072
  short* wkb  = wqb + 3072;            // 3072
  short* Wfb  = wkb + 3072;            // 12288
  short* w3b  = Wfb + 12288;           // 12288
  short* Wffnb= w3b + 12288;           // 4096
  __hip_bfloat16* y1 = (__hip_bfloat16*)(Wffnb + 4096);
  __hip_bfloat16* xa = y1 + (size_t)26214400;
  __hip_bfloat16* qb = xa + (size_t)26214400;
  __hip_bfloat16* kb = qb + (size_t)26214400;
  __hip_bfloat16* vb = kb + (size_t)26214400;
  __hip_bfloat16* oh = y1;   // reuse
  float* attg = (float*)y1;  // scratch before y1 written

  k_prep<<<48, 256, 0, stream>>>(Wq, Wk, Wf, Wq_h, Wk_h, Wv_h, W_ffn,
                                 wqb, wkb, Wfb, w3b, Wffnb);
  k_gcn_att1<<<dim3(16, N_), 256, 0, stream>>>(x, wqb, bq, wkb, bk, attg);
  k_gcn_att2<<<N_*S_, 256, 0, stream>>>(attg, A, alphap, AsTg);
  k_gcn_y<<<dim3(T_/4, N_), 256, 0, stream>>>(x, AsTg, Wfb, bfp, g_gamma, g_beta, y1);
  k_seT<<<dim3(C_, N_), 256, 0, stream>>>(y1, seT);
  k_sa<<<N_, 256, 0, stream>>>(seT, W_sa, b_sa, sa);
  k_seV<<<dim3(C_, N_), 256, 0, stream>>>(y1, sa, seV);
  k_ta_ca<<<N_, 256, 0, stream>>>(seV, W_ta, b_ta, W_fc1, b_fc1, W_fc2, b_fc2, ta, ca);
  k_xa_qkv<<<dim3(T_/4, N_), 256, 0, stream>>>(y1, pos_emb, sa, ta, ca,
      w3b, bq_h, bk_h, bv_h, xa, qb, kb, vb);
  k_attn<<<dim3(2, H_, N_), 256, 0, stream>>>(qb, kb, vb, oh);
  k_out<<<dim3(T_/8, N_), 256, 0, stream>>>(oh, xa, x, Wffnb, b_ffn, m_gamma, m_beta, out);
}

// Round 15
// 447.775 us; speedup vs baseline: 1.7190x; 1.1046x over previous
//
#include <hip/hip_runtime.h>
#include <hip/hip_bf16.h>

#define N_ 128
#define C_ 64
#define T_ 128
#define V_ 25
#define S_ 3
#define IG 16
#define IH 8
#define H_ 8
#define D_ 200   // IH*V
#define CV 1600  // C_*V_
#define TV 3200  // T_*V_
#define EPSB 1e-5f
#define NCHUNK 16

typedef __attribute__((ext_vector_type(8))) short short8v;
typedef __attribute__((ext_vector_type(4))) float f32x4;
#define MFMA16 __builtin_amdgcn_mfma_f32_16x16x32_bf16
#define ZIDX(r,c) ((r)*72 + ((c) ^ ((((r)>>3)&7)<<3)))

__device__ __forceinline__ float sigm(float x){ return 1.f/(1.f+expf(-x)); }
__device__ __forceinline__ float b2f(__hip_bfloat16 b){ return __bfloat162float(b); }
__device__ __forceinline__ __hip_bfloat16 f2b(float f){ return __float2bfloat16(f); }
__device__ __forceinline__ float ubl(unsigned int u){ return __uint_as_float(u<<16); }
__device__ __forceinline__ float ubh(unsigned int u){ return __uint_as_float(u & 0xffff0000u); }
__device__ __forceinline__ float sh2f(short s){ return __uint_as_float(((unsigned int)(unsigned short)s)<<16); }
__device__ __forceinline__ unsigned short f2bu(float f){
  unsigned int u = __float_as_uint(f);
  u += 0x7fff + ((u>>16)&1);
  return (unsigned short)(u>>16);
}
__device__ __forceinline__ unsigned long long pk4bf(f32x4 v){
  unsigned long long a = f2bu(v[0]);
  unsigned long long b = f2bu(v[1]);
  unsigned long long c = f2bu(v[2]);
  unsigned long long d = f2bu(v[3]);
  return a | (b<<16) | (c<<32) | (d<<48);
}

// ---------------- K0: one-shot weight f32->bf16 conversion ----------------
__global__ __launch_bounds__(256) void k_prep(
    const float* __restrict__ Wq, const float* __restrict__ Wk,
    const float* __restrict__ Wf,
    const float* __restrict__ Wq_h, const float* __restrict__ Wk_h,
    const float* __restrict__ Wv_h, const float* __restrict__ W_ffn,
    short* __restrict__ wqb, short* __restrict__ wkb, short* __restrict__ Wfb,
    short* __restrict__ w3b, short* __restrict__ Wffnb)
{
  const int i = blockIdx.x*256 + threadIdx.x;
  if (i < 3072){ wqb[i]=(short)f2bu(Wq[i]); wkb[i]=(short)f2bu(Wk[i]); }
  if (i < 12288) Wfb[i]=(short)f2bu(Wf[i]);
  if (i < 4096){
    w3b[i]      =(short)f2bu(Wq_h[i]);
    w3b[4096+i] =(short)f2bu(Wk_h[i]);
    w3b[8192+i] =(short)f2bu(Wv_h[i]);
    Wffnb[i]    =(short)f2bu(W_ffn[i]);
  }
}

// ---------------- K1a: MFMA graph attention partials, merged over s ----------------
__global__ __launch_bounds__(256) void k_gcn_att1(
    const float* __restrict__ x,
    const short* __restrict__ wqb, const float* __restrict__ bq,
    const short* __restrict__ wkb, const float* __restrict__ bk,
    float* __restrict__ attg)
{
  const int tc = blockIdx.x, n = blockIdx.y;
  const int tid = threadIdx.x;
  const int wv = tid>>6, l = tid&63, lc = l&15, lk = l>>4;
  __shared__ __align__(16) short xtb[4*32*72];   // [tl][v(32)][c(72)], v>=25 zeroed
  __shared__ __align__(16) char QB[3*32*256];    // per s: [v][K=128 bf16], byte^=(v&7)<<4
  __shared__ __align__(16) char KB[3*32*256];
  __shared__ float bql[48], bkl[48];
  short8v aqf[3][2], akf[3][2];
  #pragma unroll
  for (int s=0;s<3;++s){
    #pragma unroll
    for (int ks=0;ks<2;++ks){
      aqf[s][ks] = *(const short8v*)(wqb + (s*16+lc)*64 + ks*32 + lk*8);
      akf[s][ks] = *(const short8v*)(wkb + (s*16+lc)*64 + ks*32 + lk*8);
    }
  }
  if (tid<48){ bql[tid]=bq[tid]; bkl[tid]=bk[tid]; }
  for (int i=tid;i<4*7*72;i+=256){
    int tl=i/(7*72), r=i%(7*72);
    xtb[(tl*32+25)*72 + r] = 0;
  }
  const float* xn = x + (size_t)n*C_*TV;
  #pragma unroll
  for (int tg=0; tg<2; ++tg){
    if (tg) __syncthreads();
    {
      const int base = tc*200 + tg*100;
      float4 xb[7];
      #pragma unroll
      for (int k=0;k<7;++k){
        int i = tid + k*256;
        if (i<1600){ int c=i/25,a=i%25; xb[k] = *(const float4*)(xn + (size_t)c*TV + base + a*4); }
      }
      #pragma unroll
      for (int k=0;k<7;++k){
        int i = tid + k*256;
        if (i<1600){
          int c=i/25,a=i%25;
          float xv[4]={xb[k].x,xb[k].y,xb[k].z,xb[k].w};
          #pragma unroll
          for (int j=0;j<4;++j){
            int tv=a*4+j, tl=tv/25, v=tv-tl*25;
            xtb[(tl*32+v)*72 + c] = (short)f2bu(xv[j]);
          }
        }
      }
    }
    __syncthreads();
    const int tcol = (tg*4+wv)*32;
    const int sw = (lc&7)<<4;
    #pragma unroll
    for (int s=0;s<3;++s){
      f32x4 z={0.f,0.f,0.f,0.f};
      f32x4 aq0=z,aq1=z,ak0=z,ak1=z;
      #pragma unroll
      for (int ks=0;ks<2;++ks){
        short8v b0 = *(const short8v*)(xtb + (wv*32+lc)*72 + ks*32 + lk*8);
        short8v b1 = *(const short8v*)(xtb + (wv*32+16+lc)*72 + ks*32 + lk*8);
        aq0 = MFMA16(aqf[s][ks], b0, aq0,0,0,0);
        aq1 = MFMA16(aqf[s][ks], b1, aq1,0,0,0);
        ak0 = MFMA16(akf[s][ks], b0, ak0,0,0,0);
        ak1 = MFMA16(akf[s][ks], b1, ak1,0,0,0);
      }
      f32x4 q0,q1,k0,k1;
      #pragma unroll
      for (int r=0;r<4;++r){
        float bqv=bql[s*16+lk*4+r], bkv=bkl[s*16+lk*4+r];
        q0[r]=aq0[r]+bqv; q1[r]=aq1[r]+bqv;
        k0[r]=ak0[r]+bkv; k1[r]=ak1[r]+bkv;
      }
      char* QBs = QB + s*8192;
      char* KBs = KB + s*8192;
      *(unsigned long long*)(QBs + ((lc*256      + tcol + lk*8) ^ sw)) = pk4bf(q0);
      *(unsigned long long*)(QBs + (((16+lc)*256 + tcol + lk*8) ^ sw)) = pk4bf(q1);
      *(unsigned long long*)(KBs + ((lc*256      + tcol + lk*8) ^ sw)) = pk4bf(k0);
      *(unsigned long long*)(KBs + (((16+lc)*256 + tcol + lk*8) ^ sw)) = pk4bf(k1);
    }
  }
  __syncthreads();
  const int mt = wv>>1, nt = wv&1;
  const int sw = (lc&7)<<4;
  #pragma unroll
  for (int s=0;s<3;++s){
    const char* QBs = QB + s*8192;
    const char* KBs = KB + s*8192;
    f32x4 acc = {0.f,0.f,0.f,0.f};
    #pragma unroll
    for (int ks=0;ks<4;++ks){
      short8v a = *(const short8v*)(QBs + (((mt*16+lc)*256 + ks*64 + lk*16) ^ sw));
      short8v b = *(const short8v*)(KBs + (((nt*16+lc)*256 + ks*64 + lk*16) ^ sw));
      acc = MFMA16(a,b,acc,0,0,0);
    }
    float* Ao = attg + ((size_t)tc*(N_*S_) + n*S_ + s)*(V_*V_);
    #pragma unroll
    for (int reg=0;reg<4;++reg){
      int v = mt*16 + lk*4 + reg, w = nt*16 + lc;
      if (v<V_ && w<V_) Ao[v*V_+w] = acc[reg];
    }
  }
}

// ---------------- K1b: reduce chunks + softmax + write AsTg (bf16, padded, transposed) ----------------
__global__ __launch_bounds__(256) void k_gcn_att2(
    const float* __restrict__ attg, const float* __restrict__ A,
    const float* __restrict__ alphap, short* __restrict__ AsTg)
{
  const int ns = blockIdx.x, s = ns % S_, tid = threadIdx.x;
  __shared__ float att[V_*V_];
  short* dst = AsTg + (size_t)ns*1280;   // [w(32)][v(40)]
  for (int i=tid;i<1280;i+=256) dst[i]=0;
  for (int i=tid;i<V_*V_;i+=256){
    float acc=0.f;
    #pragma unroll
    for (int tcc=0;tcc<NCHUNK;++tcc) acc += attg[((size_t)tcc*(N_*S_) + ns)*(V_*V_) + i];
    att[i]=acc;
  }
  __syncthreads();
  if (tid<V_){
    const int w=tid; const float inv=1.f/(IG*T_);
    float mx=-1e30f;
    for (int v=0;v<V_;++v) mx=fmaxf(mx, att[v*V_+w]*inv);
    float sum=0.f;
    for (int v=0;v<V_;++v){ float e=expf(att[v*V_+w]*inv-mx); att[v*V_+w]=e; sum+=e; }
    float rs=1.f/sum;
    for (int v=0;v<V_;++v) att[v*V_+w]*=rs;
  }
  __syncthreads();
  const float alpha=alphap[0];
  for (int i=tid;i<V_*V_;i+=256){
    int v=i/25, w=i%25;
    dst[w*40+v] = (short)f2bu(A[s*625+i] + alpha*att[i]);
  }
}

// ---------------- K2: 4-t tile MFMA graph conv + Wf + bn + residual + relu ----------------
__global__ __launch_bounds__(256) void k_gcn_y(
    const float* __restrict__ x, const short* __restrict__ AsTg,
    const short* __restrict__ Wfb, const float* __restrict__ bfp,
    const float* __restrict__ g_gamma, const float* __restrict__ g_beta,
    __hip_bfloat16* __restrict__ y1)
{
  const int tc=blockIdx.x, n=blockIdx.y, tid=threadIdx.x;
  const int wv=tid>>6, l=tid&63, lc=l&15, lk=l>>4;
  __shared__ __align__(16) short xtb[64*136];   // [c][t*32+v], v-pad zeroed
  __shared__ __align__(16) short AsT[3*32*40];
  __shared__ __align__(16) short aggT[112*200];
  const float* xn = x + (size_t)n*C_*TV;
  const int tv0 = tc*100;
  float4 xbuf[7];
  #pragma unroll
  for (int k=0;k<7;++k){
    int i = tid + k*256;
    if (i < 1600){
      int c=i/25, a=i%25;
      xbuf[k] = *(const float4*)(xn + (size_t)c*TV + tv0 + a*4);
    }
  }
  #pragma unroll
  for (int k=0;k<7;++k){
    int i = tid + k*256;
    if (i < 1600){
      int c=i/25, a=i%25, tv4=a*4;
      float xv[4] = {xbuf[k].x, xbuf[k].y, xbuf[k].z, xbuf[k].w};
      #pragma unroll
      for (int j=0;j<4;++j){
        int tv=tv4+j, t=tv/25, v=tv-t*25;
        xtb[c*136 + t*32 + v] = (short)f2bu(xv[j]);
      }
    }
  }
  for (int i=tid;i<64*28;i+=256){ int c=i/28, r=i%28; xtb[c*136 + (r/7)*32 + 25 + (r%7)] = 0; }
  {
    const short* As_g = AsTg + (size_t)n*3840;
    for (int i=tid;i<480;i+=256)
      *(short8v*)(AsT + i*8) = *(const short8v*)(As_g + i*8);
  }
  for (int i=tid;i<12*200;i+=256) aggT[100*200+i]=0;
  __syncthreads();
  {
    const int t = wv;
    for (int s=0;s<S_;++s){
      short8v b0 = *(const short8v*)(AsT + (s*32+lc)*40 + lk*8);
      short8v b1 = *(const short8v*)(AsT + (s*32+16+lc)*40 + lk*8);
      #pragma unroll
      for (int mt=0;mt<4;++mt){
        short8v a = *(const short8v*)(xtb + (mt*16+lc)*136 + t*32 + lk*8);
        f32x4 z={0.f,0.f,0.f,0.f};
        f32x4 acc0 = MFMA16(a,b0,z,0,0,0);
        f32x4 acc1 = MFMA16(a,b1,z,0,0,0);
        *(unsigned long long*)(aggT + (t*25+lc)*200 + s*64 + mt*16 + lk*4) = pk4bf(acc0);
        if (lc<9)
          *(unsigned long long*)(aggT + (t*25+16+lc)*200 + s*64 + mt*16 + lk*4) = pk4bf(acc1);
      }
    }
  }
  short8v af[6];
  #pragma unroll
  for (int ks=0;ks<6;++ks){
    const int s = ks>>1, c0 = (ks&1)*32 + lk*8;
    af[ks] = *(const short8v*)(Wfb + (size_t)(s*C_ + wv*16+lc)*C_ + c0);
  }
  __syncthreads();
  f32x4 acc[7];
  #pragma unroll
  for (int dt=0;dt<7;++dt) acc[dt]=(f32x4){0.f,0.f,0.f,0.f};
  #pragma unroll
  for (int dt=0;dt<7;++dt){
    #pragma unroll
    for (int ks=0;ks<6;++ks){
      short8v b = *(const short8v*)(aggT + (dt*16+lc)*200 + ks*32 + lk*8);
      acc[dt] = MFMA16(af[ks], b, acc[dt],0,0,0);
    }
  }
  const float invs = rsqrtf(1.f+EPSB);
  __hip_bfloat16* yo = y1 + (size_t)n*C_*TV;
  #pragma unroll
  for (int reg=0;reg<4;++reg){
    const int o = wv*16 + lk*4 + reg;
    const float bsum = bfp[o]+bfp[C_+o]+bfp[2*C_+o];
    const float gs = g_gamma[o]*invs, gb = g_beta[o];
    #pragma unroll
    for (int dt=0;dt<7;++dt){
      const int tv = dt*16 + lc;
      if (tv < 100){
        const int t = tv/25, v = tv - t*25;
        float xres = sh2f(xtb[o*136 + t*32 + v]);   // residual from LDS-staged x
        float val = (acc[dt][reg]+bsum)*gs + gb + xres;
        yo[(size_t)o*TV + tv0 + tv] = f2b(fmaxf(val,0.f));
      }
    }
  }
}

// ---------------- K3a: seT[n,c,v] = mean_t y1 ----------------
__global__ __launch_bounds__(256) void k_seT(const __hip_bfloat16* __restrict__ y1,
    float* __restrict__ seT)
{
  const int c=blockIdx.x, n=blockIdx.y, tid=threadIdx.x;
  const int v = tid&31, g = tid>>5;
  __shared__ float red[8][33];
  const __hip_bfloat16* yp = y1 + ((size_t)n*C_+c)*T_*V_;
  float s=0.f;
  if (v < V_){
    #pragma unroll 4
    for (int j=0;j<16;++j){
      int t = g + j*8;
      s += b2f(yp[t*V_+v]);
    }
  }
  red[g][v]=s;
  __syncthreads();
  if (tid < V_){
    float tot=0.f;
    #pragma unroll
    for (int g2=0;g2<8;++g2) tot += red[g2][tid];
    seT[((size_t)n*C_+c)*V_+tid]=tot*(1.f/T_);
  }
}

// ---------------- K3b: sa[n,v] spatial gate (LDS-staged, c-split) ----------------
__global__ __launch_bounds__(256) void k_sa(const float* __restrict__ seT,
    const float* __restrict__ W_sa, const float* __restrict__ b_sa,
    float* __restrict__ sa)
{
  const int n=blockIdx.x, tid=threadIdx.x;
  __shared__ float sel[CV];
  __shared__ float wsl[CV];
  __shared__ float part[8][32];
  const float* se = seT + (size_t)n*C_*V_;
  for (int i=tid;i<CV;i+=256){ sel[i]=se[i]; wsl[i]=W_sa[i]; }
  __syncthreads();
  if (tid < 200){
    const int v = tid%25, cg = tid/25;
    float acc=0.f;
    for (int c=cg*8;c<cg*8+8;++c){
      #pragma unroll
      for (int k=0;k<V_;++k){
        int vv=v+k-12;
        if (vv>=0&&vv<V_) acc += sel[c*V_+vv]*wsl[c*V_+k];
      }
    }
    part[cg][v]=acc;
  }
  __syncthreads();
  if (tid<V_){
    float acc=b_sa[0];
    #pragma unroll
    for (int g=0;g<8;++g) acc+=part[g][tid];
    sa[n*V_+tid]=sigm(acc);
  }
}

// ---------------- K3c: seV[n,c,t] = mean_v y1*(1+sa) ----------------
__global__ __launch_bounds__(256) void k_seV(const __hip_bfloat16* __restrict__ y1,
    const float* __restrict__ sa, float* __restrict__ seV)
{
  const int c=blockIdx.x, n=blockIdx.y, tid=threadIdx.x;
  const int v = tid&31, g = tid>>5;
  __shared__ float sal[32];
  if (tid<32) sal[tid] = (tid<V_)? 1.f+sa[n*V_+tid] : 0.f;
  __syncthreads();
  const __hip_bfloat16* yp = y1 + ((size_t)n*C_+c)*T_*V_;
  float* svo = seV + ((size_t)n*C_+c)*T_;
  const float sv_ = sal[v];
  for (int j=0;j<16;++j){
    int t = g*16 + j;
    float val = (v<V_)? b2f(yp[t*V_+v])*sv_ : 0.f;
    #pragma unroll
    for (int off=16;off;off>>=1) val += __shfl_xor(val, off);
    if (v==0) svo[t]=val*(1.f/V_);
  }
}

// ---------------- K3d: ta + ca gates (LDS-staged, split reductions) ----------------
__global__ __launch_bounds__(256) void k_ta_ca(const float* __restrict__ seV,
    const float* __restrict__ W_ta, const float* __restrict__ b_ta,
    const float* __restrict__ W_fc1, const float* __restrict__ b_fc1,
    const float* __restrict__ W_fc2, const float* __restrict__ b_fc2,
    float* __restrict__ ta, float* __restrict__ ca)
{
  const int n=blockIdx.x, tid=threadIdx.x;
  __shared__ float svl[C_*T_];
  __shared__ float wtl[C_*9];
  __shared__ float w1l[32*C_];
  __shared__ float w2l[C_*32];
  __shared__ float tal[T_];
  __shared__ float part2[2][T_];
  __shared__ float part4[C_][4];
  __shared__ float scls[C_];
  __shared__ float h1[32];
  const float* sv = seV + (size_t)n*C_*T_;
  for (int i=tid;i<C_*T_;i+=256) svl[i]=sv[i];
  for (int i=tid;i<C_*9;i+=256) wtl[i]=W_ta[i];
  for (int i=tid;i<32*C_;i+=256){ w1l[i]=W_fc1[i]; w2l[i]=W_fc2[i]; }
  __syncthreads();
  {
    const int t = tid & 127, half = tid >> 7;
    float acc = 0.f;
    for (int c=half*32; c<half*32+32; ++c){
      #pragma unroll
      for (int k=0;k<9;++k){
        int tt=t+k-4;
        if (tt>=0&&tt<T_) acc += svl[c*T_+tt]*wtl[c*9+k];
      }
    }
    part2[half][t]=acc;
  }
  __syncthreads();
  if (tid<T_){
    float s_=sigm(part2[0][tid]+part2[1][tid]+b_ta[0]);
    tal[tid]=s_; ta[n*T_+tid]=s_;
  }
  __syncthreads();
  {
    const int c = tid>>2, q = tid&3;
    float acc=0.f;
    for (int t=q*32;t<q*32+32;++t) acc += svl[c*T_+t]*(1.f+tal[t]);
    part4[c][q]=acc;
  }
  __syncthreads();
  if (tid<C_) scls[tid]=(part4[tid][0]+part4[tid][1]+part4[tid][2]+part4[tid][3])*(1.f/T_);
  __syncthreads();
  if (tid<32){
    float acc=b_fc1[tid];
    for (int c=0;c<C_;++c) acc += scls[c]*w1l[tid*C_+c];
    h1[tid]=fmaxf(acc,0.f);
  }
  __syncthreads();
  if (tid<C_){
    float acc=b_fc2[tid];
    for (int j=0;j<32;++j) acc += h1[j]*w2l[tid*32+j];
    ca[n*C_+tid]=sigm(acc);
  }
}

// ---------------- K4: 4-t tile MFMA xa/gates + q/k/v projections ----------------
__global__ __launch_bounds__(256) void k_xa_qkv(
    const __hip_bfloat16* __restrict__ y1, const float* __restrict__ pos_emb,
    const float* __restrict__ sa, const float* __restrict__ ta, const float* __restrict__ ca,
    const short* __restrict__ w3b, const float* __restrict__ bq_h,
    const float* __restrict__ bk_h, const float* __restrict__ bv_h,
    __hip_bfloat16* __restrict__ xa, __hip_bfloat16* __restrict__ qb,
    __hip_bfloat16* __restrict__ kb, __hip_bfloat16* __restrict__ vb)
{
  const int tc=blockIdx.x, n=blockIdx.y, tid=threadIdx.x;
  const int wv=tid>>6, l=tid&63, lc=l&15, lk=l>>4;
  __shared__ __align__(16) short w3[192*72];
  __shared__ __align__(16) short xalT[4][32*72];
  __shared__ float bl[192];
  __shared__ float sal[32], cal[64], tgs[4];
  const int tv0 = tc*100;
  const __hip_bfloat16* y1n = y1 + (size_t)n*C_*TV;
  __hip_bfloat16* xan = xa + (size_t)n*C_*TV;
  uint2 ybuf[7];
  #pragma unroll
  for (int k=0;k<7;++k){
    int i = tid + k*256;
    if (i < 1600){
      int c=i/25, a=i%25;
      ybuf[k] = *(const uint2*)(y1n + (size_t)c*TV + tv0 + a*4);
    }
  }
  for (int i=tid;i<1536;i+=256){
    int mu=i>>3, j=i&7;
    *(short8v*)(w3 + mu*72 + j*8) = *(const short8v*)(w3b + mu*64 + j*8);
  }
  if (tid<192){
    int which=tid/C_, ho=tid%C_;
    bl[tid] = (which==0?bq_h:(which==1?bk_h:bv_h))[ho];
  }
  if (tid<32) sal[tid] = (tid<V_)? 1.f+sa[n*V_+tid] : 0.f;
  if (tid>=32 && tid<96) cal[tid-32] = 1.f+ca[n*C_+tid-32];
  if (tid>=96 && tid<100) tgs[tid-96] = 1.f+ta[n*T_+tc*4+(tid-96)];
  for (int i=tid;i<4*7*72;i+=256){
    int tl=i/(7*72), r=i%(7*72);
    xalT[tl][25*72 + r] = 0;
  }
  __syncthreads();
  #pragma unroll
  for (int k=0;k<7;++k){
    int i = tid + k*256;
    if (i < 1600){
      int c=i/25, a=i%25, tv4=a*4;
      unsigned int u0=ybuf[k].x, u1=ybuf[k].y;
      float yv[4] = {ubl(u0),ubh(u0),ubl(u1),ubh(u1)};
      const float calc = cal[c];
      unsigned long long pack = 0ull;
      #pragma unroll
      for (int j=0;j<4;++j){
        int tv=tv4+j, tl=tv/25, v=tv-tl*25;
        float val = yv[j]*sal[v]*tgs[tl]*calc + pos_emb[(size_t)(tc*4+tl)*CV + c*V_ + v];
        unsigned short b = f2bu(val);
        pack |= (unsigned long long)b << (16*j);
        xalT[tl][v*72 + c] = (short)b;
      }
      *(unsigned long long*)(xan + (size_t)c*TV + tv0 + tv4) = pack;
    }
  }
  __syncthreads();
  const int t = tc*4 + wv;
  short8v bf_[2][2];
  #pragma unroll
  for (int ks=0;ks<2;++ks){
    bf_[ks][0] = *(const short8v*)(&xalT[wv][lc*72      + ks*32 + lk*8]);
    bf_[ks][1] = *(const short8v*)(&xalT[wv][(16+lc)*72 + ks*32 + lk*8]);
  }
  #pragma unroll
  for (int mt=0;mt<12;++mt){
    f32x4 acc0 = {0.f,0.f,0.f,0.f}, acc1 = {0.f,0.f,0.f,0.f};
    #pragma unroll
    for (int ks=0;ks<2;++ks){
      short8v a = *(const short8v*)(w3 + (mt*16+lc)*72 + ks*32 + lk*8);
      acc0 = MFMA16(a, bf_[ks][0], acc0,0,0,0);
      acc1 = MFMA16(a, bf_[ks][1], acc1,0,0,0);
    }
    #pragma unroll
    for (int reg=0;reg<4;++reg){
      const int mu = mt*16 + lk*4 + reg;
      const int which = mt>>2;
      const int ho = mu & 63, h = ho>>3, o = ho&7;
      __hip_bfloat16* dst = (which==0?qb:(which==1?kb:vb))
                            + (((size_t)n*H_+h)*T_+t)*D_ + o*V_;
      const float bb = bl[mu];
      dst[lc] = f2b(acc0[reg]+bb);
      if (lc < 9) dst[16+lc] = f2b(acc1[reg]+bb);
    }
  }
}

// ---------------- K5: MFMA flash causal MHA ----------------
__global__ __launch_bounds__(256) void k_attn(
    const __hip_bfloat16* __restrict__ qb, const __hip_bfloat16* __restrict__ kb,
    const __hip_bfloat16* __restrict__ vb, __hip_bfloat16* __restrict__ oh)
{
  const int bx = blockIdx.x;
  const int hh = blockIdx.y;
  const int n  = blockIdx.z;
  const int nh = n*H_ + hh;
  const int tid = threadIdx.x;
  const int wv = tid>>6, l = tid&63;
  const int lc = l&15, lg = l>>4;
  __shared__ __align__(16) char KlB[32*512];
  __shared__ __align__(16) short VT[208*40];
  __shared__ __align__(16) short Pl[64*40];
  const __hip_bfloat16* qg_ = qb + (size_t)nh*T_*D_;
  const __hip_bfloat16* kg_ = kb + (size_t)nh*T_*D_;
  const __hip_bfloat16* vg_ = vb + (size_t)nh*T_*D_;
  __hip_bfloat16* ohn = oh + (size_t)n*C_*TV;
  const float scale = 0.0707106781f;

  for (int i=tid;i<32*12;i+=256){
    int key=i/12, j=i%12;
    *(unsigned int*)(KlB + ((key*512 + 400 + j*4) ^ ((key&7)<<4))) = 0u;
  }
  for (int i=tid;i<8*40;i+=256) VT[200*40 + i] = 0;

  const int qrow = bx*64 + wv*16 + lc;
  short8v qf[7];
  {
    const short8v* qs8 = (const short8v*)(qg_ + (size_t)qrow*D_);
    #pragma unroll
    for (int ks=0;ks<7;++ks) qf[ks] = qs8[ks*4 + lg];
  }
  f32x4 oacc[13];
  #pragma unroll
  for (int i=0;i<13;++i) oacc[i] = (f32x4){0.f,0.f,0.f,0.f};
  float m[4], lsm[4];
  #pragma unroll
  for (int r=0;r<4;++r){ m[r]=-1e30f; lsm[r]=0.f; }

  const int ntiles = (bx==0)? 2 : 4;
  for (int kt=0; kt<ntiles; ++kt){
    const int j0 = kt*32;
    __syncthreads();
    {
      const short8v* ks8 = (const short8v*)(kg_ + (size_t)j0*D_);
      for (int i=tid;i<32*25;i+=256){
        int row=i/25, w=i%25;
        *(short8v*)(KlB + ((row*512 + w*16) ^ ((row&7)<<4))) = ks8[i];
      }
      const short8v* vs8 = (const short8v*)(vg_ + (size_t)j0*D_);
      for (int i=tid;i<32*25;i+=256){
        int row=i&31, w4=i>>5;
        short8v u = vs8[row*25 + w4];
        #pragma unroll
        for (int j=0;j<8;++j) VT[(w4*8+j)*40 + row] = u[j];
      }
    }
    __syncthreads();
    const bool active = (j0 <= bx*64 + wv*16 + 15);
    if (active){
      f32x4 s0 = {0.f,0.f,0.f,0.f}, s1 = {0.f,0.f,0.f,0.f};
      #pragma unroll
      for (int ks=0;ks<7;++ks){
        short8v b0 = *(const short8v*)(KlB + ((lc*512      + ks*64 + lg*16) ^ ((lc&7)<<4)));
        short8v b1 = *(const short8v*)(KlB + (((16+lc)*512 + ks*64 + lg*16) ^ ((lc&7)<<4)));
        s0 = MFMA16(qf[ks], b0, s0,0,0,0);
        s1 = MFMA16(qf[ks], b1, s1,0,0,0);
      }
      float fr[4];
      #pragma unroll
      for (int r=0;r<4;++r){
        const int qg = bx*64 + wv*16 + lg*4 + r;
        float v0 = (j0+lc    <= qg) ? s0[r]*scale : -1e30f;
        float v1 = (j0+16+lc <= qg) ? s1[r]*scale : -1e30f;
        float mx = fmaxf(v0,v1);
        #pragma unroll
        for (int off=1;off<16;off<<=1) mx = fmaxf(mx, __shfl_xor(mx, off));
        float mn = fmaxf(m[r], mx);
        fr[r] = __expf(m[r]-mn);
        float p0 = __expf(v0-mn), p1 = __expf(v1-mn);
        float ts = p0+p1;
        #pragma unroll
        for (int off=1;off<16;off<<=1) ts += __shfl_xor(ts, off);
        lsm[r] = lsm[r]*fr[r] + ts;
        m[r] = mn;
        Pl[(wv*16 + lg*4 + r)*40 + lc]      = (short)f2bu(p0);
        Pl[(wv*16 + lg*4 + r)*40 + 16 + lc] = (short)f2bu(p1);
      }
      #pragma unroll
      for (int dt=0;dt<13;++dt){
        #pragma unroll
        for (int r=0;r<4;++r) oacc[dt][r] *= fr[r];
      }
      short8v pa = *(const short8v*)(Pl + (wv*16+lc)*40 + lg*8);
      #pragma unroll
      for (int dt=0;dt<13;++dt){
        short8v b = *(const short8v*)(VT + (dt*16+lc)*40 + lg*8);
        oacc[dt] = MFMA16(pa, b, oacc[dt],0,0,0);
      }
    }
  }
  float rl[4];
  #pragma unroll
  for (int r=0;r<4;++r) rl[r] = 1.f/lsm[r];
  #pragma unroll
  for (int dt=0;dt<13;++dt){
    const int d = dt*16 + lc;
    if (d < D_){
      const int oi = d/25, v = d - oi*25;
      const int c = hh*IH + oi;
      #pragma unroll
      for (int r=0;r<4;++r){
        const int q = bx*64 + wv*16 + lg*4 + r;
        ohn[(size_t)c*TV + q*V_ + v] = f2b(oacc[dt][r]*rl[r]);
      }
    }
  }
}

// ---------------- K7: 8-t tile MFMA out kernel (coalesced transposed epilogue) ----------------
__global__ __launch_bounds__(256) void k_out(
    const __hip_bfloat16* __restrict__ oh, const __hip_bfloat16* __restrict__ xa,
    const float* __restrict__ x, const short* __restrict__ Wffnb,
    const float* __restrict__ b_ffn, const float* __restrict__ m_gamma,
    const float* __restrict__ m_beta, float* __restrict__ out)
{
  const int tc = blockIdx.x, n = blockIdx.y, tid = threadIdx.x;
  const int wv = tid>>6, l = tid&63, lc = l&15, lg = l>>4;
  __shared__ __align__(16) short zT[208*72];
  __shared__ float bn_s[64], bn_b[64], bff[64];
  const float invs = rsqrtf(1.f+EPSB);
  if (tid<64){ bn_s[tid]=m_gamma[tid]*invs; bn_b[tid]=m_beta[tid]; bff[tid]=b_ffn[tid]; }
  for (int i=tid;i<8*72;i+=256) zT[200*72+i]=0;
  const int tv0 = tc*200;
  const __hip_bfloat16* xan = xa + (size_t)n*C_*TV;
  const __hip_bfloat16* ohn = oh + (size_t)n*C_*TV;
  uint4 xbuf[7], obuf[7];
  #pragma unroll
  for (int k=0;k<7;++k){
    int i = tid + k*256;
    if (i < 1600){
      int c=i/25, a=i%25;
      xbuf[k] = *(const uint4*)(xan + (size_t)c*TV + tv0 + a*8);
      obuf[k] = *(const uint4*)(ohn + (size_t)c*TV + tv0 + a*8);
    }
  }
  __syncthreads();
  #pragma unroll
  for (int k=0;k<7;++k){
    int i = tid + k*256;
    if (i < 1600){
      int c=i/25, a=i%25, tv8=a*8;
      const float s_=bn_s[c], b_=bn_b[c];
      const unsigned int* xu = (const unsigned int*)&xbuf[k];
      const unsigned int* ou = (const unsigned int*)&obuf[k];
      #pragma unroll
      for (int j=0;j<4;++j){
        zT[ZIDX(tv8+2*j,   c)] = (short)f2bu(s_*ubl(ou[j]) + b_ + ubl(xu[j]));
        zT[ZIDX(tv8+2*j+1, c)] = (short)f2bu(s_*ubh(ou[j]) + b_ + ubh(xu[j]));
      }
    }
  }
  __syncthreads();
  short8v af0 = *(const short8v*)(Wffnb + (wv*16+lc)*64 + lg*8);
  short8v af1 = *(const short8v*)(Wffnb + (wv*16+lc)*64 + 32 + lg*8);
  f32x4 acc[13];
  #pragma unroll
  for (int dt=0;dt<13;++dt) acc[dt] = (f32x4){0.f,0.f,0.f,0.f};
  #pragma unroll
  for (int dt=0;dt<13;++dt){
    short8v b0 = *(const short8v*)(zT + ZIDX(dt*16+lc, lg*8));
    short8v b1 = *(const short8v*)(zT + ZIDX(dt*16+lc, 32+lg*8));
    acc[dt] = MFMA16(af0, b0, acc[dt],0,0,0);
    acc[dt] = MFMA16(af1, b1, acc[dt],0,0,0);
  }
  __syncthreads();   // zT fully consumed by all waves
  // store FFN pre-bias output back into zT (bf16), layout [tv][o]
  #pragma unroll
  for (int dt=0;dt<13;++dt){
    const int tv = dt*16 + lc;
    if (tv < 200){
      #pragma unroll
      for (int reg=0;reg<4;++reg){
        const int o = wv*16 + lg*4 + reg;
        zT[ZIDX(tv, o)] = (short)f2bu(acc[dt][reg]);
      }
    }
  }
  __syncthreads();
  // ---- coalesced epilogue: thread = (c, 4-tv chunk) ----
  const float* xn = x + (size_t)n*C_*TV;
  float* outn = out + (size_t)n*C_*TV;
  for (int ii=tid; ii<3200; ii+=256){
    const int c = ii/50, a = ii%50, tv4 = a*4;
    uint2 xu = *(const uint2*)(xan + (size_t)c*TV + tv0 + tv4);
    float4 xf4 = *(const float4*)(xn + (size_t)c*TV + tv0 + tv4);
    float xa4[4] = {ubl(xu.x),ubh(xu.x),ubl(xu.y),ubh(xu.y)};
    float xf[4] = {xf4.x,xf4.y,xf4.z,xf4.w};
    const float s_=bn_s[c], b_=bn_b[c], bf_=bff[c];
    float4 o4;
    float res[4];
    #pragma unroll
    for (int j=0;j<4;++j){
      float f = sh2f(zT[ZIDX(tv4+j, c)]);
      float z2 = fmaxf(f + bf_, 0.f) + xa4[j];
      float z3 = s_*z2 + b_;
      res[j] = fmaxf(z3 + xf[j], 0.f);
    }
    o4.x=res[0]; o4.y=res[1]; o4.z=res[2]; o4.w=res[3];
    *(float4*)(outn + (size_t)c*TV + tv0 + tv4) = o4;
  }
}

extern "C" void kernel_launch(void* const* d_in, const int* in_sizes, int n_in,
                              void* d_out, int out_size, void* d_ws, size_t ws_size,
                              hipStream_t stream) {
  const float* x      = (const float*)d_in[0];
  const float* A      = (const float*)d_in[1];
  const float* alphap = (const float*)d_in[2];
  const float* Wq     = (const float*)d_in[3];
  const float* bq     = (const float*)d_in[4];
  const float* Wk     = (const float*)d_in[5];
  const float* bk     = (const float*)d_in[6];
  const float* Wf     = (const float*)d_in[7];
  const float* bfp    = (const float*)d_in[8];
  const float* g_gamma= (const float*)d_in[9];
  const float* g_beta = (const float*)d_in[10];
  const float* W_sa   = (const float*)d_in[11];
  const float* b_sa   = (const float*)d_in[12];
  const float* W_ta   = (const float*)d_in[13];
  const float* b_ta   = (const float*)d_in[14];
  const float* W_fc1  = (const float*)d_in[15];
  const float* b_fc1  = (const float*)d_in[16];
  const float* W_fc2  = (const float*)d_in[17];
  const float* b_fc2  = (const float*)d_in[18];
  const float* pos_emb= (const float*)d_in[19];
  const float* Wq_h   = (const float*)d_in[20];
  const float* bq_h   = (const float*)d_in[21];
  const float* Wk_h   = (const float*)d_in[22];
  const float* bk_h   = (const float*)d_in[23];
  const float* Wv_h   = (const float*)d_in[24];
  const float* bv_h   = (const float*)d_in[25];
  const float* W_ffn  = (const float*)d_in[26];
  const float* b_ffn  = (const float*)d_in[27];
  const float* m_gamma= (const float*)d_in[28];
  const float* m_beta = (const float*)d_in[29];
  float* out = (float*)d_out;

  float* ws   = (float*)d_ws;
  float* seT  = ws;                    // 204800
  float* seV  = seT + 204800;          // 1048576
  float* sa   = seV + 1048576;         // 3200
  float* ta   = sa  + 3200;            // 16384
  float* ca   = ta  + 16384;           // 8192
  short* wsh  = (short*)(ca + 8192);
  short* AsTg = wsh;                   // 491520
  short* wqb  = AsTg + 491520;
  short* wkb  = wqb + 3072;
  short* Wfb  = wkb + 3072;
  short* w3b  = Wfb + 12288;
  short* Wffnb= w3b + 12288;
  __hip_bfloat16* y1 = (__hip_bfloat16*)(Wffnb + 4096);
  __hip_bfloat16* xa = y1 + (size_t)26214400;
  __hip_bfloat16* qb = xa + (size_t)26214400;
  __hip_bfloat16* kb = qb + (size_t)26214400;
  __hip_bfloat16* vb = kb + (size_t)26214400;
  __hip_bfloat16* oh = y1;   // reuse
  float* attg = (float*)y1;  // scratch before y1 written

  k_prep<<<48, 256, 0, stream>>>(Wq, Wk, Wf, Wq_h, Wk_h, Wv_h, W_ffn,
                                 wqb, wkb, Wfb, w3b, Wffnb);
  k_gcn_att1<<<dim3(16, N_), 256, 0, stream>>>(x, wqb, bq, wkb, bk, attg);
  k_gcn_att2<<<N_*S_, 256, 0, stream>>>(attg, A, alphap, AsTg);
  k_gcn_y<<<dim3(T_/4, N_), 256, 0, stream>>>(x, AsTg, Wfb, bfp, g_gamma, g_beta, y1);
  k_seT<<<dim3(C_, N_), 256, 0, stream>>>(y1, seT);
  k_sa<<<N_, 256, 0, stream>>>(seT, W_sa, b_sa, sa);
  k_seV<<<dim3(C_, N_), 256, 0, stream>>>(y1, sa, seV);
  k_ta_ca<<<N_, 256, 0, stream>>>(seV, W_ta, b_ta, W_fc1, b_fc1, W_fc2, b_fc2, ta, ca);
  k_xa_qkv<<<dim3(T_/4, N_), 256, 0, stream>>>(y1, pos_emb, sa, ta, ca,
      w3b, bq_h, bk_h, bv_h, xa, qb, kb, vb);
  k_attn<<<dim3(2, H_, N_), 256, 0, stream>>>(qb, kb, vb, oh);
  k_out<<<dim3(T_/8, N_), 256, 0, stream>>>(oh, xa, x, Wffnb, b_ffn, m_gamma, m_beta, out);
}

// Round 16
// 431.487 us; speedup vs baseline: 1.7839x; 1.0377x over previous
//
#include <hip/hip_runtime.h>
#include <hip/hip_bf16.h>

#define N_ 128
#define C_ 64
#define T_ 128
#define V_ 25
#define S_ 3
#define IG 16
#define IH 8
#define H_ 8
#define D_ 200   // IH*V
#define CV 1600  // C_*V_
#define TV 3200  // T_*V_
#define EPSB 1e-5f
#define NCHUNK 16

typedef __attribute__((ext_vector_type(8))) short short8v;
typedef __attribute__((ext_vector_type(4))) float f32x4;
#define MFMA16 __builtin_amdgcn_mfma_f32_16x16x32_bf16
#define ZIDX(r,c) ((r)*72 + ((c) ^ ((((r)>>3)&7)<<3)))

__device__ __forceinline__ float sigm(float x){ return 1.f/(1.f+expf(-x)); }
__device__ __forceinline__ float b2f(__hip_bfloat16 b){ return __bfloat162float(b); }
__device__ __forceinline__ __hip_bfloat16 f2b(float f){ return __float2bfloat16(f); }
__device__ __forceinline__ float ubl(unsigned int u){ return __uint_as_float(u<<16); }
__device__ __forceinline__ float ubh(unsigned int u){ return __uint_as_float(u & 0xffff0000u); }
__device__ __forceinline__ float sh2f(short s){ return __uint_as_float(((unsigned int)(unsigned short)s)<<16); }
__device__ __forceinline__ unsigned short f2bu(float f){
  unsigned int u = __float_as_uint(f);
  u += 0x7fff + ((u>>16)&1);
  return (unsigned short)(u>>16);
}
__device__ __forceinline__ unsigned long long pk4bf(f32x4 v){
  unsigned long long a = f2bu(v[0]);
  unsigned long long b = f2bu(v[1]);
  unsigned long long c = f2bu(v[2]);
  unsigned long long d = f2bu(v[3]);
  return a | (b<<16) | (c<<32) | (d<<48);
}

// ---------------- K0: one-shot weight f32->bf16 conversion ----------------
__global__ __launch_bounds__(256) void k_prep(
    const float* __restrict__ Wq, const float* __restrict__ Wk,
    const float* __restrict__ Wf,
    const float* __restrict__ Wq_h, const float* __restrict__ Wk_h,
    const float* __restrict__ Wv_h, const float* __restrict__ W_ffn,
    short* __restrict__ wqb, short* __restrict__ wkb, short* __restrict__ Wfb,
    short* __restrict__ w3b, short* __restrict__ Wffnb)
{
  const int i = blockIdx.x*256 + threadIdx.x;
  if (i < 3072){ wqb[i]=(short)f2bu(Wq[i]); wkb[i]=(short)f2bu(Wk[i]); }
  if (i < 12288) Wfb[i]=(short)f2bu(Wf[i]);
  if (i < 4096){
    w3b[i]      =(short)f2bu(Wq_h[i]);
    w3b[4096+i] =(short)f2bu(Wk_h[i]);
    w3b[8192+i] =(short)f2bu(Wv_h[i]);
    Wffnb[i]    =(short)f2bu(W_ffn[i]);
  }
}

// ---------------- K1a: MFMA graph attention partials, merged over s ----------------
__global__ __launch_bounds__(256) void k_gcn_att1(
    const float* __restrict__ x,
    const short* __restrict__ wqb, const float* __restrict__ bq,
    const short* __restrict__ wkb, const float* __restrict__ bk,
    float* __restrict__ attg)
{
  const int tc = blockIdx.x, n = blockIdx.y;
  const int tid = threadIdx.x;
  const int wv = tid>>6, l = tid&63, lc = l&15, lk = l>>4;
  __shared__ __align__(16) short xtb[4*32*72];   // [tl][v(32)][c(72)], v>=25 zeroed
  __shared__ __align__(16) char QB[3*32*256];    // per s: [v][K=128 bf16], byte^=(v&7)<<4
  __shared__ __align__(16) char KB[3*32*256];
  __shared__ float bql[48], bkl[48];
  short8v aqf[3][2], akf[3][2];
  #pragma unroll
  for (int s=0;s<3;++s){
    #pragma unroll
    for (int ks=0;ks<2;++ks){
      aqf[s][ks] = *(const short8v*)(wqb + (s*16+lc)*64 + ks*32 + lk*8);
      akf[s][ks] = *(const short8v*)(wkb + (s*16+lc)*64 + ks*32 + lk*8);
    }
  }
  if (tid<48){ bql[tid]=bq[tid]; bkl[tid]=bk[tid]; }
  for (int i=tid;i<4*7*72;i+=256){
    int tl=i/(7*72), r=i%(7*72);
    xtb[(tl*32+25)*72 + r] = 0;
  }
  const float* xn = x + (size_t)n*C_*TV;
  #pragma unroll
  for (int tg=0; tg<2; ++tg){
    if (tg) __syncthreads();
    {
      const int base = tc*200 + tg*100;
      float4 xb[7];
      #pragma unroll
      for (int k=0;k<7;++k){
        int i = tid + k*256;
        if (i<1600){ int c=i/25,a=i%25; xb[k] = *(const float4*)(xn + (size_t)c*TV + base + a*4); }
      }
      #pragma unroll
      for (int k=0;k<7;++k){
        int i = tid + k*256;
        if (i<1600){
          int c=i/25,a=i%25;
          float xv[4]={xb[k].x,xb[k].y,xb[k].z,xb[k].w};
          #pragma unroll
          for (int j=0;j<4;++j){
            int tv=a*4+j, tl=tv/25, v=tv-tl*25;
            xtb[(tl*32+v)*72 + c] = (short)f2bu(xv[j]);
          }
        }
      }
    }
    __syncthreads();
    const int tcol = (tg*4+wv)*32;
    const int sw = (lc&7)<<4;
    #pragma unroll
    for (int s=0;s<3;++s){
      f32x4 z={0.f,0.f,0.f,0.f};
      f32x4 aq0=z,aq1=z,ak0=z,ak1=z;
      #pragma unroll
      for (int ks=0;ks<2;++ks){
        short8v b0 = *(const short8v*)(xtb + (wv*32+lc)*72 + ks*32 + lk*8);
        short8v b1 = *(const short8v*)(xtb + (wv*32+16+lc)*72 + ks*32 + lk*8);
        aq0 = MFMA16(aqf[s][ks], b0, aq0,0,0,0);
        aq1 = MFMA16(aqf[s][ks], b1, aq1,0,0,0);
        ak0 = MFMA16(akf[s][ks], b0, ak0,0,0,0);
        ak1 = MFMA16(akf[s][ks], b1, ak1,0,0,0);
      }
      f32x4 q0,q1,k0,k1;
      #pragma unroll
      for (int r=0;r<4;++r){
        float bqv=bql[s*16+lk*4+r], bkv=bkl[s*16+lk*4+r];
        q0[r]=aq0[r]+bqv; q1[r]=aq1[r]+bqv;
        k0[r]=ak0[r]+bkv; k1[r]=ak1[r]+bkv;
      }
      char* QBs = QB + s*8192;
      char* KBs = KB + s*8192;
      *(unsigned long long*)(QBs + ((lc*256      + tcol + lk*8) ^ sw)) = pk4bf(q0);
      *(unsigned long long*)(QBs + (((16+lc)*256 + tcol + lk*8) ^ sw)) = pk4bf(q1);
      *(unsigned long long*)(KBs + ((lc*256      + tcol + lk*8) ^ sw)) = pk4bf(k0);
      *(unsigned long long*)(KBs + (((16+lc)*256 + tcol + lk*8) ^ sw)) = pk4bf(k1);
    }
  }
  __syncthreads();
  const int mt = wv>>1, nt = wv&1;
  const int sw = (lc&7)<<4;
  #pragma unroll
  for (int s=0;s<3;++s){
    const char* QBs = QB + s*8192;
    const char* KBs = KB + s*8192;
    f32x4 acc = {0.f,0.f,0.f,0.f};
    #pragma unroll
    for (int ks=0;ks<4;++ks){
      short8v a = *(const short8v*)(QBs + (((mt*16+lc)*256 + ks*64 + lk*16) ^ sw));
      short8v b = *(const short8v*)(KBs + (((nt*16+lc)*256 + ks*64 + lk*16) ^ sw));
      acc = MFMA16(a,b,acc,0,0,0);
    }
    float* Ao = attg + ((size_t)tc*(N_*S_) + n*S_ + s)*(V_*V_);
    #pragma unroll
    for (int reg=0;reg<4;++reg){
      int v = mt*16 + lk*4 + reg, w = nt*16 + lc;
      if (v<V_ && w<V_) Ao[v*V_+w] = acc[reg];
    }
  }
}

// ---------------- K1b: reduce chunks + softmax + write AsTg ----------------
__global__ __launch_bounds__(256) void k_gcn_att2(
    const float* __restrict__ attg, const float* __restrict__ A,
    const float* __restrict__ alphap, short* __restrict__ AsTg)
{
  const int ns = blockIdx.x, s = ns % S_, tid = threadIdx.x;
  __shared__ float att[V_*V_];
  short* dst = AsTg + (size_t)ns*1280;   // [w(32)][v(40)]
  for (int i=tid;i<1280;i+=256) dst[i]=0;
  for (int i=tid;i<V_*V_;i+=256){
    float acc=0.f;
    #pragma unroll
    for (int tcc=0;tcc<NCHUNK;++tcc) acc += attg[((size_t)tcc*(N_*S_) + ns)*(V_*V_) + i];
    att[i]=acc;
  }
  __syncthreads();
  if (tid<V_){
    const int w=tid; const float inv=1.f/(IG*T_);
    float mx=-1e30f;
    for (int v=0;v<V_;++v) mx=fmaxf(mx, att[v*V_+w]*inv);
    float sum=0.f;
    for (int v=0;v<V_;++v){ float e=expf(att[v*V_+w]*inv-mx); att[v*V_+w]=e; sum+=e; }
    float rs=1.f/sum;
    for (int v=0;v<V_;++v) att[v*V_+w]*=rs;
  }
  __syncthreads();
  const float alpha=alphap[0];
  for (int i=tid;i<V_*V_;i+=256){
    int v=i/25, w=i%25;
    dst[w*40+v] = (short)f2bu(A[s*625+i] + alpha*att[i]);
  }
}

// ---------------- K2: 4-t tile MFMA graph conv + Wf + bn + residual + relu ----------------
__global__ __launch_bounds__(256) void k_gcn_y(
    const float* __restrict__ x, const short* __restrict__ AsTg,
    const short* __restrict__ Wfb, const float* __restrict__ bfp,
    const float* __restrict__ g_gamma, const float* __restrict__ g_beta,
    __hip_bfloat16* __restrict__ y1)
{
  const int tc=blockIdx.x, n=blockIdx.y, tid=threadIdx.x;
  const int wv=tid>>6, l=tid&63, lc=l&15, lk=l>>4;
  __shared__ __align__(16) short xtb[64*136];   // [c][t*32+v], v-pad zeroed
  __shared__ __align__(16) short AsT[3*32*40];
  __shared__ __align__(16) short aggT[112*200];
  const float* xn = x + (size_t)n*C_*TV;
  const int tv0 = tc*100;
  float4 xbuf[7];
  #pragma unroll
  for (int k=0;k<7;++k){
    int i = tid + k*256;
    if (i < 1600){
      int c=i/25, a=i%25;
      xbuf[k] = *(const float4*)(xn + (size_t)c*TV + tv0 + a*4);
    }
  }
  #pragma unroll
  for (int k=0;k<7;++k){
    int i = tid + k*256;
    if (i < 1600){
      int c=i/25, a=i%25, tv4=a*4;
      float xv[4] = {xbuf[k].x, xbuf[k].y, xbuf[k].z, xbuf[k].w};
      #pragma unroll
      for (int j=0;j<4;++j){
        int tv=tv4+j, t=tv/25, v=tv-t*25;
        xtb[c*136 + t*32 + v] = (short)f2bu(xv[j]);
      }
    }
  }
  for (int i=tid;i<64*28;i+=256){ int c=i/28, r=i%28; xtb[c*136 + (r/7)*32 + 25 + (r%7)] = 0; }
  {
    const short* As_g = AsTg + (size_t)n*3840;
    for (int i=tid;i<480;i+=256)
      *(short8v*)(AsT + i*8) = *(const short8v*)(As_g + i*8);
  }
  for (int i=tid;i<12*200;i+=256) aggT[100*200+i]=0;
  __syncthreads();
  {
    const int t = wv;
    for (int s=0;s<S_;++s){
      short8v b0 = *(const short8v*)(AsT + (s*32+lc)*40 + lk*8);
      short8v b1 = *(const short8v*)(AsT + (s*32+16+lc)*40 + lk*8);
      #pragma unroll
      for (int mt=0;mt<4;++mt){
        short8v a = *(const short8v*)(xtb + (mt*16+lc)*136 + t*32 + lk*8);
        f32x4 z={0.f,0.f,0.f,0.f};
        f32x4 acc0 = MFMA16(a,b0,z,0,0,0);
        f32x4 acc1 = MFMA16(a,b1,z,0,0,0);
        *(unsigned long long*)(aggT + (t*25+lc)*200 + s*64 + mt*16 + lk*4) = pk4bf(acc0);
        if (lc<9)
          *(unsigned long long*)(aggT + (t*25+16+lc)*200 + s*64 + mt*16 + lk*4) = pk4bf(acc1);
      }
    }
  }
  short8v af[6];
  #pragma unroll
  for (int ks=0;ks<6;++ks){
    const int s = ks>>1, c0 = (ks&1)*32 + lk*8;
    af[ks] = *(const short8v*)(Wfb + (size_t)(s*C_ + wv*16+lc)*C_ + c0);
  }
  __syncthreads();
  f32x4 acc[7];
  #pragma unroll
  for (int dt=0;dt<7;++dt) acc[dt]=(f32x4){0.f,0.f,0.f,0.f};
  #pragma unroll
  for (int dt=0;dt<7;++dt){
    #pragma unroll
    for (int ks=0;ks<6;++ks){
      short8v b = *(const short8v*)(aggT + (dt*16+lc)*200 + ks*32 + lk*8);
      acc[dt] = MFMA16(af[ks], b, acc[dt],0,0,0);
    }
  }
  const float invs = rsqrtf(1.f+EPSB);
  __hip_bfloat16* yo = y1 + (size_t)n*C_*TV;
  #pragma unroll
  for (int reg=0;reg<4;++reg){
    const int o = wv*16 + lk*4 + reg;
    const float bsum = bfp[o]+bfp[C_+o]+bfp[2*C_+o];
    const float gs = g_gamma[o]*invs, gb = g_beta[o];
    #pragma unroll
    for (int dt=0;dt<7;++dt){
      const int tv = dt*16 + lc;
      if (tv < 100){
        const int t = tv/25, v = tv - t*25;
        float xres = sh2f(xtb[o*136 + t*32 + v]);
        float val = (acc[dt][reg]+bsum)*gs + gb + xres;
        yo[(size_t)o*TV + tv0 + tv] = f2b(fmaxf(val,0.f));
      }
    }
  }
}

// ---------------- K3a: seT[n,c,v] = mean_t y1 ----------------
__global__ __launch_bounds__(256) void k_seT(const __hip_bfloat16* __restrict__ y1,
    float* __restrict__ seT)
{
  const int c=blockIdx.x, n=blockIdx.y, tid=threadIdx.x;
  const int v = tid&31, g = tid>>5;
  __shared__ float red[8][33];
  const __hip_bfloat16* yp = y1 + ((size_t)n*C_+c)*T_*V_;
  float s=0.f;
  if (v < V_){
    #pragma unroll 4
    for (int j=0;j<16;++j){
      int t = g + j*8;
      s += b2f(yp[t*V_+v]);
    }
  }
  red[g][v]=s;
  __syncthreads();
  if (tid < V_){
    float tot=0.f;
    #pragma unroll
    for (int g2=0;g2<8;++g2) tot += red[g2][tid];
    seT[((size_t)n*C_+c)*V_+tid]=tot*(1.f/T_);
  }
}

// ---------------- K3b: sa[n,v] spatial gate ----------------
__global__ __launch_bounds__(256) void k_sa(const float* __restrict__ seT,
    const float* __restrict__ W_sa, const float* __restrict__ b_sa,
    float* __restrict__ sa)
{
  const int n=blockIdx.x, tid=threadIdx.x;
  __shared__ float sel[CV];
  __shared__ float wsl[CV];
  __shared__ float part[8][32];
  const float* se = seT + (size_t)n*C_*V_;
  for (int i=tid;i<CV;i+=256){ sel[i]=se[i]; wsl[i]=W_sa[i]; }
  __syncthreads();
  if (tid < 200){
    const int v = tid%25, cg = tid/25;
    float acc=0.f;
    for (int c=cg*8;c<cg*8+8;++c){
      #pragma unroll
      for (int k=0;k<V_;++k){
        int vv=v+k-12;
        if (vv>=0&&vv<V_) acc += sel[c*V_+vv]*wsl[c*V_+k];
      }
    }
    part[cg][v]=acc;
  }
  __syncthreads();
  if (tid<V_){
    float acc=b_sa[0];
    #pragma unroll
    for (int g=0;g<8;++g) acc+=part[g][tid];
    sa[n*V_+tid]=sigm(acc);
  }
}

// ---------------- K3c: seV[n,c,t] = mean_v y1*(1+sa) ----------------
__global__ __launch_bounds__(256) void k_seV(const __hip_bfloat16* __restrict__ y1,
    const float* __restrict__ sa, float* __restrict__ seV)
{
  const int c=blockIdx.x, n=blockIdx.y, tid=threadIdx.x;
  const int v = tid&31, g = tid>>5;
  __shared__ float sal[32];
  if (tid<32) sal[tid] = (tid<V_)? 1.f+sa[n*V_+tid] : 0.f;
  __syncthreads();
  const __hip_bfloat16* yp = y1 + ((size_t)n*C_+c)*T_*V_;
  float* svo = seV + ((size_t)n*C_+c)*T_;
  const float sv_ = sal[v];
  for (int j=0;j<16;++j){
    int t = g*16 + j;
    float val = (v<V_)? b2f(yp[t*V_+v])*sv_ : 0.f;
    #pragma unroll
    for (int off=16;off;off>>=1) val += __shfl_xor(val, off);
    if (v==0) svo[t]=val*(1.f/V_);
  }
}

// ---------------- K3d: ta + ca gates ----------------
__global__ __launch_bounds__(256) void k_ta_ca(const float* __restrict__ seV,
    const float* __restrict__ W_ta, const float* __restrict__ b_ta,
    const float* __restrict__ W_fc1, const float* __restrict__ b_fc1,
    const float* __restrict__ W_fc2, const float* __restrict__ b_fc2,
    float* __restrict__ ta, float* __restrict__ ca)
{
  const int n=blockIdx.x, tid=threadIdx.x;
  __shared__ float svl[C_*T_];
  __shared__ float wtl[C_*9];
  __shared__ float w1l[32*C_];
  __shared__ float w2l[C_*32];
  __shared__ float tal[T_];
  __shared__ float part2[2][T_];
  __shared__ float part4[C_][4];
  __shared__ float scls[C_];
  __shared__ float h1[32];
  const float* sv = seV + (size_t)n*C_*T_;
  for (int i=tid;i<C_*T_;i+=256) svl[i]=sv[i];
  for (int i=tid;i<C_*9;i+=256) wtl[i]=W_ta[i];
  for (int i=tid;i<32*C_;i+=256){ w1l[i]=W_fc1[i]; w2l[i]=W_fc2[i]; }
  __syncthreads();
  {
    const int t = tid & 127, half = tid >> 7;
    float acc = 0.f;
    for (int c=half*32; c<half*32+32; ++c){
      #pragma unroll
      for (int k=0;k<9;++k){
        int tt=t+k-4;
        if (tt>=0&&tt<T_) acc += svl[c*T_+tt]*wtl[c*9+k];
      }
    }
    part2[half][t]=acc;
  }
  __syncthreads();
  if (tid<T_){
    float s_=sigm(part2[0][tid]+part2[1][tid]+b_ta[0]);
    tal[tid]=s_; ta[n*T_+tid]=s_;
  }
  __syncthreads();
  {
    const int c = tid>>2, q = tid&3;
    float acc=0.f;
    for (int t=q*32;t<q*32+32;++t) acc += svl[c*T_+t]*(1.f+tal[t]);
    part4[c][q]=acc;
  }
  __syncthreads();
  if (tid<C_) scls[tid]=(part4[tid][0]+part4[tid][1]+part4[tid][2]+part4[tid][3])*(1.f/T_);
  __syncthreads();
  if (tid<32){
    float acc=b_fc1[tid];
    for (int c=0;c<C_;++c) acc += scls[c]*w1l[tid*C_+c];
    h1[tid]=fmaxf(acc,0.f);
  }
  __syncthreads();
  if (tid<C_){
    float acc=b_fc2[tid];
    for (int j=0;j<32;++j) acc += h1[j]*w2l[tid*32+j];
    ca[n*C_+tid]=sigm(acc);
  }
}

// ---------------- K4: 4-t tile MFMA xa/gates + q/k/v projections ----------------
__global__ __launch_bounds__(256) void k_xa_qkv(
    const __hip_bfloat16* __restrict__ y1, const float* __restrict__ pos_emb,
    const float* __restrict__ sa, const float* __restrict__ ta, const float* __restrict__ ca,
    const short* __restrict__ w3b, const float* __restrict__ bq_h,
    const float* __restrict__ bk_h, const float* __restrict__ bv_h,
    __hip_bfloat16* __restrict__ xa, __hip_bfloat16* __restrict__ qb,
    __hip_bfloat16* __restrict__ kb, __hip_bfloat16* __restrict__ vb)
{
  const int tc=blockIdx.x, n=blockIdx.y, tid=threadIdx.x;
  const int wv=tid>>6, l=tid&63, lc=l&15, lk=l>>4;
  __shared__ __align__(16) short w3[192*72];
  __shared__ __align__(16) short xalT[4][32*72];
  __shared__ float bl[192];
  __shared__ float sal[32], cal[64], tgs[4];
  const int tv0 = tc*100;
  const __hip_bfloat16* y1n = y1 + (size_t)n*C_*TV;
  __hip_bfloat16* xan = xa + (size_t)n*C_*TV;
  uint2 ybuf[7];
  #pragma unroll
  for (int k=0;k<7;++k){
    int i = tid + k*256;
    if (i < 1600){
      int c=i/25, a=i%25;
      ybuf[k] = *(const uint2*)(y1n + (size_t)c*TV + tv0 + a*4);
    }
  }
  for (int i=tid;i<1536;i+=256){
    int mu=i>>3, j=i&7;
    *(short8v*)(w3 + mu*72 + j*8) = *(const short8v*)(w3b + mu*64 + j*8);
  }
  if (tid<192){
    int which=tid/C_, ho=tid%C_;
    bl[tid] = (which==0?bq_h:(which==1?bk_h:bv_h))[ho];
  }
  if (tid<32) sal[tid] = (tid<V_)? 1.f+sa[n*V_+tid] : 0.f;
  if (tid>=32 && tid<96) cal[tid-32] = 1.f+ca[n*C_+tid-32];
  if (tid>=96 && tid<100) tgs[tid-96] = 1.f+ta[n*T_+tc*4+(tid-96)];
  for (int i=tid;i<4*7*72;i+=256){
    int tl=i/(7*72), r=i%(7*72);
    xalT[tl][25*72 + r] = 0;
  }
  __syncthreads();
  #pragma unroll
  for (int k=0;k<7;++k){
    int i = tid + k*256;
    if (i < 1600){
      int c=i/25, a=i%25, tv4=a*4;
      unsigned int u0=ybuf[k].x, u1=ybuf[k].y;
      float yv[4] = {ubl(u0),ubh(u0),ubl(u1),ubh(u1)};
      const float calc = cal[c];
      unsigned long long pack = 0ull;
      #pragma unroll
      for (int j=0;j<4;++j){
        int tv=tv4+j, tl=tv/25, v=tv-tl*25;
        float val = yv[j]*sal[v]*tgs[tl]*calc + pos_emb[(size_t)(tc*4+tl)*CV + c*V_ + v];
        unsigned short b = f2bu(val);
        pack |= (unsigned long long)b << (16*j);
        xalT[tl][v*72 + c] = (short)b;
      }
      *(unsigned long long*)(xan + (size_t)c*TV + tv0 + tv4) = pack;
    }
  }
  __syncthreads();
  const int t = tc*4 + wv;
  short8v bf_[2][2];
  #pragma unroll
  for (int ks=0;ks<2;++ks){
    bf_[ks][0] = *(const short8v*)(&xalT[wv][lc*72      + ks*32 + lk*8]);
    bf_[ks][1] = *(const short8v*)(&xalT[wv][(16+lc)*72 + ks*32 + lk*8]);
  }
  #pragma unroll
  for (int mt=0;mt<12;++mt){
    f32x4 acc0 = {0.f,0.f,0.f,0.f}, acc1 = {0.f,0.f,0.f,0.f};
    #pragma unroll
    for (int ks=0;ks<2;++ks){
      short8v a = *(const short8v*)(w3 + (mt*16+lc)*72 + ks*32 + lk*8);
      acc0 = MFMA16(a, bf_[ks][0], acc0,0,0,0);
      acc1 = MFMA16(a, bf_[ks][1], acc1,0,0,0);
    }
    #pragma unroll
    for (int reg=0;reg<4;++reg){
      const int mu = mt*16 + lk*4 + reg;
      const int which = mt>>2;
      const int ho = mu & 63, h = ho>>3, o = ho&7;
      __hip_bfloat16* dst = (which==0?qb:(which==1?kb:vb))
                            + (((size_t)n*H_+h)*T_+t)*D_ + o*V_;
      const float bb = bl[mu];
      dst[lc] = f2b(acc0[reg]+bb);
      if (lc < 9) dst[16+lc] = f2b(acc1[reg]+bb);
    }
  }
}

// ---------------- K5: MFMA flash causal MHA (double-buffered K/V staging) ----------------
__global__ __launch_bounds__(256) void k_attn(
    const __hip_bfloat16* __restrict__ qb, const __hip_bfloat16* __restrict__ kb,
    const __hip_bfloat16* __restrict__ vb, __hip_bfloat16* __restrict__ oh)
{
  const int bx = blockIdx.x;
  const int hh = blockIdx.y;
  const int n  = blockIdx.z;
  const int nh = n*H_ + hh;
  const int tid = threadIdx.x;
  const int wv = tid>>6, l = tid&63;
  const int lc = l&15, lg = l>>4;
  __shared__ __align__(16) char KlB[32*512];
  __shared__ __align__(16) short VT[208*40];
  __shared__ __align__(16) short Pl[64*40];
  const __hip_bfloat16* qg_ = qb + (size_t)nh*T_*D_;
  const __hip_bfloat16* kg_ = kb + (size_t)nh*T_*D_;
  const __hip_bfloat16* vg_ = vb + (size_t)nh*T_*D_;
  __hip_bfloat16* ohn = oh + (size_t)n*C_*TV;
  const float scale = 0.0707106781f;

  for (int i=tid;i<32*12;i+=256){
    int key=i/12, j=i%12;
    *(unsigned int*)(KlB + ((key*512 + 400 + j*4) ^ ((key&7)<<4))) = 0u;
  }
  for (int i=tid;i<8*40;i+=256) VT[200*40 + i] = 0;

  const int qrow = bx*64 + wv*16 + lc;
  short8v qf[7];
  {
    const short8v* qs8 = (const short8v*)(qg_ + (size_t)qrow*D_);
    #pragma unroll
    for (int ks=0;ks<7;++ks) qf[ks] = qs8[ks*4 + lg];
  }
  f32x4 oacc[13];
  #pragma unroll
  for (int i=0;i<13;++i) oacc[i] = (f32x4){0.f,0.f,0.f,0.f};
  float m[4], lsm[4];
  #pragma unroll
  for (int r=0;r<4;++r){ m[r]=-1e30f; lsm[r]=0.f; }

  const int ntiles = (bx==0)? 2 : 4;
  // prologue: load tile 0 into registers
  short8v kreg[4], vreg[4];
  {
    const short8v* ks8 = (const short8v*)(kg_);
    const short8v* vs8 = (const short8v*)(vg_);
    #pragma unroll
    for (int k=0;k<4;++k){
      int i = tid + k*256;
      if (i<800){
        kreg[k] = ks8[i];
        vreg[k] = vs8[(i&31)*25 + (i>>5)];
      }
    }
  }
  for (int kt=0; kt<ntiles; ++kt){
    const int j0 = kt*32;
    // write staged registers to LDS
    #pragma unroll
    for (int k=0;k<4;++k){
      int i = tid + k*256;
      if (i<800){
        int row=i/25, w=i%25;
        *(short8v*)(KlB + ((row*512 + w*16) ^ ((row&7)<<4))) = kreg[k];
        int rowv=i&31, w4=i>>5;
        short8v u = vreg[k];
        #pragma unroll
        for (int j=0;j<8;++j) VT[(w4*8+j)*40 + rowv] = u[j];
      }
    }
    __syncthreads();
    // prefetch next tile into registers (overlaps with compute below)
    if (kt+1 < ntiles){
      const short8v* ks8 = (const short8v*)(kg_ + (size_t)(kt+1)*32*D_);
      const short8v* vs8 = (const short8v*)(vg_ + (size_t)(kt+1)*32*D_);
      #pragma unroll
      for (int k=0;k<4;++k){
        int i = tid + k*256;
        if (i<800){
          kreg[k] = ks8[i];
          vreg[k] = vs8[(i&31)*25 + (i>>5)];
        }
      }
    }
    const bool active = (j0 <= bx*64 + wv*16 + 15);
    if (active){
      f32x4 s0 = {0.f,0.f,0.f,0.f}, s1 = {0.f,0.f,0.f,0.f};
      #pragma unroll
      for (int ks=0;ks<7;++ks){
        short8v b0 = *(const short8v*)(KlB + ((lc*512      + ks*64 + lg*16) ^ ((lc&7)<<4)));
        short8v b1 = *(const short8v*)(KlB + (((16+lc)*512 + ks*64 + lg*16) ^ ((lc&7)<<4)));
        s0 = MFMA16(qf[ks], b0, s0,0,0,0);
        s1 = MFMA16(qf[ks], b1, s1,0,0,0);
      }
      float fr[4];
      #pragma unroll
      for (int r=0;r<4;++r){
        const int qg = bx*64 + wv*16 + lg*4 + r;
        float v0 = (j0+lc    <= qg) ? s0[r]*scale : -1e30f;
        float v1 = (j0+16+lc <= qg) ? s1[r]*scale : -1e30f;
        float mx = fmaxf(v0,v1);
        #pragma unroll
        for (int off=1;off<16;off<<=1) mx = fmaxf(mx, __shfl_xor(mx, off));
        float mn = fmaxf(m[r], mx);
        fr[r] = __expf(m[r]-mn);
        float p0 = __expf(v0-mn), p1 = __expf(v1-mn);
        float ts = p0+p1;
        #pragma unroll
        for (int off=1;off<16;off<<=1) ts += __shfl_xor(ts, off);
        lsm[r] = lsm[r]*fr[r] + ts;
        m[r] = mn;
        Pl[(wv*16 + lg*4 + r)*40 + lc]      = (short)f2bu(p0);
        Pl[(wv*16 + lg*4 + r)*40 + 16 + lc] = (short)f2bu(p1);
      }
      #pragma unroll
      for (int dt=0;dt<13;++dt){
        #pragma unroll
        for (int r=0;r<4;++r) oacc[dt][r] *= fr[r];
      }
      short8v pa = *(const short8v*)(Pl + (wv*16+lc)*40 + lg*8);
      #pragma unroll
      for (int dt=0;dt<13;++dt){
        short8v b = *(const short8v*)(VT + (dt*16+lc)*40 + lg*8);
        oacc[dt] = MFMA16(pa, b, oacc[dt],0,0,0);
      }
    }
    __syncthreads();   // all waves done reading this tile's LDS
  }
  float rl[4];
  #pragma unroll
  for (int r=0;r<4;++r) rl[r] = 1.f/lsm[r];
  #pragma unroll
  for (int dt=0;dt<13;++dt){
    const int d = dt*16 + lc;
    if (d < D_){
      const int oi = d/25, v = d - oi*25;
      const int c = hh*IH + oi;
      #pragma unroll
      for (int r=0;r<4;++r){
        const int q = bx*64 + wv*16 + lg*4 + r;
        ohn[(size_t)c*TV + q*V_ + v] = f2b(oacc[dt][r]*rl[r]);
      }
    }
  }
}

// ---------------- K7: 8-t tile MFMA out kernel (register-reuse epilogue) ----------------
__global__ __launch_bounds__(256) void k_out(
    const __hip_bfloat16* __restrict__ oh, const __hip_bfloat16* __restrict__ xa,
    const float* __restrict__ x, const short* __restrict__ Wffnb,
    const float* __restrict__ b_ffn, const float* __restrict__ m_gamma,
    const float* __restrict__ m_beta, float* __restrict__ out)
{
  const int tc = blockIdx.x, n = blockIdx.y, tid = threadIdx.x;
  const int wv = tid>>6, l = tid&63, lc = l&15, lg = l>>4;
  __shared__ __align__(16) short zT[208*72];
  __shared__ float bn_s[64], bn_b[64], bff[64];
  const float invs = rsqrtf(1.f+EPSB);
  if (tid<64){ bn_s[tid]=m_gamma[tid]*invs; bn_b[tid]=m_beta[tid]; bff[tid]=b_ffn[tid]; }
  for (int i=tid;i<8*72;i+=256) zT[200*72+i]=0;
  const int tv0 = tc*200;
  const __hip_bfloat16* xan = xa + (size_t)n*C_*TV;
  const __hip_bfloat16* ohn = oh + (size_t)n*C_*TV;
  uint4 xbuf[7], obuf[7];
  #pragma unroll
  for (int k=0;k<7;++k){
    int i = tid + k*256;
    if (i < 1600){
      int c=i/25, a=i%25;
      xbuf[k] = *(const uint4*)(xan + (size_t)c*TV + tv0 + a*8);
      obuf[k] = *(const uint4*)(ohn + (size_t)c*TV + tv0 + a*8);
    }
  }
  __syncthreads();
  #pragma unroll
  for (int k=0;k<7;++k){
    int i = tid + k*256;
    if (i < 1600){
      int c=i/25, a=i%25, tv8=a*8;
      const float s_=bn_s[c], b_=bn_b[c];
      const unsigned int* xu = (const unsigned int*)&xbuf[k];
      const unsigned int* ou = (const unsigned int*)&obuf[k];
      #pragma unroll
      for (int j=0;j<4;++j){
        zT[ZIDX(tv8+2*j,   c)] = (short)f2bu(s_*ubl(ou[j]) + b_ + ubl(xu[j]));
        zT[ZIDX(tv8+2*j+1, c)] = (short)f2bu(s_*ubh(ou[j]) + b_ + ubh(xu[j]));
      }
    }
  }
  __syncthreads();
  short8v af0 = *(const short8v*)(Wffnb + (wv*16+lc)*64 + lg*8);
  short8v af1 = *(const short8v*)(Wffnb + (wv*16+lc)*64 + 32 + lg*8);
  f32x4 acc[13];
  #pragma unroll
  for (int dt=0;dt<13;++dt) acc[dt] = (f32x4){0.f,0.f,0.f,0.f};
  #pragma unroll
  for (int dt=0;dt<13;++dt){
    short8v b0 = *(const short8v*)(zT + ZIDX(dt*16+lc, lg*8));
    short8v b1 = *(const short8v*)(zT + ZIDX(dt*16+lc, 32+lg*8));
    acc[dt] = MFMA16(af0, b0, acc[dt],0,0,0);
    acc[dt] = MFMA16(af1, b1, acc[dt],0,0,0);
  }
  __syncthreads();   // zT fully consumed
  // store FFN pre-bias output back into zT (bf16), layout [tv][o]
  #pragma unroll
  for (int dt=0;dt<13;++dt){
    const int tv = dt*16 + lc;
    if (tv < 200){
      #pragma unroll
      for (int reg=0;reg<4;++reg){
        const int o = wv*16 + lg*4 + reg;
        zT[ZIDX(tv, o)] = (short)f2bu(acc[dt][reg]);
      }
    }
  }
  __syncthreads();
  // ---- epilogue: reuse xbuf registers for xa; coalesced float4 x/out ----
  const float* xn = x + (size_t)n*C_*TV;
  float* outn = out + (size_t)n*C_*TV;
  #pragma unroll
  for (int k=0;k<7;++k){
    int i = tid + k*256;
    if (i < 1600){
      const int c=i/25, a=i%25, tv8=a*8;
      const unsigned int* xu = (const unsigned int*)&xbuf[k];
      const float s_=bn_s[c], b_=bn_b[c], bf_=bff[c];
      float4 xf0 = *(const float4*)(xn + (size_t)c*TV + tv0 + tv8);
      float4 xf1 = *(const float4*)(xn + (size_t)c*TV + tv0 + tv8 + 4);
      float xf[8] = {xf0.x,xf0.y,xf0.z,xf0.w,xf1.x,xf1.y,xf1.z,xf1.w};
      float res[8];
      #pragma unroll
      for (int j=0;j<4;++j){
        float xal = ubl(xu[j]), xah = ubh(xu[j]);
        float f0 = sh2f(zT[ZIDX(tv8+2*j,   c)]);
        float f1 = sh2f(zT[ZIDX(tv8+2*j+1, c)]);
        res[2*j]   = fmaxf(s_*(fmaxf(f0+bf_,0.f)+xal)+b_ + xf[2*j],   0.f);
        res[2*j+1] = fmaxf(s_*(fmaxf(f1+bf_,0.f)+xah)+b_ + xf[2*j+1], 0.f);
      }
      float4 o0 = {res[0],res[1],res[2],res[3]};
      float4 o1 = {res[4],res[5],res[6],res[7]};
      *(float4*)(outn + (size_t)c*TV + tv0 + tv8)     = o0;
      *(float4*)(outn + (size_t)c*TV + tv0 + tv8 + 4) = o1;
    }
  }
}

extern "C" void kernel_launch(void* const* d_in, const int* in_sizes, int n_in,
                              void* d_out, int out_size, void* d_ws, size_t ws_size,
                              hipStream_t stream) {
  const float* x      = (const float*)d_in[0];
  const float* A      = (const float*)d_in[1];
  const float* alphap = (const float*)d_in[2];
  const float* Wq     = (const float*)d_in[3];
  const float* bq     = (const float*)d_in[4];
  const float* Wk     = (const float*)d_in[5];
  const float* bk     = (const float*)d_in[6];
  const float* Wf     = (const float*)d_in[7];
  const float* bfp    = (const float*)d_in[8];
  const float* g_gamma= (const float*)d_in[9];
  const float* g_beta = (const float*)d_in[10];
  const float* W_sa   = (const float*)d_in[11];
  const float* b_sa   = (const float*)d_in[12];
  const float* W_ta   = (const float*)d_in[13];
  const float* b_ta   = (const float*)d_in[14];
  const float* W_fc1  = (const float*)d_in[15];
  const float* b_fc1  = (const float*)d_in[16];
  const float* W_fc2  = (const float*)d_in[17];
  const float* b_fc2  = (const float*)d_in[18];
  const float* pos_emb= (const float*)d_in[19];
  const float* Wq_h   = (const float*)d_in[20];
  const float* bq_h   = (const float*)d_in[21];
  const float* Wk_h   = (const float*)d_in[22];
  const float* bk_h   = (const float*)d_in[23];
  const float* Wv_h   = (const float*)d_in[24];
  const float* bv_h   = (const float*)d_in[25];
  const float* W_ffn  = (const float*)d_in[26];
  const float* b_ffn  = (const float*)d_in[27];
  const float* m_gamma= (const float*)d_in[28];
  const float* m_beta = (const float*)d_in[29];
  float* out = (float*)d_out;

  float* ws   = (float*)d_ws;
  float* seT  = ws;                    // 204800
  float* seV  = seT + 204800;          // 1048576
  float* sa   = seV + 1048576;         // 3200
  float* ta   = sa  + 3200;            // 16384
  float* ca   = ta  + 16384;           // 8192
  short* wsh  = (short*)(ca + 8192);
  short* AsTg = wsh;                   // 491520
  short* wqb  = AsTg + 491520;
  short* wkb  = wqb + 3072;
  short* Wfb  = wkb + 3072;
  short* w3b  = Wfb + 12288;
  short* Wffnb= w3b + 12288;
  __hip_bfloat16* y1 = (__hip_bfloat16*)(Wffnb + 4096);
  __hip_bfloat16* xa = y1 + (size_t)26214400;
  __hip_bfloat16* qb = xa + (size_t)26214400;
  __hip_bfloat16* kb = qb + (size_t)26214400;
  __hip_bfloat16* vb = kb + (size_t)26214400;
  __hip_bfloat16* oh = y1;   // reuse
  float* attg = (float*)y1;  // scratch before y1 written

  k_prep<<<48, 256, 0, stream>>>(Wq, Wk, Wf, Wq_h, Wk_h, Wv_h, W_ffn,
                                 wqb, wkb, Wfb, w3b, Wffnb);
  k_gcn_att1<<<dim3(16, N_), 256, 0, stream>>>(x, wqb, bq, wkb, bk, attg);
  k_gcn_att2<<<N_*S_, 256, 0, stream>>>(attg, A, alphap, AsTg);
  k_gcn_y<<<dim3(T_/4, N_), 256, 0, stream>>>(x, AsTg, Wfb, bfp, g_gamma, g_beta, y1);
  k_seT<<<dim3(C_, N_), 256, 0, stream>>>(y1, seT);
  k_sa<<<N_, 256, 0, stream>>>(seT, W_sa, b_sa, sa);
  k_seV<<<dim3(C_, N_), 256, 0, stream>>>(y1, sa, seV);
  k_ta_ca<<<N_, 256, 0, stream>>>(seV, W_ta, b_ta, W_fc1, b_fc1, W_fc2, b_fc2, ta, ca);
  k_xa_qkv<<<dim3(T_/4, N_), 256, 0, stream>>>(y1, pos_emb, sa, ta, ca,
      w3b, bq_h, bk_h, bv_h, xa, qb, kb, vb);
  k_attn<<<dim3(2, H_, N_), 256, 0, stream>>>(qb, kb, vb, oh);
  k_out<<<dim3(T_/8, N_), 256, 0, stream>>>(oh, xa, x, Wffnb, b_ffn, m_gamma, m_beta, out);
}